// Round 1
// baseline (5959.341 us; speedup 1.0000x reference)
//
#include <hip/hip_runtime.h>
#include <math.h>

#define NN 32768      // nodes total
#define BB 64         // graphs
#define NPG 512
#define DD 128
#define LL 3
#define EE 524288     // edges per side
#define NBINS 16
#define KNTN 16
#define NND (NN*DD)

__global__ void k_fill(float* __restrict__ p, float v, int n) {
    int i = blockIdx.x * blockDim.x + threadIdx.x;
    if (i < n) p[i] = v;
}

__global__ void k_count(const int* __restrict__ dst, float* __restrict__ deg) {
    int i = blockIdx.x * blockDim.x + threadIdx.x;
    atomicAdd(&deg[dst[i]], 1.0f);
}

__global__ void k_rsqrt(float* __restrict__ p, int n) {
    int i = blockIdx.x * blockDim.x + threadIdx.x;
    if (i < n) p[i] = 1.0f / sqrtf(p[i]);
}

// Out[n][j] = sum_d X[n][d] * W[j][d]  (+bias, +tanh per EPI)
template<int EPI>
__global__ __launch_bounds__(512) void k_gemm(const float* __restrict__ X,
                                              const float* __restrict__ W,
                                              const float* __restrict__ bias,
                                              float* __restrict__ Out) {
    __shared__ __align__(16) float xs[128][33];
    __shared__ __align__(16) float wt[32][132];
    const int t = threadIdx.x;
    const int row0 = blockIdx.x * 128;
    const int tr = t >> 5;    // 0..15
    const int tc = t & 31;    // 0..31
    const int lf = t & 7;     // float4 col 0..7
    const int lr = t >> 3;    // 0..63
    float acc[8][4];
    #pragma unroll
    for (int i = 0; i < 8; i++)
        #pragma unroll
        for (int j = 0; j < 4; j++) acc[i][j] = 0.f;

    for (int kt = 0; kt < 4; ++kt) {
        #pragma unroll
        for (int p = 0; p < 2; p++) {
            int r = lr + p * 64;
            float4 v = *(const float4*)&X[(size_t)(row0 + r) * DD + kt * 32 + lf * 4];
            xs[r][lf * 4 + 0] = v.x; xs[r][lf * 4 + 1] = v.y;
            xs[r][lf * 4 + 2] = v.z; xs[r][lf * 4 + 3] = v.w;
        }
        #pragma unroll
        for (int p = 0; p < 2; p++) {
            int j = lr + p * 64;
            float4 v = *(const float4*)&W[(size_t)j * DD + kt * 32 + lf * 4];
            wt[lf * 4 + 0][j] = v.x; wt[lf * 4 + 1][j] = v.y;
            wt[lf * 4 + 2][j] = v.z; wt[lf * 4 + 3][j] = v.w;
        }
        __syncthreads();
        #pragma unroll
        for (int k = 0; k < 32; k++) {
            float a[8];
            #pragma unroll
            for (int i = 0; i < 8; i++) a[i] = xs[tr * 8 + i][k];
            float4 b4 = *(const float4*)&wt[k][tc * 4];
            #pragma unroll
            for (int i = 0; i < 8; i++) {
                acc[i][0] += a[i] * b4.x; acc[i][1] += a[i] * b4.y;
                acc[i][2] += a[i] * b4.z; acc[i][3] += a[i] * b4.w;
            }
        }
        __syncthreads();
    }
    #pragma unroll
    for (int i = 0; i < 8; i++) {
        int row = row0 + tr * 8 + i;
        int col = tc * 4;
        float4 v;
        v.x = acc[i][0]; v.y = acc[i][1]; v.z = acc[i][2]; v.w = acc[i][3];
        if (EPI >= 1) { v.x += bias[col]; v.y += bias[col+1]; v.z += bias[col+2]; v.w += bias[col+3]; }
        if (EPI == 2) { v.x = tanhf(v.x); v.y = tanhf(v.y); v.z = tanhf(v.z); v.w = tanhf(v.w); }
        *(float4*)&Out[(size_t)row * DD + col] = v;
    }
}

// Out[dst] += dinv[src]*dinv[dst]*H[src]  (32 threads per edge, 4 floats each)
__global__ void k_scatter(const int* __restrict__ src, const int* __restrict__ dst,
                          const float* __restrict__ dinv, const float* __restrict__ H,
                          float* __restrict__ Out) {
    unsigned tid = blockIdx.x * blockDim.x + threadIdx.x;
    int e = tid >> 5;
    int c = (tid & 31) * 4;
    int s = src[e], d = dst[e];
    float w = dinv[s] * dinv[d];
    float4 h4 = *(const float4*)&H[(size_t)s * DD + c];
    float* o = &Out[(size_t)d * DD + c];
    atomicAdd(o + 0, w * h4.x);
    atomicAdd(o + 1, w * h4.y);
    atomicAdd(o + 2, w * h4.z);
    atomicAdd(o + 3, w * h4.w);
}

// A = relu(BN(A + dinv^2*H + gcn_b))
__global__ void k_bnrelu(float* __restrict__ A, const float* __restrict__ H,
                         const float* __restrict__ dinv, const float* __restrict__ gb,
                         const float* __restrict__ gam, const float* __restrict__ bet,
                         const float* __restrict__ mean, const float* __restrict__ var) {
    int idx = blockIdx.x * blockDim.x + threadIdx.x;   // per float4
    int n = idx >> 5;
    int c = (idx & 31) * 4;
    float di = dinv[n];
    float w = di * di;
    float4 a = *(float4*)&A[(size_t)idx * 4];
    float4 h = *(const float4*)&H[(size_t)idx * 4];
    float4 b4 = *(const float4*)&gb[c];
    float4 g4 = *(const float4*)&gam[c];
    float4 be4 = *(const float4*)&bet[c];
    float4 m4 = *(const float4*)&mean[c];
    float4 v4 = *(const float4*)&var[c];
    float o0 = a.x + w * h.x + b4.x, o1 = a.y + w * h.y + b4.y;
    float o2 = a.z + w * h.z + b4.z, o3 = a.w + w * h.w + b4.w;
    o0 = (o0 - m4.x) * rsqrtf(v4.x + 1e-5f) * g4.x + be4.x;
    o1 = (o1 - m4.y) * rsqrtf(v4.y + 1e-5f) * g4.y + be4.y;
    o2 = (o2 - m4.z) * rsqrtf(v4.z + 1e-5f) * g4.z + be4.z;
    o3 = (o3 - m4.w) * rsqrtf(v4.w + 1e-5f) * g4.w + be4.w;
    float4 o;
    o.x = fmaxf(o0, 0.f); o.y = fmaxf(o1, 0.f); o.z = fmaxf(o2, 0.f); o.w = fmaxf(o3, 0.f);
    *(float4*)&A[(size_t)idx * 4] = o;
}

// S[n] = dot(T[n,:], att_w) + att_b  (one wave per node)
__global__ void k_score(const float* __restrict__ T, const float* __restrict__ aw,
                        const float* __restrict__ ab, float* __restrict__ S) {
    int g = blockIdx.x * blockDim.x + threadIdx.x;
    int wid = g >> 6;
    int lane = threadIdx.x & 63;
    float acc = T[(size_t)wid * DD + lane] * aw[lane] +
                T[(size_t)wid * DD + 64 + lane] * aw[64 + lane];
    #pragma unroll
    for (int o = 32; o > 0; o >>= 1) acc += __shfl_down(acc, o);
    if (lane == 0) S[wid] = acc + ab[0];
}

// per-graph softmax over S then weighted sum of Emb -> G[b][:]
__global__ __launch_bounds__(256) void k_pool(const float* __restrict__ S,
                                              const float* __restrict__ Emb,
                                              float* __restrict__ G) {
    int b = blockIdx.x;
    __shared__ float w[512];
    __shared__ float red[256];
    int t = threadIdx.x;
    float s0 = S[b * NPG + t], s1 = S[b * NPG + 256 + t];
    red[t] = fmaxf(s0, s1);
    __syncthreads();
    for (int o = 128; o > 0; o >>= 1) { if (t < o) red[t] = fmaxf(red[t], red[t + o]); __syncthreads(); }
    float mx = red[0];
    __syncthreads();
    float e0 = expf(s0 - mx), e1 = expf(s1 - mx);
    w[t] = e0; w[t + 256] = e1;
    red[t] = e0 + e1;
    __syncthreads();
    for (int o = 128; o > 0; o >>= 1) { if (t < o) red[t] += red[t + o]; __syncthreads(); }
    float inv = 1.0f / red[0];
    __syncthreads();
    int d = t & 127, half = t >> 7;
    float acc = 0.f;
    for (int n = half * 256; n < half * 256 + 256; n++)
        acc += w[n] * Emb[((size_t)b * NPG + n) * DD + d];
    red[t] = acc;
    __syncthreads();
    if (t < 128) G[b * DD + t] = (red[t] + red[t + 128]) * inv;
}

// cosine-sim histogram: block = 64x64 tile of one graph's 512x512 sims
__global__ __launch_bounds__(256) void k_hist(const float* __restrict__ E1,
                                              const float* __restrict__ E2,
                                              float* __restrict__ Hist) {
    __shared__ __align__(16) float s1[64][129];
    __shared__ __align__(16) float s2[64][129];
    __shared__ float inv1[64], inv2[64];
    __shared__ int hloc[NBINS];
    int blk = blockIdx.x;
    int b = blk >> 6, tt = blk & 63;
    int i0 = (tt >> 3) * 64, j0 = (tt & 7) * 64;
    int t = threadIdx.x;
    int lf = t & 31, r = t >> 5;   // lf: float4 col 0..31, r: 0..7
    #pragma unroll
    for (int p = 0; p < 8; p++) {
        int row = r + p * 8;
        float4 v1 = *(const float4*)&E1[((size_t)b * NPG + i0 + row) * DD + lf * 4];
        s1[row][lf * 4 + 0] = v1.x; s1[row][lf * 4 + 1] = v1.y;
        s1[row][lf * 4 + 2] = v1.z; s1[row][lf * 4 + 3] = v1.w;
        float4 v2 = *(const float4*)&E2[((size_t)b * NPG + j0 + row) * DD + lf * 4];
        s2[row][lf * 4 + 0] = v2.x; s2[row][lf * 4 + 1] = v2.y;
        s2[row][lf * 4 + 2] = v2.z; s2[row][lf * 4 + 3] = v2.w;
    }
    if (t < NBINS) hloc[t] = 0;
    __syncthreads();
    if (t < 128) {
        const float* rowp = (t < 64) ? &s1[t][0] : &s2[t - 64][0];
        float ss = 0.f;
        for (int d = 0; d < DD; d++) { float x = rowp[d]; ss += x * x; }
        float iv = 1.0f / fmaxf(sqrtf(ss), 1e-8f);
        if (t < 64) inv1[t] = iv; else inv2[t - 64] = iv;
    }
    __syncthreads();
    int ty = t >> 4, tx = t & 15;
    float acc[4][4] = {};
    for (int d = 0; d < DD; d++) {
        float a0 = s1[ty * 4 + 0][d], a1 = s1[ty * 4 + 1][d];
        float a2 = s1[ty * 4 + 2][d], a3 = s1[ty * 4 + 3][d];
        float b0 = s2[tx * 4 + 0][d], b1 = s2[tx * 4 + 1][d];
        float b2 = s2[tx * 4 + 2][d], b3 = s2[tx * 4 + 3][d];
        acc[0][0] += a0 * b0; acc[0][1] += a0 * b1; acc[0][2] += a0 * b2; acc[0][3] += a0 * b3;
        acc[1][0] += a1 * b0; acc[1][1] += a1 * b1; acc[1][2] += a1 * b2; acc[1][3] += a1 * b3;
        acc[2][0] += a2 * b0; acc[2][1] += a2 * b1; acc[2][2] += a2 * b2; acc[2][3] += a2 * b3;
        acc[3][0] += a3 * b0; acc[3][1] += a3 * b1; acc[3][2] += a3 * b2; acc[3][3] += a3 * b3;
    }
    #pragma unroll
    for (int i = 0; i < 4; i++)
        #pragma unroll
        for (int j = 0; j < 4; j++) {
            float sim = acc[i][j] * inv1[ty * 4 + i] * inv2[tx * 4 + j];
            int bi = (int)floorf((sim + 1.0f) * 8.0f);
            bi = bi < 0 ? 0 : (bi > 15 ? 15 : bi);
            atomicAdd(&hloc[bi], 1);
        }
    __syncthreads();
    if (t < NBINS) atomicAdd(&Hist[b * NBINS + t], (float)hloc[t]);
}

// TP[b][k] = g1[b]^T T_k g2[b] + tb[k]
__global__ __launch_bounds__(128) void k_ntn(const float* __restrict__ G1,
                                             const float* __restrict__ G2,
                                             const float* __restrict__ T,
                                             const float* __restrict__ tb,
                                             float* __restrict__ TP) {
    int b = blockIdx.x, k = blockIdx.y;
    int e = threadIdx.x;
    const float* Tk = T + (size_t)k * DD * DD;
    float g2e = G2[b * DD + e];
    float acc = 0.f;
    for (int d = 0; d < DD; d++) acc += G1[b * DD + d] * Tk[(size_t)d * DD + e];
    float val = acc * g2e;
    #pragma unroll
    for (int o = 32; o > 0; o >>= 1) val += __shfl_down(val, o);
    __shared__ float ps[2];
    if ((e & 63) == 0) ps[e >> 6] = val;
    __syncthreads();
    if (e == 0) TP[b * KNTN + k] = ps[0] + ps[1] + tb[k];
}

__global__ void k_final(const float* __restrict__ TP, const float* __restrict__ Hist,
                        const float* nw1, const float* nb1, const float* nw2, const float* nb2,
                        const float* nw3, const float* nb3,
                        const float* hw1, const float* hb1, const float* hw2, const float* hb2,
                        const float* fw1, const float* fb1, const float* fw2, const float* fb2,
                        float* __restrict__ out) {
    int b = threadIdx.x;
    float h1[32];
    #pragma unroll
    for (int i = 0; i < 32; i++) {
        float a = nb1[i];
        for (int k = 0; k < 16; k++) a += TP[b * 16 + k] * nw1[i * 16 + k];
        h1[i] = fmaxf(a, 0.f);
    }
    float h2[16];
    #pragma unroll
    for (int j = 0; j < 16; j++) {
        float a = nb2[j];
        for (int i = 0; i < 32; i++) a += h1[i] * nw2[j * 32 + i];
        h2[j] = fmaxf(a, 0.f);
    }
    float nt = nb3[0];
    for (int j = 0; j < 16; j++) nt += h2[j] * nw3[j];
    nt = 1.f / (1.f + expf(-nt));
    float hh[16]; float sum = 0.f;
    for (int k = 0; k < 16; k++) { hh[k] = Hist[b * 16 + k]; sum += hh[k]; }
    float inv = 1.f / (sum + 1e-8f);
    for (int k = 0; k < 16; k++) hh[k] *= inv;
    float g1v[32];
    #pragma unroll
    for (int i = 0; i < 32; i++) {
        float a = hb1[i];
        for (int k = 0; k < 16; k++) a += hh[k] * hw1[i * 16 + k];
        g1v[i] = fmaxf(a, 0.f);
    }
    float hemb[16];
    #pragma unroll
    for (int j = 0; j < 16; j++) {
        float a = hb2[j];
        for (int i = 0; i < 32; i++) a += g1v[i] * hw2[j * 32 + i];
        hemb[j] = a;
    }
    float comb[17];
    comb[0] = nt;
    for (int j = 0; j < 16; j++) comb[1 + j] = hemb[j];
    float f1[8];
    #pragma unroll
    for (int i = 0; i < 8; i++) {
        float a = fb1[i];
        for (int j = 0; j < 17; j++) a += comb[j] * fw1[i * 17 + j];
        f1[i] = fmaxf(a, 0.f);
    }
    float o = fb2[0];
    for (int i = 0; i < 8; i++) o += f1[i] * fw2[i];
    out[b] = 1.f / (1.f + expf(-o));
}

extern "C" void kernel_launch(void* const* d_in, const int* in_sizes, int n_in,
                              void* d_out, int out_size, void* d_ws, size_t ws_size,
                              hipStream_t stream) {
    const float* x1    = (const float*)d_in[0];
    const float* x2    = (const float*)d_in[1];
    const int*   ei1   = (const int*)d_in[2];
    const int*   ei2   = (const int*)d_in[3];
    const float* gcn_w = (const float*)d_in[6];
    const float* gcn_b = (const float*)d_in[7];
    const float* bn_g  = (const float*)d_in[8];
    const float* bn_b  = (const float*)d_in[9];
    const float* bn_m  = (const float*)d_in[10];
    const float* bn_v  = (const float*)d_in[11];
    const float* ctx_w = (const float*)d_in[12];
    const float* ctx_b = (const float*)d_in[13];
    const float* att_w = (const float*)d_in[14];
    const float* att_b = (const float*)d_in[15];
    const float* ntn_T = (const float*)d_in[16];
    const float* ntn_b = (const float*)d_in[17];
    const float* nw1 = (const float*)d_in[18];
    const float* nb1 = (const float*)d_in[19];
    const float* nw2 = (const float*)d_in[20];
    const float* nb2 = (const float*)d_in[21];
    const float* nw3 = (const float*)d_in[22];
    const float* nb3 = (const float*)d_in[23];
    const float* hw1 = (const float*)d_in[24];
    const float* hb1 = (const float*)d_in[25];
    const float* hw2 = (const float*)d_in[26];
    const float* hb2 = (const float*)d_in[27];
    const float* fw1 = (const float*)d_in[28];
    const float* fb1 = (const float*)d_in[29];
    const float* fw2 = (const float*)d_in[30];
    const float* fb2 = (const float*)d_in[31];
    float* out = (float*)d_out;

    float* A1    = (float*)d_ws;
    float* A2    = A1 + NND;
    float* H     = A2 + NND;
    float* dinv1 = H + NND;
    float* dinv2 = dinv1 + NN;
    float* sbuf  = dinv2 + NN;
    float* g1    = sbuf + NN;
    float* g2    = g1 + BB * DD;
    float* hist  = g2 + BB * DD;
    float* tp    = hist + BB * NBINS;

    // degrees (init 1.0 = self-loop) -> dinv
    k_fill<<<2 * NN / 256, 256, 0, stream>>>(dinv1, 1.0f, 2 * NN);
    k_count<<<EE / 256, 256, 0, stream>>>(ei1 + EE, dinv1);
    k_count<<<EE / 256, 256, 0, stream>>>(ei2 + EE, dinv2);
    k_rsqrt<<<2 * NN / 256, 256, 0, stream>>>(dinv1, 2 * NN);

    for (int side = 0; side < 2; ++side) {
        const float* X0 = side ? x2 : x1;
        float* A = side ? A2 : A1;
        const int* ei = side ? ei2 : ei1;
        const float* dinv = side ? dinv2 : dinv1;
        for (int l = 0; l < LL; l++) {
            k_gemm<0><<<NN / 128, 512, 0, stream>>>(l == 0 ? X0 : A, gcn_w + (size_t)l * DD * DD, nullptr, H);
            hipMemsetAsync(A, 0, (size_t)NND * 4, stream);
            k_scatter<<<EE * 32 / 256, 256, 0, stream>>>(ei, ei + EE, dinv, H, A);
            k_bnrelu<<<NND / 1024, 256, 0, stream>>>(A, H, dinv, gcn_b + l * DD, bn_g + l * DD,
                                                     bn_b + l * DD, bn_m + l * DD, bn_v + l * DD);
        }
        k_gemm<2><<<NN / 128, 512, 0, stream>>>(A, ctx_w, ctx_b, H);
        k_score<<<NN / 4, 256, 0, stream>>>(H, att_w, att_b, sbuf);
        k_pool<<<BB, 256, 0, stream>>>(sbuf, A, side ? g2 : g1);
    }

    hipMemsetAsync(hist, 0, BB * NBINS * sizeof(float), stream);
    k_hist<<<BB * 64, 256, 0, stream>>>(A1, A2, hist);
    k_ntn<<<dim3(BB, KNTN), 128, 0, stream>>>(g1, g2, ntn_T, ntn_b, tp);
    k_final<<<1, 64, 0, stream>>>(tp, hist, nw1, nb1, nw2, nb2, nw3, nb3,
                                  hw1, hb1, hw2, hb2, fw1, fb1, fw2, fb2, out);
}

// Round 2
// 997.171 us; speedup vs baseline: 5.9762x; 5.9762x over previous
//
#include <hip/hip_runtime.h>
#include <math.h>

#define NN 32768      // nodes total
#define BB 64         // graphs
#define NPG 512
#define DD 128
#define LL 3
#define EE 524288     // edges per side
#define NBINS 16
#define KNTN 16
#define NND (NN*DD)

__global__ void k_counti(const int* __restrict__ dst, int* __restrict__ deg) {
    int i = blockIdx.x * blockDim.x + threadIdx.x;
    atomicAdd(&deg[dst[i]], 1);
}

__global__ void k_dinv(const int* __restrict__ deg, float* __restrict__ dinv) {
    int i = blockIdx.x * blockDim.x + threadIdx.x;
    dinv[i] = rsqrtf((float)deg[i] + 1.0f);   // +1 = self-loop
}

// single block: exclusive scan of deg[NN] -> rowstart[NN+1], cursor copy
__global__ __launch_bounds__(1024) void k_scan(const int* __restrict__ deg,
                                               int* __restrict__ rowstart,
                                               int* __restrict__ cursor) {
    __shared__ int part[1024];
    int t = threadIdx.x;
    int base = t * 32;
    int loc[32];
    int s = 0;
    #pragma unroll
    for (int i = 0; i < 32; i++) { loc[i] = s; s += deg[base + i]; }
    part[t] = s;
    __syncthreads();
    for (int o = 1; o < 1024; o <<= 1) {
        int v = (t >= o) ? part[t - o] : 0;
        __syncthreads();
        part[t] += v;
        __syncthreads();
    }
    int excl = (t == 0) ? 0 : part[t - 1];
    #pragma unroll
    for (int i = 0; i < 32; i++) {
        int v = excl + loc[i];
        rowstart[base + i] = v;
        cursor[base + i] = v;
    }
    if (t == 1023) rowstart[NN] = part[1023];
}

__global__ void k_fill_edges(const int* __restrict__ src, const int* __restrict__ dst,
                             int* __restrict__ cursor, int* __restrict__ esrc) {
    int e = blockIdx.x * blockDim.x + threadIdx.x;
    int s = src[e], d = dst[e];
    int slot = atomicAdd(&cursor[d], 1);
    esrc[slot] = s;
}

// Out[n][j] = sum_d X[n][d] * W[j][d]  (+bias, +tanh per EPI)
template<int EPI>
__global__ __launch_bounds__(512) void k_gemm(const float* __restrict__ X,
                                              const float* __restrict__ W,
                                              const float* __restrict__ bias,
                                              float* __restrict__ Out) {
    __shared__ __align__(16) float xs[128][33];
    __shared__ __align__(16) float wt[32][132];
    const int t = threadIdx.x;
    const int row0 = blockIdx.x * 128;
    const int tr = t >> 5;    // 0..15
    const int tc = t & 31;    // 0..31
    const int lf = t & 7;     // float4 col 0..7
    const int lr = t >> 3;    // 0..63
    float acc[8][4];
    #pragma unroll
    for (int i = 0; i < 8; i++)
        #pragma unroll
        for (int j = 0; j < 4; j++) acc[i][j] = 0.f;

    for (int kt = 0; kt < 4; ++kt) {
        #pragma unroll
        for (int p = 0; p < 2; p++) {
            int r = lr + p * 64;
            float4 v = *(const float4*)&X[(size_t)(row0 + r) * DD + kt * 32 + lf * 4];
            xs[r][lf * 4 + 0] = v.x; xs[r][lf * 4 + 1] = v.y;
            xs[r][lf * 4 + 2] = v.z; xs[r][lf * 4 + 3] = v.w;
        }
        #pragma unroll
        for (int p = 0; p < 2; p++) {
            int j = lr + p * 64;
            float4 v = *(const float4*)&W[(size_t)j * DD + kt * 32 + lf * 4];
            wt[lf * 4 + 0][j] = v.x; wt[lf * 4 + 1][j] = v.y;
            wt[lf * 4 + 2][j] = v.z; wt[lf * 4 + 3][j] = v.w;
        }
        __syncthreads();
        #pragma unroll
        for (int k = 0; k < 32; k++) {
            float a[8];
            #pragma unroll
            for (int i = 0; i < 8; i++) a[i] = xs[tr * 8 + i][k];
            float4 b4 = *(const float4*)&wt[k][tc * 4];
            #pragma unroll
            for (int i = 0; i < 8; i++) {
                acc[i][0] += a[i] * b4.x; acc[i][1] += a[i] * b4.y;
                acc[i][2] += a[i] * b4.z; acc[i][3] += a[i] * b4.w;
            }
        }
        __syncthreads();
    }
    #pragma unroll
    for (int i = 0; i < 8; i++) {
        int row = row0 + tr * 8 + i;
        int col = tc * 4;
        float4 v;
        v.x = acc[i][0]; v.y = acc[i][1]; v.z = acc[i][2]; v.w = acc[i][3];
        if (EPI >= 1) { v.x += bias[col]; v.y += bias[col+1]; v.z += bias[col+2]; v.w += bias[col+3]; }
        if (EPI == 2) { v.x = tanhf(v.x); v.y = tanhf(v.y); v.z = tanhf(v.z); v.w = tanhf(v.w); }
        *(float4*)&Out[(size_t)row * DD + col] = v;
    }
}

// A[n] = relu(BN( dinv[n]*( sum_in dinv[s]*H[s] + dinv[n]*H[n] ) + gcn_b ))
// one wave per node, 2 floats per lane
__global__ __launch_bounds__(256) void k_aggregate(
    const float* __restrict__ H, const int* __restrict__ rowstart,
    const int* __restrict__ esrc, const float* __restrict__ dinv,
    const float* __restrict__ gb, const float* __restrict__ gam,
    const float* __restrict__ bet, const float* __restrict__ mean,
    const float* __restrict__ var, float* __restrict__ A) {
    int n = (blockIdx.x * blockDim.x + threadIdx.x) >> 6;
    int lane = threadIdx.x & 63;
    int beg = rowstart[n], end = rowstart[n + 1];
    float di = dinv[n];
    float acc0 = di * H[(size_t)n * DD + lane];
    float acc1 = di * H[(size_t)n * DD + 64 + lane];
    for (int j = beg; j < end; j++) {
        int s = esrc[j];
        float w = dinv[s];
        acc0 += w * H[(size_t)s * DD + lane];
        acc1 += w * H[(size_t)s * DD + 64 + lane];
    }
    acc0 *= di; acc1 *= di;
    int c0 = lane, c1 = 64 + lane;
    float sc0 = gam[c0] * rsqrtf(var[c0] + 1e-5f);
    float sc1 = gam[c1] * rsqrtf(var[c1] + 1e-5f);
    float o0 = (acc0 + gb[c0] - mean[c0]) * sc0 + bet[c0];
    float o1 = (acc1 + gb[c1] - mean[c1]) * sc1 + bet[c1];
    A[(size_t)n * DD + c0] = fmaxf(o0, 0.f);
    A[(size_t)n * DD + c1] = fmaxf(o1, 0.f);
}

// S[n] = dot(T[n,:], att_w) + att_b  (one wave per node)
__global__ void k_score(const float* __restrict__ T, const float* __restrict__ aw,
                        const float* __restrict__ ab, float* __restrict__ S) {
    int g = blockIdx.x * blockDim.x + threadIdx.x;
    int wid = g >> 6;
    int lane = threadIdx.x & 63;
    float acc = T[(size_t)wid * DD + lane] * aw[lane] +
                T[(size_t)wid * DD + 64 + lane] * aw[64 + lane];
    #pragma unroll
    for (int o = 32; o > 0; o >>= 1) acc += __shfl_down(acc, o);
    if (lane == 0) S[wid] = acc + ab[0];
}

// per-graph softmax over S then weighted sum of Emb -> G[b][:]
__global__ __launch_bounds__(256) void k_pool(const float* __restrict__ S,
                                              const float* __restrict__ Emb,
                                              float* __restrict__ G) {
    int b = blockIdx.x;
    __shared__ float w[512];
    __shared__ float red[256];
    int t = threadIdx.x;
    float s0 = S[b * NPG + t], s1 = S[b * NPG + 256 + t];
    red[t] = fmaxf(s0, s1);
    __syncthreads();
    for (int o = 128; o > 0; o >>= 1) { if (t < o) red[t] = fmaxf(red[t], red[t + o]); __syncthreads(); }
    float mx = red[0];
    __syncthreads();
    float e0 = expf(s0 - mx), e1 = expf(s1 - mx);
    w[t] = e0; w[t + 256] = e1;
    red[t] = e0 + e1;
    __syncthreads();
    for (int o = 128; o > 0; o >>= 1) { if (t < o) red[t] += red[t + o]; __syncthreads(); }
    float inv = 1.0f / red[0];
    __syncthreads();
    int d = t & 127, half = t >> 7;
    float acc = 0.f;
    for (int n = half * 256; n < half * 256 + 256; n++)
        acc += w[n] * Emb[((size_t)b * NPG + n) * DD + d];
    red[t] = acc;
    __syncthreads();
    if (t < 128) G[b * DD + t] = (red[t] + red[t + 128]) * inv;
}

// cosine-sim histogram: block = 64x64 tile of one graph's 512x512 sims
__global__ __launch_bounds__(256) void k_hist(const float* __restrict__ E1,
                                              const float* __restrict__ E2,
                                              float* __restrict__ Hist) {
    __shared__ __align__(16) float s1[64][129];
    __shared__ __align__(16) float s2[64][129];
    __shared__ float inv1[64], inv2[64];
    __shared__ int hloc[NBINS];
    int blk = blockIdx.x;
    int b = blk >> 6, tt = blk & 63;
    int i0 = (tt >> 3) * 64, j0 = (tt & 7) * 64;
    int t = threadIdx.x;
    int lf = t & 31, r = t >> 5;   // lf: float4 col 0..31, r: 0..7
    #pragma unroll
    for (int p = 0; p < 8; p++) {
        int row = r + p * 8;
        float4 v1 = *(const float4*)&E1[((size_t)b * NPG + i0 + row) * DD + lf * 4];
        s1[row][lf * 4 + 0] = v1.x; s1[row][lf * 4 + 1] = v1.y;
        s1[row][lf * 4 + 2] = v1.z; s1[row][lf * 4 + 3] = v1.w;
        float4 v2 = *(const float4*)&E2[((size_t)b * NPG + j0 + row) * DD + lf * 4];
        s2[row][lf * 4 + 0] = v2.x; s2[row][lf * 4 + 1] = v2.y;
        s2[row][lf * 4 + 2] = v2.z; s2[row][lf * 4 + 3] = v2.w;
    }
    if (t < NBINS) hloc[t] = 0;
    __syncthreads();
    if (t < 128) {
        const float* rowp = (t < 64) ? &s1[t][0] : &s2[t - 64][0];
        float ss = 0.f;
        for (int d = 0; d < DD; d++) { float x = rowp[d]; ss += x * x; }
        float iv = 1.0f / fmaxf(sqrtf(ss), 1e-8f);
        if (t < 64) inv1[t] = iv; else inv2[t - 64] = iv;
    }
    __syncthreads();
    int ty = t >> 4, tx = t & 15;
    float acc[4][4] = {};
    for (int d = 0; d < DD; d++) {
        float a0 = s1[ty * 4 + 0][d], a1 = s1[ty * 4 + 1][d];
        float a2 = s1[ty * 4 + 2][d], a3 = s1[ty * 4 + 3][d];
        float b0 = s2[tx * 4 + 0][d], b1 = s2[tx * 4 + 1][d];
        float b2 = s2[tx * 4 + 2][d], b3 = s2[tx * 4 + 3][d];
        acc[0][0] += a0 * b0; acc[0][1] += a0 * b1; acc[0][2] += a0 * b2; acc[0][3] += a0 * b3;
        acc[1][0] += a1 * b0; acc[1][1] += a1 * b1; acc[1][2] += a1 * b2; acc[1][3] += a1 * b3;
        acc[2][0] += a2 * b0; acc[2][1] += a2 * b1; acc[2][2] += a2 * b2; acc[2][3] += a2 * b3;
        acc[3][0] += a3 * b0; acc[3][1] += a3 * b1; acc[3][2] += a3 * b2; acc[3][3] += a3 * b3;
    }
    #pragma unroll
    for (int i = 0; i < 4; i++)
        #pragma unroll
        for (int j = 0; j < 4; j++) {
            float sim = acc[i][j] * inv1[ty * 4 + i] * inv2[tx * 4 + j];
            int bi = (int)floorf((sim + 1.0f) * 8.0f);
            bi = bi < 0 ? 0 : (bi > 15 ? 15 : bi);
            atomicAdd(&hloc[bi], 1);
        }
    __syncthreads();
    if (t < NBINS) atomicAdd(&Hist[b * NBINS + t], (float)hloc[t]);
}

// TP[b][k] = g1[b]^T T_k g2[b] + tb[k]
__global__ __launch_bounds__(128) void k_ntn(const float* __restrict__ G1,
                                             const float* __restrict__ G2,
                                             const float* __restrict__ T,
                                             const float* __restrict__ tb,
                                             float* __restrict__ TP) {
    int b = blockIdx.x, k = blockIdx.y;
    int e = threadIdx.x;
    const float* Tk = T + (size_t)k * DD * DD;
    float g2e = G2[b * DD + e];
    float acc = 0.f;
    for (int d = 0; d < DD; d++) acc += G1[b * DD + d] * Tk[(size_t)d * DD + e];
    float val = acc * g2e;
    #pragma unroll
    for (int o = 32; o > 0; o >>= 1) val += __shfl_down(val, o);
    __shared__ float ps[2];
    if ((e & 63) == 0) ps[e >> 6] = val;
    __syncthreads();
    if (e == 0) TP[b * KNTN + k] = ps[0] + ps[1] + tb[k];
}

__global__ void k_final(const float* __restrict__ TP, const float* __restrict__ Hist,
                        const float* nw1, const float* nb1, const float* nw2, const float* nb2,
                        const float* nw3, const float* nb3,
                        const float* hw1, const float* hb1, const float* hw2, const float* hb2,
                        const float* fw1, const float* fb1, const float* fw2, const float* fb2,
                        float* __restrict__ out) {
    int b = threadIdx.x;
    float h1[32];
    #pragma unroll
    for (int i = 0; i < 32; i++) {
        float a = nb1[i];
        for (int k = 0; k < 16; k++) a += TP[b * 16 + k] * nw1[i * 16 + k];
        h1[i] = fmaxf(a, 0.f);
    }
    float h2[16];
    #pragma unroll
    for (int j = 0; j < 16; j++) {
        float a = nb2[j];
        for (int i = 0; i < 32; i++) a += h1[i] * nw2[j * 32 + i];
        h2[j] = fmaxf(a, 0.f);
    }
    float nt = nb3[0];
    for (int j = 0; j < 16; j++) nt += h2[j] * nw3[j];
    nt = 1.f / (1.f + expf(-nt));
    float hh[16]; float sum = 0.f;
    for (int k = 0; k < 16; k++) { hh[k] = Hist[b * 16 + k]; sum += hh[k]; }
    float inv = 1.f / (sum + 1e-8f);
    for (int k = 0; k < 16; k++) hh[k] *= inv;
    float g1v[32];
    #pragma unroll
    for (int i = 0; i < 32; i++) {
        float a = hb1[i];
        for (int k = 0; k < 16; k++) a += hh[k] * hw1[i * 16 + k];
        g1v[i] = fmaxf(a, 0.f);
    }
    float hemb[16];
    #pragma unroll
    for (int j = 0; j < 16; j++) {
        float a = hb2[j];
        for (int i = 0; i < 32; i++) a += g1v[i] * hw2[j * 32 + i];
        hemb[j] = a;
    }
    float comb[17];
    comb[0] = nt;
    for (int j = 0; j < 16; j++) comb[1 + j] = hemb[j];
    float f1[8];
    #pragma unroll
    for (int i = 0; i < 8; i++) {
        float a = fb1[i];
        for (int j = 0; j < 17; j++) a += comb[j] * fw1[i * 17 + j];
        f1[i] = fmaxf(a, 0.f);
    }
    float o = fb2[0];
    for (int i = 0; i < 8; i++) o += f1[i] * fw2[i];
    out[b] = 1.f / (1.f + expf(-o));
}

extern "C" void kernel_launch(void* const* d_in, const int* in_sizes, int n_in,
                              void* d_out, int out_size, void* d_ws, size_t ws_size,
                              hipStream_t stream) {
    const float* x1    = (const float*)d_in[0];
    const float* x2    = (const float*)d_in[1];
    const int*   ei1   = (const int*)d_in[2];
    const int*   ei2   = (const int*)d_in[3];
    const float* gcn_w = (const float*)d_in[6];
    const float* gcn_b = (const float*)d_in[7];
    const float* bn_g  = (const float*)d_in[8];
    const float* bn_b  = (const float*)d_in[9];
    const float* bn_m  = (const float*)d_in[10];
    const float* bn_v  = (const float*)d_in[11];
    const float* ctx_w = (const float*)d_in[12];
    const float* ctx_b = (const float*)d_in[13];
    const float* att_w = (const float*)d_in[14];
    const float* att_b = (const float*)d_in[15];
    const float* ntn_T = (const float*)d_in[16];
    const float* ntn_b = (const float*)d_in[17];
    const float* nw1 = (const float*)d_in[18];
    const float* nb1 = (const float*)d_in[19];
    const float* nw2 = (const float*)d_in[20];
    const float* nb2 = (const float*)d_in[21];
    const float* nw3 = (const float*)d_in[22];
    const float* nb3 = (const float*)d_in[23];
    const float* hw1 = (const float*)d_in[24];
    const float* hb1 = (const float*)d_in[25];
    const float* hw2 = (const float*)d_in[26];
    const float* hb2 = (const float*)d_in[27];
    const float* fw1 = (const float*)d_in[28];
    const float* fb1 = (const float*)d_in[29];
    const float* fw2 = (const float*)d_in[30];
    const float* fb2 = (const float*)d_in[31];
    float* out = (float*)d_out;

    float* A1    = (float*)d_ws;
    float* A2    = A1 + NND;
    float* H     = A2 + NND;
    float* dinv  = H + NND;
    float* sbuf  = dinv + NN;
    float* g1    = sbuf + NN;
    float* g2    = g1 + BB * DD;
    float* hist  = g2 + BB * DD;
    float* tp    = hist + BB * NBINS;
    int*   degi  = (int*)(tp + BB * KNTN);
    int*   rowst = degi + NN;
    int*   curs  = rowst + NN + 1;
    int*   esrc  = curs + NN + 1;   // EE ints

    for (int side = 0; side < 2; ++side) {
        const float* X0 = side ? x2 : x1;
        float* A = side ? A2 : A1;
        const int* ei = side ? ei2 : ei1;

        // CSR build (by destination) + dinv
        hipMemsetAsync(degi, 0, NN * sizeof(int), stream);
        k_counti<<<EE / 256, 256, 0, stream>>>(ei + EE, degi);
        k_scan<<<1, 1024, 0, stream>>>(degi, rowst, curs);
        k_dinv<<<NN / 256, 256, 0, stream>>>(degi, dinv);
        k_fill_edges<<<EE / 256, 256, 0, stream>>>(ei, ei + EE, curs, esrc);

        for (int l = 0; l < LL; l++) {
            k_gemm<0><<<NN / 128, 512, 0, stream>>>(l == 0 ? X0 : A, gcn_w + (size_t)l * DD * DD, nullptr, H);
            k_aggregate<<<NN * 64 / 256, 256, 0, stream>>>(H, rowst, esrc, dinv,
                                                           gcn_b + l * DD, bn_g + l * DD,
                                                           bn_b + l * DD, bn_m + l * DD, bn_v + l * DD, A);
        }
        k_gemm<2><<<NN / 128, 512, 0, stream>>>(A, ctx_w, ctx_b, H);
        k_score<<<NN / 4, 256, 0, stream>>>(H, att_w, att_b, sbuf);
        k_pool<<<BB, 256, 0, stream>>>(sbuf, A, side ? g2 : g1);
    }

    hipMemsetAsync(hist, 0, BB * NBINS * sizeof(float), stream);
    k_hist<<<BB * 64, 256, 0, stream>>>(A1, A2, hist);
    k_ntn<<<dim3(BB, KNTN), 128, 0, stream>>>(g1, g2, ntn_T, ntn_b, tp);
    k_final<<<1, 64, 0, stream>>>(tp, hist, nw1, nb1, nw2, nb2, nw3, nb3,
                                  hw1, hb1, hw2, hb2, fw1, fb1, fw2, fb2, out);
}

// Round 3
// 831.157 us; speedup vs baseline: 7.1699x; 1.1997x over previous
//
#include <hip/hip_runtime.h>
#include <math.h>

#define NN 32768      // nodes total
#define BB 64         // graphs
#define NPG 512
#define DD 128
#define LL 3
#define EE 524288     // edges per side
#define NBINS 16
#define KNTN 16
#define NND (NN*DD)

typedef unsigned short ushort_t;
typedef __attribute__((ext_vector_type(8))) short short8;
typedef __attribute__((ext_vector_type(4))) float f32x4;

__device__ __forceinline__ ushort_t f2bf(float f) {
    unsigned u = __builtin_bit_cast(unsigned, f);
    u += 0x7FFFu + ((u >> 16) & 1u);
    return (ushort_t)(u >> 16);
}
__device__ __forceinline__ float bf2f(ushort_t h) {
    unsigned u = ((unsigned)h) << 16;
    return __builtin_bit_cast(float, u);
}
__device__ __forceinline__ unsigned pack2(float a, float b) {
    return (unsigned)f2bf(a) | ((unsigned)f2bf(b) << 16);
}

// ---------- CSR build ----------
__global__ void k_counti(const int* __restrict__ dst, int* __restrict__ deg) {
    int i = blockIdx.x * blockDim.x + threadIdx.x;
    atomicAdd(&deg[dst[i]], 1);
}

__global__ void k_dinv(const int* __restrict__ deg, float* __restrict__ dinv) {
    int i = blockIdx.x * blockDim.x + threadIdx.x;
    dinv[i] = rsqrtf((float)deg[i] + 1.0f);   // +1 = self-loop
}

__global__ __launch_bounds__(1024) void k_scan(const int* __restrict__ deg,
                                               int* __restrict__ rowstart,
                                               int* __restrict__ cursor) {
    __shared__ int part[1024];
    int t = threadIdx.x;
    int base = t * 32;
    int loc[32];
    int s = 0;
    #pragma unroll
    for (int i = 0; i < 32; i++) { loc[i] = s; s += deg[base + i]; }
    part[t] = s;
    __syncthreads();
    for (int o = 1; o < 1024; o <<= 1) {
        int v = (t >= o) ? part[t - o] : 0;
        __syncthreads();
        part[t] += v;
        __syncthreads();
    }
    int excl = (t == 0) ? 0 : part[t - 1];
    #pragma unroll
    for (int i = 0; i < 32; i++) {
        int v = excl + loc[i];
        rowstart[base + i] = v;
        cursor[base + i] = v;
    }
    if (t == 1023) rowstart[NN] = part[1023];
}

__global__ void k_fill_edges(const int* __restrict__ src, const int* __restrict__ dst,
                             int* __restrict__ cursor, int* __restrict__ esrc) {
    int e = blockIdx.x * blockDim.x + threadIdx.x;
    int s = src[e], d = dst[e];
    int slot = atomicAdd(&cursor[d], 1);
    esrc[slot] = s;
}

// ---------- fp32 -> bf16 convert ----------
__global__ void k_tobf16(const float* __restrict__ in, ushort_t* __restrict__ out, int n4) {
    int i = blockIdx.x * blockDim.x + threadIdx.x;
    if (i < n4) {
        float4 v = ((const float4*)in)[i];
        uint2 o;
        o.x = pack2(v.x, v.y);
        o.y = pack2(v.z, v.w);
        ((uint2*)out)[i] = o;
    }
}

// ---------- MFMA GEMM: Out[n][j] = sum_d X[n][d]*W[j][d]; EPI 0 plain, 2 bias+tanh ----------
template<int EPI>
__global__ __launch_bounds__(256) void k_mgemm(const ushort_t* __restrict__ X,
                                               const ushort_t* __restrict__ Wb,
                                               const float* __restrict__ bias,
                                               ushort_t* __restrict__ Out) {
    int w = threadIdx.x >> 6, l = threadIdx.x & 63;
    int rw = blockIdx.x * 64 + w * 16;     // this wave's 16 rows
    int lr = l & 15, lg = l >> 4;
    f32x4 acc[8];
    #pragma unroll
    for (int c = 0; c < 8; c++) acc[c] = (f32x4){0.f, 0.f, 0.f, 0.f};
    const ushort_t* xrow = X + (size_t)(rw + lr) * DD + lg * 8;
    const ushort_t* wrow = Wb + (size_t)lr * DD + lg * 8;
    for (int kt = 0; kt < 4; kt++) {
        short8 a = *(const short8*)(xrow + kt * 32);
        #pragma unroll
        for (int c = 0; c < 8; c++) {
            short8 b = *(const short8*)(wrow + (size_t)c * 16 * DD + kt * 32);
            acc[c] = __builtin_amdgcn_mfma_f32_16x16x32_bf16(a, b, acc[c], 0, 0, 0);
        }
    }
    #pragma unroll
    for (int c = 0; c < 8; c++) {
        int col = c * 16 + lr;
        float bv = (EPI >= 1) ? bias[col] : 0.f;
        #pragma unroll
        for (int q = 0; q < 4; q++) {
            int row = rw + lg * 4 + q;
            float v = acc[c][q];
            if (EPI >= 1) v += bv;
            if (EPI == 2) v = tanhf(v);
            Out[(size_t)row * DD + col] = f2bf(v);
        }
    }
}

// ---------- aggregate: A[n] = relu(BN(dinv[n]*(sum_in dinv[s]*H[s] + dinv[n]*H[n]) + gb)) ----------
__global__ __launch_bounds__(256) void k_agg(
    const ushort_t* __restrict__ H, const int* __restrict__ rowstart,
    const int* __restrict__ esrc, const float* __restrict__ dinv,
    const float* __restrict__ gb, const float* __restrict__ gam,
    const float* __restrict__ bet, const float* __restrict__ mean,
    const float* __restrict__ var, ushort_t* __restrict__ A) {
    int n = (blockIdx.x * blockDim.x + threadIdx.x) >> 6;
    int l = threadIdx.x & 63;
    int beg = rowstart[n], end = rowstart[n + 1];
    float di = dinv[n];
    unsigned h = ((const unsigned*)(H + (size_t)n * DD))[l];
    float acc0 = di * bf2f(h & 0xffff);
    float acc1 = di * bf2f(h >> 16);
    for (int j = beg; j < end; j++) {
        int s = esrc[j];
        float wgt = dinv[s];
        unsigned u = ((const unsigned*)(H + (size_t)s * DD))[l];
        acc0 += wgt * bf2f(u & 0xffff);
        acc1 += wgt * bf2f(u >> 16);
    }
    acc0 *= di; acc1 *= di;
    int c0 = 2 * l, c1 = 2 * l + 1;
    float o0 = (acc0 + gb[c0] - mean[c0]) * (gam[c0] * rsqrtf(var[c0] + 1e-5f)) + bet[c0];
    float o1 = (acc1 + gb[c1] - mean[c1]) * (gam[c1] * rsqrtf(var[c1] + 1e-5f)) + bet[c1];
    ((unsigned*)(A + (size_t)n * DD))[l] = pack2(fmaxf(o0, 0.f), fmaxf(o1, 0.f));
}

// ---------- attention score: S[n] = dot(T[n,:], aw) + ab ----------
__global__ void k_score(const ushort_t* __restrict__ T, const float* __restrict__ aw,
                        const float* __restrict__ ab, float* __restrict__ S) {
    int g = blockIdx.x * blockDim.x + threadIdx.x;
    int wid = g >> 6;
    int lane = threadIdx.x & 63;
    float acc = bf2f(T[(size_t)wid * DD + lane]) * aw[lane] +
                bf2f(T[(size_t)wid * DD + 64 + lane]) * aw[64 + lane];
    #pragma unroll
    for (int o = 32; o > 0; o >>= 1) acc += __shfl_down(acc, o);
    if (lane == 0) S[wid] = acc + ab[0];
}

// ---------- per-graph softmax + weighted sum ----------
__global__ __launch_bounds__(256) void k_pool(const float* __restrict__ S,
                                              const ushort_t* __restrict__ Emb,
                                              float* __restrict__ G) {
    int b = blockIdx.x;
    __shared__ float w[512];
    __shared__ float red[256];
    int t = threadIdx.x;
    float s0 = S[b * NPG + t], s1 = S[b * NPG + 256 + t];
    red[t] = fmaxf(s0, s1);
    __syncthreads();
    for (int o = 128; o > 0; o >>= 1) { if (t < o) red[t] = fmaxf(red[t], red[t + o]); __syncthreads(); }
    float mx = red[0];
    __syncthreads();
    float e0 = expf(s0 - mx), e1 = expf(s1 - mx);
    w[t] = e0; w[t + 256] = e1;
    red[t] = e0 + e1;
    __syncthreads();
    for (int o = 128; o > 0; o >>= 1) { if (t < o) red[t] += red[t + o]; __syncthreads(); }
    float inv = 1.0f / red[0];
    __syncthreads();
    int d = t & 127, half = t >> 7;
    float acc = 0.f;
    for (int n = half * 256; n < half * 256 + 256; n++)
        acc += w[n] * bf2f(Emb[((size_t)b * NPG + n) * DD + d]);
    red[t] = acc;
    __syncthreads();
    if (t < 128) G[b * DD + t] = (red[t] + red[t + 128]) * inv;
}

// ---------- row-normalize to bf16 ----------
__global__ __launch_bounds__(256) void k_norm(const ushort_t* __restrict__ A,
                                              ushort_t* __restrict__ Nrm) {
    int n = (blockIdx.x * blockDim.x + threadIdx.x) >> 6;
    int l = threadIdx.x & 63;
    unsigned u = ((const unsigned*)(A + (size_t)n * DD))[l];
    float a0 = bf2f(u & 0xffff), a1 = bf2f(u >> 16);
    float ss = a0 * a0 + a1 * a1;
    #pragma unroll
    for (int o = 32; o > 0; o >>= 1) ss += __shfl_xor(ss, o);
    float inv = 1.0f / fmaxf(sqrtf(ss), 1e-8f);
    ((unsigned*)(Nrm + (size_t)n * DD))[l] = pack2(a0 * inv, a1 * inv);
}

// ---------- MFMA cosine-sim histogram: block = 128x128 tile of one graph ----------
__global__ __launch_bounds__(256) void k_hist(const ushort_t* __restrict__ N1,
                                              const ushort_t* __restrict__ N2,
                                              float* __restrict__ Hist) {
    __shared__ int hl[256 * 17];
    __shared__ float hred[NBINS];
    int t = threadIdx.x, w = t >> 6, l = t & 63;
    int lr = l & 15, lg = l >> 4;
    int g = blockIdx.x >> 4, ti = (blockIdx.x >> 2) & 3, tj = blockIdx.x & 3;
    #pragma unroll
    for (int i = t; i < 256 * 17; i += 256) hl[i] = 0;
    if (t < NBINS) hred[t] = 0.f;
    __syncthreads();

    const ushort_t* arow = N1 + ((size_t)g * NPG + ti * 128 + w * 32 + lr) * DD + lg * 8;
    const ushort_t* brow = N2 + ((size_t)g * NPG + tj * 128 + lr) * DD + lg * 8;
    f32x4 acc[2][8];
    #pragma unroll
    for (int r = 0; r < 2; r++)
        #pragma unroll
        for (int c = 0; c < 8; c++) acc[r][c] = (f32x4){0.f, 0.f, 0.f, 0.f};
    for (int kt = 0; kt < 4; kt++) {
        short8 a0 = *(const short8*)(arow + kt * 32);
        short8 a1 = *(const short8*)(arow + (size_t)16 * DD + kt * 32);
        #pragma unroll
        for (int c = 0; c < 8; c++) {
            short8 b = *(const short8*)(brow + (size_t)c * 16 * DD + kt * 32);
            acc[0][c] = __builtin_amdgcn_mfma_f32_16x16x32_bf16(a0, b, acc[0][c], 0, 0, 0);
            acc[1][c] = __builtin_amdgcn_mfma_f32_16x16x32_bf16(a1, b, acc[1][c], 0, 0, 0);
        }
    }
    int base = t * 17;
    #pragma unroll
    for (int r = 0; r < 2; r++)
        #pragma unroll
        for (int c = 0; c < 8; c++)
            #pragma unroll
            for (int q = 0; q < 4; q++) {
                float sim = acc[r][c][q];
                float v = floorf((sim + 1.0f) * 8.0f);
                v = fminf(fmaxf(v, 0.f), 15.f);
                atomicAdd(&hl[base + (int)v], 1);   // private per-thread bins, ds_add
            }
    __syncthreads();
    // reduce 256x16 -> 16
    int bin = t & 15, r0 = (t >> 4) * 16;
    int s = 0;
    #pragma unroll
    for (int r = 0; r < 16; r++) s += hl[(r0 + r) * 17 + bin];
    atomicAdd(&hred[bin], (float)s);
    __syncthreads();
    if (t < NBINS) atomicAdd(&Hist[g * NBINS + t], hred[t]);
}

// ---------- NTN bilinear ----------
__global__ __launch_bounds__(128) void k_ntn(const float* __restrict__ G1,
                                             const float* __restrict__ G2,
                                             const float* __restrict__ T,
                                             const float* __restrict__ tb,
                                             float* __restrict__ TP) {
    int b = blockIdx.x, k = blockIdx.y;
    int e = threadIdx.x;
    const float* Tk = T + (size_t)k * DD * DD;
    float g2e = G2[b * DD + e];
    float acc = 0.f;
    for (int d = 0; d < DD; d++) acc += G1[b * DD + d] * Tk[(size_t)d * DD + e];
    float val = acc * g2e;
    #pragma unroll
    for (int o = 32; o > 0; o >>= 1) val += __shfl_down(val, o);
    __shared__ float ps[2];
    if ((e & 63) == 0) ps[e >> 6] = val;
    __syncthreads();
    if (e == 0) TP[b * KNTN + k] = ps[0] + ps[1] + tb[k];
}

__global__ void k_final(const float* __restrict__ TP, const float* __restrict__ Hist,
                        const float* nw1, const float* nb1, const float* nw2, const float* nb2,
                        const float* nw3, const float* nb3,
                        const float* hw1, const float* hb1, const float* hw2, const float* hb2,
                        const float* fw1, const float* fb1, const float* fw2, const float* fb2,
                        float* __restrict__ out) {
    int b = threadIdx.x;
    float h1[32];
    #pragma unroll
    for (int i = 0; i < 32; i++) {
        float a = nb1[i];
        for (int k = 0; k < 16; k++) a += TP[b * 16 + k] * nw1[i * 16 + k];
        h1[i] = fmaxf(a, 0.f);
    }
    float h2[16];
    #pragma unroll
    for (int j = 0; j < 16; j++) {
        float a = nb2[j];
        for (int i = 0; i < 32; i++) a += h1[i] * nw2[j * 32 + i];
        h2[j] = fmaxf(a, 0.f);
    }
    float nt = nb3[0];
    for (int j = 0; j < 16; j++) nt += h2[j] * nw3[j];
    nt = 1.f / (1.f + expf(-nt));
    float hh[16]; float sum = 0.f;
    for (int k = 0; k < 16; k++) { hh[k] = Hist[b * 16 + k]; sum += hh[k]; }
    float inv = 1.f / (sum + 1e-8f);
    for (int k = 0; k < 16; k++) hh[k] *= inv;
    float g1v[32];
    #pragma unroll
    for (int i = 0; i < 32; i++) {
        float a = hb1[i];
        for (int k = 0; k < 16; k++) a += hh[k] * hw1[i * 16 + k];
        g1v[i] = fmaxf(a, 0.f);
    }
    float hemb[16];
    #pragma unroll
    for (int j = 0; j < 16; j++) {
        float a = hb2[j];
        for (int i = 0; i < 32; i++) a += g1v[i] * hw2[j * 32 + i];
        hemb[j] = a;
    }
    float comb[17];
    comb[0] = nt;
    for (int j = 0; j < 16; j++) comb[1 + j] = hemb[j];
    float f1[8];
    #pragma unroll
    for (int i = 0; i < 8; i++) {
        float a = fb1[i];
        for (int j = 0; j < 17; j++) a += comb[j] * fw1[i * 17 + j];
        f1[i] = fmaxf(a, 0.f);
    }
    float o = fb2[0];
    for (int i = 0; i < 8; i++) o += f1[i] * fw2[i];
    out[b] = 1.f / (1.f + expf(-o));
}

extern "C" void kernel_launch(void* const* d_in, const int* in_sizes, int n_in,
                              void* d_out, int out_size, void* d_ws, size_t ws_size,
                              hipStream_t stream) {
    const float* x1    = (const float*)d_in[0];
    const float* x2    = (const float*)d_in[1];
    const int*   ei1   = (const int*)d_in[2];
    const int*   ei2   = (const int*)d_in[3];
    const float* gcn_w = (const float*)d_in[6];
    const float* gcn_b = (const float*)d_in[7];
    const float* bn_g  = (const float*)d_in[8];
    const float* bn_b  = (const float*)d_in[9];
    const float* bn_m  = (const float*)d_in[10];
    const float* bn_v  = (const float*)d_in[11];
    const float* ctx_w = (const float*)d_in[12];
    const float* ctx_b = (const float*)d_in[13];
    const float* att_w = (const float*)d_in[14];
    const float* att_b = (const float*)d_in[15];
    const float* ntn_T = (const float*)d_in[16];
    const float* ntn_b = (const float*)d_in[17];
    const float* nw1 = (const float*)d_in[18];
    const float* nb1 = (const float*)d_in[19];
    const float* nw2 = (const float*)d_in[20];
    const float* nb2 = (const float*)d_in[21];
    const float* nw3 = (const float*)d_in[22];
    const float* nb3 = (const float*)d_in[23];
    const float* hw1 = (const float*)d_in[24];
    const float* hb1 = (const float*)d_in[25];
    const float* hw2 = (const float*)d_in[26];
    const float* hb2 = (const float*)d_in[27];
    const float* fw1 = (const float*)d_in[28];
    const float* fb1 = (const float*)d_in[29];
    const float* fw2 = (const float*)d_in[30];
    const float* fb2 = (const float*)d_in[31];
    float* out = (float*)d_out;

    ushort_t* A1bf = (ushort_t*)d_ws;
    ushort_t* A2bf = A1bf + NND;
    ushort_t* xbf  = A2bf + NND;   // aliased as N1 after GCN
    ushort_t* habf = xbf + NND;    // aliased as N2 after GCN
    ushort_t* wbf  = habf + NND;   // (LL+1)*DD*DD bf16 weights
    float* fbase = (float*)(wbf + 4 * DD * DD);
    float* dinv = fbase;
    float* sbuf = dinv + NN;
    float* g1   = sbuf + NN;
    float* g2   = g1 + BB * DD;
    float* hist = g2 + BB * DD;
    float* tp   = hist + BB * NBINS;
    int* degi  = (int*)(tp + BB * KNTN);
    int* rowst = degi + NN;
    int* curs  = rowst + NN + 1;
    int* esrc  = curs + NN + 1;   // EE ints

    // convert weights to bf16 once
    k_tobf16<<<(LL * DD * DD / 4 + 255) / 256, 256, 0, stream>>>(gcn_w, wbf, LL * DD * DD / 4);
    k_tobf16<<<(DD * DD / 4 + 255) / 256, 256, 0, stream>>>(ctx_w, wbf + 3 * DD * DD, DD * DD / 4);

    for (int side = 0; side < 2; ++side) {
        const float* X0 = side ? x2 : x1;
        ushort_t* Abf = side ? A2bf : A1bf;
        const int* ei = side ? ei2 : ei1;

        hipMemsetAsync(degi, 0, NN * sizeof(int), stream);
        k_counti<<<EE / 256, 256, 0, stream>>>(ei + EE, degi);
        k_scan<<<1, 1024, 0, stream>>>(degi, rowst, curs);
        k_dinv<<<NN / 256, 256, 0, stream>>>(degi, dinv);
        k_fill_edges<<<EE / 256, 256, 0, stream>>>(ei, ei + EE, curs, esrc);
        k_tobf16<<<NND / 4 / 256, 256, 0, stream>>>(X0, xbf, NND / 4);

        for (int l = 0; l < LL; l++) {
            k_mgemm<0><<<NN / 64, 256, 0, stream>>>(l == 0 ? xbf : Abf, wbf + (size_t)l * DD * DD,
                                                    nullptr, habf);
            k_agg<<<NN / 4, 256, 0, stream>>>(habf, rowst, esrc, dinv,
                                              gcn_b + l * DD, bn_g + l * DD, bn_b + l * DD,
                                              bn_m + l * DD, bn_v + l * DD, Abf);
        }
        k_mgemm<2><<<NN / 64, 256, 0, stream>>>(Abf, wbf + 3 * DD * DD, ctx_b, habf);
        k_score<<<NN / 4, 256, 0, stream>>>(habf, att_w, att_b, sbuf);
        k_pool<<<BB, 256, 0, stream>>>(sbuf, Abf, side ? g2 : g1);
    }

    // normalized bf16 embeddings (alias dead buffers)
    k_norm<<<NN / 4, 256, 0, stream>>>(A1bf, xbf);    // N1
    k_norm<<<NN / 4, 256, 0, stream>>>(A2bf, habf);   // N2

    hipMemsetAsync(hist, 0, BB * NBINS * sizeof(float), stream);
    k_hist<<<BB * 16, 256, 0, stream>>>(xbf, habf, hist);
    k_ntn<<<dim3(BB, KNTN), 128, 0, stream>>>(g1, g2, ntn_T, ntn_b, tp);
    k_final<<<1, 64, 0, stream>>>(tp, hist, nw1, nb1, nw2, nb2, nw3, nb3,
                                  hw1, hb1, hw2, hb2, fw1, fb1, fw2, fb2, out);
}

// Round 4
// 659.784 us; speedup vs baseline: 9.0323x; 1.2597x over previous
//
#include <hip/hip_runtime.h>
#include <math.h>

#define NN 32768      // nodes per side
#define BB 64         // graphs per side
#define NPG 512
#define DD 128
#define LL 3
#define EE 524288     // edges per side
#define NBINS 16
#define KNTN 16
#define NND (NN*DD)

typedef unsigned short ushort_t;
typedef __attribute__((ext_vector_type(8))) short short8;
typedef __attribute__((ext_vector_type(4))) float f32x4;

__device__ __forceinline__ ushort_t f2bf(float f) {
    unsigned u = __builtin_bit_cast(unsigned, f);
    u += 0x7FFFu + ((u >> 16) & 1u);
    return (ushort_t)(u >> 16);
}
__device__ __forceinline__ float bf2f(ushort_t h) {
    unsigned u = ((unsigned)h) << 16;
    return __builtin_bit_cast(float, u);
}
__device__ __forceinline__ unsigned pack2(float a, float b) {
    return (unsigned)f2bf(a) | ((unsigned)f2bf(b) << 16);
}

// ---------- CSR build (both sides at once; side2 nodes offset by NN) ----------
__global__ void k_counti2(const int* __restrict__ d1, const int* __restrict__ d2,
                          int* __restrict__ deg) {
    int i = blockIdx.x * blockDim.x + threadIdx.x;   // 0..2EE
    int d = (i < EE) ? d1[i] : (d2[i - EE] + NN);
    atomicAdd(&deg[d], 1);
}

// single block: exclusive scan of deg[2NN] -> rowstart/cursor, plus dinv
__global__ __launch_bounds__(1024) void k_scan2(const int* __restrict__ deg,
                                                int* __restrict__ rowstart,
                                                int* __restrict__ cursor,
                                                float* __restrict__ dinv) {
    __shared__ int part[1024];
    int t = threadIdx.x;
    int base = t * 64;
    int s = 0;
    for (int i = 0; i < 64; i++) s += deg[base + i];
    part[t] = s;
    __syncthreads();
    for (int o = 1; o < 1024; o <<= 1) {
        int v = (t >= o) ? part[t - o] : 0;
        __syncthreads();
        part[t] += v;
        __syncthreads();
    }
    int run = (t == 0) ? 0 : part[t - 1];
    for (int i = 0; i < 64; i++) {
        int dg = deg[base + i];
        rowstart[base + i] = run;
        cursor[base + i] = run;
        dinv[base + i] = rsqrtf((float)dg + 1.0f);
        run += dg;
    }
    if (t == 1023) rowstart[2 * NN] = run;
}

__global__ void k_fill2(const int* __restrict__ ei1, const int* __restrict__ ei2,
                        int* __restrict__ cursor, int* __restrict__ esrc) {
    int e = blockIdx.x * blockDim.x + threadIdx.x;   // 0..2EE
    int s, d;
    if (e < EE) { s = ei1[e];            d = ei1[EE + e]; }
    else        { s = ei2[e - EE] + NN;  d = ei2[EE + e - EE] + NN; }
    int slot = atomicAdd(&cursor[d], 1);
    esrc[slot] = s;
}

// ---------- fp32 -> bf16 converts ----------
__global__ void k_xconv(const float* __restrict__ x1, const float* __restrict__ x2,
                        ushort_t* __restrict__ out) {
    int i = blockIdx.x * blockDim.x + threadIdx.x;   // per float4, 2*NND/4 total
    const float4 v = (i < NND / 4) ? ((const float4*)x1)[i] : ((const float4*)x2)[i - NND / 4];
    uint2 o;
    o.x = pack2(v.x, v.y);
    o.y = pack2(v.z, v.w);
    ((uint2*)out)[i] = o;
}

__global__ void k_wconv(const float* __restrict__ gw, const float* __restrict__ cw,
                        ushort_t* __restrict__ out) {
    int i = blockIdx.x * blockDim.x + threadIdx.x;   // per float4, 4*DD*DD/4 total
    const float4 v = (i < 3 * DD * DD / 4) ? ((const float4*)gw)[i]
                                           : ((const float4*)cw)[i - 3 * DD * DD / 4];
    uint2 o;
    o.x = pack2(v.x, v.y);
    o.y = pack2(v.z, v.w);
    ((uint2*)out)[i] = o;
}

// ---------- MFMA GEMM: Out[n][j] = sum_d X[n][d]*W[j][d] ----------
// EPI 0: plain bf16 out.  EPI 2: fused bias+tanh+attention-score -> Sout[n].
template<int EPI>
__global__ __launch_bounds__(256) void k_mgemm(const ushort_t* __restrict__ X,
                                               const ushort_t* __restrict__ Wb,
                                               const float* __restrict__ bias,
                                               ushort_t* __restrict__ Out,
                                               const float* __restrict__ aw,
                                               const float* __restrict__ ab,
                                               float* __restrict__ Sout) {
    int w = threadIdx.x >> 6, l = threadIdx.x & 63;
    int rw = blockIdx.x * 64 + w * 16;     // this wave's 16 rows
    int lr = l & 15, lg = l >> 4;
    f32x4 acc[8];
    #pragma unroll
    for (int c = 0; c < 8; c++) acc[c] = (f32x4){0.f, 0.f, 0.f, 0.f};
    const ushort_t* xrow = X + (size_t)(rw + lr) * DD + lg * 8;
    const ushort_t* wrow = Wb + (size_t)lr * DD + lg * 8;
    for (int kt = 0; kt < 4; kt++) {
        short8 a = *(const short8*)(xrow + kt * 32);
        #pragma unroll
        for (int c = 0; c < 8; c++) {
            short8 b = *(const short8*)(wrow + (size_t)c * 16 * DD + kt * 32);
            acc[c] = __builtin_amdgcn_mfma_f32_16x16x32_bf16(a, b, acc[c], 0, 0, 0);
        }
    }
    if (EPI == 0) {
        #pragma unroll
        for (int c = 0; c < 8; c++) {
            int col = c * 16 + lr;
            #pragma unroll
            for (int q = 0; q < 4; q++)
                Out[(size_t)(rw + lg * 4 + q) * DD + col] = f2bf(acc[c][q]);
        }
    } else {
        float rs0 = 0.f, rs1 = 0.f, rs2 = 0.f, rs3 = 0.f;
        #pragma unroll
        for (int c = 0; c < 8; c++) {
            int col = c * 16 + lr;
            float bv = bias[col], wv = aw[col];
            rs0 += tanhf(acc[c][0] + bv) * wv;
            rs1 += tanhf(acc[c][1] + bv) * wv;
            rs2 += tanhf(acc[c][2] + bv) * wv;
            rs3 += tanhf(acc[c][3] + bv) * wv;
        }
        #pragma unroll
        for (int m = 1; m < 16; m <<= 1) {
            rs0 += __shfl_xor(rs0, m);
            rs1 += __shfl_xor(rs1, m);
            rs2 += __shfl_xor(rs2, m);
            rs3 += __shfl_xor(rs3, m);
        }
        if (lr == 0) {
            float a0 = ab[0];
            Sout[rw + lg * 4 + 0] = rs0 + a0;
            Sout[rw + lg * 4 + 1] = rs1 + a0;
            Sout[rw + lg * 4 + 2] = rs2 + a0;
            Sout[rw + lg * 4 + 3] = rs3 + a0;
        }
    }
}

// ---------- aggregate: A[n] = relu(BN(dinv[n]*(sum_in dinv[s]*H[s] + dinv[n]*H[n]) + gb)) ----------
__global__ __launch_bounds__(256) void k_agg(
    const ushort_t* __restrict__ H, const int* __restrict__ rowstart,
    const int* __restrict__ esrc, const float* __restrict__ dinv,
    const float* __restrict__ gb, const float* __restrict__ gam,
    const float* __restrict__ bet, const float* __restrict__ mean,
    const float* __restrict__ var, ushort_t* __restrict__ A) {
    int n = (blockIdx.x * blockDim.x + threadIdx.x) >> 6;
    int l = threadIdx.x & 63;
    int beg = rowstart[n], end = rowstart[n + 1];
    float di = dinv[n];
    unsigned h = ((const unsigned*)(H + (size_t)n * DD))[l];
    float acc0 = di * bf2f(h & 0xffff);
    float acc1 = di * bf2f(h >> 16);
    for (int j = beg; j < end; j++) {
        int s = esrc[j];
        float wgt = dinv[s];
        unsigned u = ((const unsigned*)(H + (size_t)s * DD))[l];
        acc0 += wgt * bf2f(u & 0xffff);
        acc1 += wgt * bf2f(u >> 16);
    }
    acc0 *= di; acc1 *= di;
    int c0 = 2 * l, c1 = 2 * l + 1;
    float o0 = (acc0 + gb[c0] - mean[c0]) * (gam[c0] * rsqrtf(var[c0] + 1e-5f)) + bet[c0];
    float o1 = (acc1 + gb[c1] - mean[c1]) * (gam[c1] * rsqrtf(var[c1] + 1e-5f)) + bet[c1];
    ((unsigned*)(A + (size_t)n * DD))[l] = pack2(fmaxf(o0, 0.f), fmaxf(o1, 0.f));
}

// ---------- per-graph softmax weights: W[n] = exp(s-m)/Z ----------
__global__ __launch_bounds__(512) void k_smax(const float* __restrict__ S,
                                              float* __restrict__ W) {
    int b = blockIdx.x;       // 0..2*BB
    int t = threadIdx.x;
    __shared__ float red[512];
    float s = S[b * NPG + t];
    red[t] = s;
    __syncthreads();
    for (int o = 256; o > 0; o >>= 1) { if (t < o) red[t] = fmaxf(red[t], red[t + o]); __syncthreads(); }
    float m = red[0];
    __syncthreads();
    float e = expf(s - m);
    red[t] = e;
    __syncthreads();
    for (int o = 256; o > 0; o >>= 1) { if (t < o) red[t] += red[t + o]; __syncthreads(); }
    W[b * NPG + t] = e / red[0];
}

// ---------- weighted sum: G[b][:] += sum_n W[n]*Emb[n][:]  (8 chunk-blocks per graph) ----------
__global__ __launch_bounds__(256) void k_pool(const float* __restrict__ W,
                                              const ushort_t* __restrict__ Emb,
                                              float* __restrict__ G) {
    int blk = blockIdx.x;            // 2*BB*8
    int b = blk >> 3, ch = blk & 7;  // 64-node chunk
    int t = threadIdx.x;
    int l = t & 63, grp = t >> 6;    // 4 groups of 16 nodes
    int nbase = b * NPG + ch * 64 + grp * 16;
    float a0 = 0.f, a1 = 0.f;
    for (int i = 0; i < 16; i++) {
        float wv = W[nbase + i];
        unsigned u = ((const unsigned*)(Emb + (size_t)(nbase + i) * DD))[l];
        a0 += wv * bf2f(u & 0xffff);
        a1 += wv * bf2f(u >> 16);
    }
    __shared__ float red0[256], red1[256];
    red0[t] = a0; red1[t] = a1;
    __syncthreads();
    if (t < 64) {
        float s0 = red0[t] + red0[t + 64] + red0[t + 128] + red0[t + 192];
        float s1 = red1[t] + red1[t + 64] + red1[t + 128] + red1[t + 192];
        atomicAdd(&G[b * DD + 2 * t], s0);
        atomicAdd(&G[b * DD + 2 * t + 1], s1);
    }
}

// ---------- row-normalize to bf16 ----------
__global__ __launch_bounds__(256) void k_norm(const ushort_t* __restrict__ A,
                                              ushort_t* __restrict__ Nrm) {
    int n = (blockIdx.x * blockDim.x + threadIdx.x) >> 6;
    int l = threadIdx.x & 63;
    unsigned u = ((const unsigned*)(A + (size_t)n * DD))[l];
    float a0 = bf2f(u & 0xffff), a1 = bf2f(u >> 16);
    float ss = a0 * a0 + a1 * a1;
    #pragma unroll
    for (int o = 32; o > 0; o >>= 1) ss += __shfl_xor(ss, o);
    float inv = 1.0f / fmaxf(sqrtf(ss), 1e-8f);
    ((unsigned*)(Nrm + (size_t)n * DD))[l] = pack2(a0 * inv, a1 * inv);
}

// ---------- MFMA cosine-sim histogram: block = 128x128 tile of one graph ----------
__global__ __launch_bounds__(256) void k_hist(const ushort_t* __restrict__ N1,
                                              const ushort_t* __restrict__ N2,
                                              float* __restrict__ Hist) {
    __shared__ int hl[256 * 17];
    __shared__ float hred[NBINS];
    int t = threadIdx.x, w = t >> 6, l = t & 63;
    int lr = l & 15, lg = l >> 4;
    int g = blockIdx.x >> 4, ti = (blockIdx.x >> 2) & 3, tj = blockIdx.x & 3;
    #pragma unroll
    for (int i = t; i < 256 * 17; i += 256) hl[i] = 0;
    if (t < NBINS) hred[t] = 0.f;
    __syncthreads();

    const ushort_t* arow = N1 + ((size_t)g * NPG + ti * 128 + w * 32 + lr) * DD + lg * 8;
    const ushort_t* brow = N2 + ((size_t)g * NPG + tj * 128 + lr) * DD + lg * 8;
    f32x4 acc[2][8];
    #pragma unroll
    for (int r = 0; r < 2; r++)
        #pragma unroll
        for (int c = 0; c < 8; c++) acc[r][c] = (f32x4){0.f, 0.f, 0.f, 0.f};
    for (int kt = 0; kt < 4; kt++) {
        short8 a0 = *(const short8*)(arow + kt * 32);
        short8 a1 = *(const short8*)(arow + (size_t)16 * DD + kt * 32);
        #pragma unroll
        for (int c = 0; c < 8; c++) {
            short8 b = *(const short8*)(brow + (size_t)c * 16 * DD + kt * 32);
            acc[0][c] = __builtin_amdgcn_mfma_f32_16x16x32_bf16(a0, b, acc[0][c], 0, 0, 0);
            acc[1][c] = __builtin_amdgcn_mfma_f32_16x16x32_bf16(a1, b, acc[1][c], 0, 0, 0);
        }
    }
    int base = t * 17;
    #pragma unroll
    for (int r = 0; r < 2; r++)
        #pragma unroll
        for (int c = 0; c < 8; c++)
            #pragma unroll
            for (int q = 0; q < 4; q++) {
                float sim = acc[r][c][q];
                float v = floorf((sim + 1.0f) * 8.0f);
                v = fminf(fmaxf(v, 0.f), 15.f);
                atomicAdd(&hl[base + (int)v], 1);   // private per-thread bins
            }
    __syncthreads();
    int bin = t & 15, r0 = (t >> 4) * 16;
    int s = 0;
    #pragma unroll
    for (int r = 0; r < 16; r++) s += hl[(r0 + r) * 17 + bin];
    atomicAdd(&hred[bin], (float)s);
    __syncthreads();
    if (t < NBINS) atomicAdd(&Hist[g * NBINS + t], hred[t]);
}

// ---------- NTN bilinear ----------
__global__ __launch_bounds__(128) void k_ntn(const float* __restrict__ G1,
                                             const float* __restrict__ G2,
                                             const float* __restrict__ T,
                                             const float* __restrict__ tb,
                                             float* __restrict__ TP) {
    int b = blockIdx.x, k = blockIdx.y;
    int e = threadIdx.x;
    const float* Tk = T + (size_t)k * DD * DD;
    float g2e = G2[b * DD + e];
    float acc = 0.f;
    for (int d = 0; d < DD; d++) acc += G1[b * DD + d] * Tk[(size_t)d * DD + e];
    float val = acc * g2e;
    #pragma unroll
    for (int o = 32; o > 0; o >>= 1) val += __shfl_down(val, o);
    __shared__ float ps[2];
    if ((e & 63) == 0) ps[e >> 6] = val;
    __syncthreads();
    if (e == 0) TP[b * KNTN + k] = ps[0] + ps[1] + tb[k];
}

__global__ void k_final(const float* __restrict__ TP, const float* __restrict__ Hist,
                        const float* nw1, const float* nb1, const float* nw2, const float* nb2,
                        const float* nw3, const float* nb3,
                        const float* hw1, const float* hb1, const float* hw2, const float* hb2,
                        const float* fw1, const float* fb1, const float* fw2, const float* fb2,
                        float* __restrict__ out) {
    int b = threadIdx.x;
    float h1[32];
    #pragma unroll
    for (int i = 0; i < 32; i++) {
        float a = nb1[i];
        for (int k = 0; k < 16; k++) a += TP[b * 16 + k] * nw1[i * 16 + k];
        h1[i] = fmaxf(a, 0.f);
    }
    float h2[16];
    #pragma unroll
    for (int j = 0; j < 16; j++) {
        float a = nb2[j];
        for (int i = 0; i < 32; i++) a += h1[i] * nw2[j * 32 + i];
        h2[j] = fmaxf(a, 0.f);
    }
    float nt = nb3[0];
    for (int j = 0; j < 16; j++) nt += h2[j] * nw3[j];
    nt = 1.f / (1.f + expf(-nt));
    float hh[16]; float sum = 0.f;
    for (int k = 0; k < 16; k++) { hh[k] = Hist[b * 16 + k]; sum += hh[k]; }
    float inv = 1.f / (sum + 1e-8f);
    for (int k = 0; k < 16; k++) hh[k] *= inv;
    float g1v[32];
    #pragma unroll
    for (int i = 0; i < 32; i++) {
        float a = hb1[i];
        for (int k = 0; k < 16; k++) a += hh[k] * hw1[i * 16 + k];
        g1v[i] = fmaxf(a, 0.f);
    }
    float hemb[16];
    #pragma unroll
    for (int j = 0; j < 16; j++) {
        float a = hb2[j];
        for (int i = 0; i < 32; i++) a += g1v[i] * hw2[j * 32 + i];
        hemb[j] = a;
    }
    float comb[17];
    comb[0] = nt;
    for (int j = 0; j < 16; j++) comb[1 + j] = hemb[j];
    float f1[8];
    #pragma unroll
    for (int i = 0; i < 8; i++) {
        float a = fb1[i];
        for (int j = 0; j < 17; j++) a += comb[j] * fw1[i * 17 + j];
        f1[i] = fmaxf(a, 0.f);
    }
    float o = fb2[0];
    for (int i = 0; i < 8; i++) o += f1[i] * fw2[i];
    out[b] = 1.f / (1.f + expf(-o));
}

extern "C" void kernel_launch(void* const* d_in, const int* in_sizes, int n_in,
                              void* d_out, int out_size, void* d_ws, size_t ws_size,
                              hipStream_t stream) {
    const float* x1    = (const float*)d_in[0];
    const float* x2    = (const float*)d_in[1];
    const int*   ei1   = (const int*)d_in[2];
    const int*   ei2   = (const int*)d_in[3];
    const float* gcn_w = (const float*)d_in[6];
    const float* gcn_b = (const float*)d_in[7];
    const float* bn_g  = (const float*)d_in[8];
    const float* bn_b  = (const float*)d_in[9];
    const float* bn_m  = (const float*)d_in[10];
    const float* bn_v  = (const float*)d_in[11];
    const float* ctx_b = (const float*)d_in[13];
    const float* att_w = (const float*)d_in[14];
    const float* att_b = (const float*)d_in[15];
    const float* ntn_T = (const float*)d_in[16];
    const float* ntn_b = (const float*)d_in[17];
    const float* nw1 = (const float*)d_in[18];
    const float* nb1 = (const float*)d_in[19];
    const float* nw2 = (const float*)d_in[20];
    const float* nb2 = (const float*)d_in[21];
    const float* nw3 = (const float*)d_in[22];
    const float* nb3 = (const float*)d_in[23];
    const float* hw1 = (const float*)d_in[24];
    const float* hb1 = (const float*)d_in[25];
    const float* hw2 = (const float*)d_in[26];
    const float* hb2 = (const float*)d_in[27];
    const float* fw1 = (const float*)d_in[28];
    const float* fb1 = (const float*)d_in[29];
    const float* fw2 = (const float*)d_in[30];
    const float* fb2 = (const float*)d_in[31];
    float* out = (float*)d_out;

    ushort_t* Xbf = (ushort_t*)d_ws;        // 2*NND (also reused as Nrm)
    ushort_t* Abf = Xbf + 2 * (size_t)NND;  // 2*NND
    ushort_t* Hbf = Abf + 2 * (size_t)NND;  // 2*NND
    ushort_t* wbf = Hbf + 2 * (size_t)NND;  // 4*DD*DD
    float* dinv = (float*)(wbf + 4 * DD * DD);  // 2*NN
    float* S    = dinv + 2 * NN;                // 2*NN
    float* Wsm  = S + 2 * NN;                   // 2*NN
    float* G    = Wsm + 2 * NN;                 // 2*BB*DD
    float* hist = G + 2 * BB * DD;              // BB*NBINS
    float* tp   = hist + BB * NBINS;            // BB*KNTN
    int* degi  = (int*)(tp + BB * KNTN);        // 2*NN
    int* rowst = degi + 2 * NN;                 // 2*NN+1
    int* curs  = rowst + 2 * NN + 1;            // 2*NN
    int* esrc  = curs + 2 * NN;                 // 2*EE

    k_wconv<<<4 * DD * DD / 4 / 256, 256, 0, stream>>>(gcn_w, (const float*)d_in[12], wbf);
    hipMemsetAsync(degi, 0, 2 * NN * sizeof(int), stream);
    hipMemsetAsync(G, 0, (2 * BB * DD + BB * NBINS) * sizeof(float), stream);
    k_counti2<<<2 * EE / 256, 256, 0, stream>>>(ei1 + EE, ei2 + EE, degi);
    k_scan2<<<1, 1024, 0, stream>>>(degi, rowst, curs, dinv);
    k_fill2<<<2 * EE / 256, 256, 0, stream>>>(ei1, ei2, curs, esrc);
    k_xconv<<<2 * NND / 4 / 256, 256, 0, stream>>>(x1, x2, Xbf);

    for (int l = 0; l < LL; l++) {
        k_mgemm<0><<<2 * NN / 64, 256, 0, stream>>>(l == 0 ? Xbf : Abf,
                                                    wbf + (size_t)l * DD * DD,
                                                    nullptr, Hbf, nullptr, nullptr, nullptr);
        k_agg<<<2 * NN / 4, 256, 0, stream>>>(Hbf, rowst, esrc, dinv,
                                              gcn_b + l * DD, bn_g + l * DD, bn_b + l * DD,
                                              bn_m + l * DD, bn_v + l * DD, Abf);
    }
    k_mgemm<2><<<2 * NN / 64, 256, 0, stream>>>(Abf, wbf + 3 * DD * DD, ctx_b,
                                                nullptr, att_w, att_b, S);
    k_smax<<<2 * BB, 512, 0, stream>>>(S, Wsm);
    k_pool<<<2 * BB * 8, 256, 0, stream>>>(Wsm, Abf, G);
    k_norm<<<2 * NN / 4, 256, 0, stream>>>(Abf, Xbf);
    k_hist<<<BB * 16, 256, 0, stream>>>(Xbf, Xbf + NND, hist);
    k_ntn<<<dim3(BB, KNTN), 128, 0, stream>>>(G, G + BB * DD, ntn_T, ntn_b, tp);
    k_final<<<1, 64, 0, stream>>>(tp, hist, nw1, nb1, nw2, nb2, nw3, nb3,
                                  hw1, hb1, hw2, hb2, fw1, fb1, fw2, fb2, out);
}

// Round 5
// 482.299 us; speedup vs baseline: 12.3561x; 1.3680x over previous
//
#include <hip/hip_runtime.h>
#include <math.h>

#define NN 32768      // nodes per side
#define BB 64         // graphs per side
#define NPG 512
#define DD 128
#define LL 3
#define EE 524288     // edges per side
#define NBINS 16
#define KNTN 16
#define NND (NN*DD)

typedef unsigned short ushort_t;
typedef __attribute__((ext_vector_type(8))) short short8;
typedef __attribute__((ext_vector_type(4))) float f32x4;

__device__ __forceinline__ ushort_t f2bf(float f) {
    unsigned u = __builtin_bit_cast(unsigned, f);
    u += 0x7FFFu + ((u >> 16) & 1u);
    return (ushort_t)(u >> 16);
}
__device__ __forceinline__ float bf2f(ushort_t h) {
    unsigned u = ((unsigned)h) << 16;
    return __builtin_bit_cast(float, u);
}
__device__ __forceinline__ unsigned pack2(float a, float b) {
    return (unsigned)f2bf(a) | ((unsigned)f2bf(b) << 16);
}
__device__ __forceinline__ float lo16(unsigned u) { return __builtin_bit_cast(float, u << 16); }
__device__ __forceinline__ float hi16(unsigned u) { return __builtin_bit_cast(float, u & 0xffff0000u); }

// ---------- CSR build (both sides at once; side2 nodes offset by NN) ----------
__global__ void k_counti2(const int* __restrict__ d1, const int* __restrict__ d2,
                          int* __restrict__ deg) {
    int i = blockIdx.x * blockDim.x + threadIdx.x;   // 0..2EE
    int d = (i < EE) ? d1[i] : (d2[i - EE] + NN);
    atomicAdd(&deg[d], 1);
}

// single block: exclusive scan of deg[2NN] -> rowstart/cursor, plus dinv
__global__ __launch_bounds__(1024) void k_scan2(const int* __restrict__ deg,
                                                int* __restrict__ rowstart,
                                                int* __restrict__ cursor,
                                                float* __restrict__ dinv) {
    __shared__ int part[1024];
    int t = threadIdx.x;
    int base = t * 64;
    int s = 0;
    for (int i = 0; i < 64; i++) s += deg[base + i];
    part[t] = s;
    __syncthreads();
    for (int o = 1; o < 1024; o <<= 1) {
        int v = (t >= o) ? part[t - o] : 0;
        __syncthreads();
        part[t] += v;
        __syncthreads();
    }
    int run = (t == 0) ? 0 : part[t - 1];
    for (int i = 0; i < 64; i++) {
        int dg = deg[base + i];
        rowstart[base + i] = run;
        cursor[base + i] = run;
        dinv[base + i] = rsqrtf((float)dg + 1.0f);
        run += dg;
    }
    if (t == 1023) rowstart[2 * NN] = run;
}

__global__ void k_fill2(const int* __restrict__ ei1, const int* __restrict__ ei2,
                        int* __restrict__ cursor, int* __restrict__ esrc) {
    int e = blockIdx.x * blockDim.x + threadIdx.x;   // 0..2EE
    int s, d;
    if (e < EE) { s = ei1[e];            d = ei1[EE + e]; }
    else        { s = ei2[e - EE] + NN;  d = ei2[EE + e - EE] + NN; }
    int slot = atomicAdd(&cursor[d], 1);
    esrc[slot] = s;
}

// ---------- fp32 -> bf16 converts ----------
__global__ void k_xconv(const float* __restrict__ x1, const float* __restrict__ x2,
                        ushort_t* __restrict__ out) {
    int i = blockIdx.x * blockDim.x + threadIdx.x;   // per float4, 2*NND/4 total
    const float4 v = (i < NND / 4) ? ((const float4*)x1)[i] : ((const float4*)x2)[i - NND / 4];
    uint2 o;
    o.x = pack2(v.x, v.y);
    o.y = pack2(v.z, v.w);
    ((uint2*)out)[i] = o;
}

__global__ void k_wconv(const float* __restrict__ gw, const float* __restrict__ cw,
                        ushort_t* __restrict__ out) {
    int i = blockIdx.x * blockDim.x + threadIdx.x;   // per float4, 4*DD*DD/4 total
    const float4 v = (i < 3 * DD * DD / 4) ? ((const float4*)gw)[i]
                                           : ((const float4*)cw)[i - 3 * DD * DD / 4];
    uint2 o;
    o.x = pack2(v.x, v.y);
    o.y = pack2(v.z, v.w);
    ((uint2*)out)[i] = o;
}

// ---------- MFMA GEMM: Out[n][j] = sum_d X[n][d]*W[j][d] ----------
// EPI 0: bf16 out scaled by dscale[row] (pre-scale for aggregation).
// EPI 2: fused bias+tanh+attention-score -> Sout[n].
template<int EPI>
__global__ __launch_bounds__(256) void k_mgemm(const ushort_t* __restrict__ X,
                                               const ushort_t* __restrict__ Wb,
                                               const float* __restrict__ bias,
                                               ushort_t* __restrict__ Out,
                                               const float* __restrict__ aw,
                                               const float* __restrict__ ab,
                                               float* __restrict__ Sout,
                                               const float* __restrict__ dscale) {
    int w = threadIdx.x >> 6, l = threadIdx.x & 63;
    int rw = blockIdx.x * 64 + w * 16;     // this wave's 16 rows
    int lr = l & 15, lg = l >> 4;
    f32x4 acc[8];
    #pragma unroll
    for (int c = 0; c < 8; c++) acc[c] = (f32x4){0.f, 0.f, 0.f, 0.f};
    const ushort_t* xrow = X + (size_t)(rw + lr) * DD + lg * 8;
    const ushort_t* wrow = Wb + (size_t)lr * DD + lg * 8;
    for (int kt = 0; kt < 4; kt++) {
        short8 a = *(const short8*)(xrow + kt * 32);
        #pragma unroll
        for (int c = 0; c < 8; c++) {
            short8 b = *(const short8*)(wrow + (size_t)c * 16 * DD + kt * 32);
            acc[c] = __builtin_amdgcn_mfma_f32_16x16x32_bf16(a, b, acc[c], 0, 0, 0);
        }
    }
    if (EPI == 0) {
        float ds[4];
        #pragma unroll
        for (int q = 0; q < 4; q++) ds[q] = dscale[rw + lg * 4 + q];
        #pragma unroll
        for (int c = 0; c < 8; c++) {
            int col = c * 16 + lr;
            #pragma unroll
            for (int q = 0; q < 4; q++)
                Out[(size_t)(rw + lg * 4 + q) * DD + col] = f2bf(acc[c][q] * ds[q]);
        }
    } else {
        float rs0 = 0.f, rs1 = 0.f, rs2 = 0.f, rs3 = 0.f;
        #pragma unroll
        for (int c = 0; c < 8; c++) {
            int col = c * 16 + lr;
            float bv = bias[col], wv = aw[col];
            rs0 += tanhf(acc[c][0] + bv) * wv;
            rs1 += tanhf(acc[c][1] + bv) * wv;
            rs2 += tanhf(acc[c][2] + bv) * wv;
            rs3 += tanhf(acc[c][3] + bv) * wv;
        }
        #pragma unroll
        for (int m = 1; m < 16; m <<= 1) {
            rs0 += __shfl_xor(rs0, m);
            rs1 += __shfl_xor(rs1, m);
            rs2 += __shfl_xor(rs2, m);
            rs3 += __shfl_xor(rs3, m);
        }
        if (lr == 0) {
            float a0 = ab[0];
            Sout[rw + lg * 4 + 0] = rs0 + a0;
            Sout[rw + lg * 4 + 1] = rs1 + a0;
            Sout[rw + lg * 4 + 2] = rs2 + a0;
            Sout[rw + lg * 4 + 3] = rs3 + a0;
        }
    }
}

// ---------- aggregate over pre-scaled rows Hs[s]=dinv[s]*H[s]:
// A[n] = relu(BN( dinv[n]*(sum_in Hs[s] + Hs[n]) + gb ))
__global__ __launch_bounds__(256) void k_agg(
    const ushort_t* __restrict__ Hs, const int* __restrict__ rowstart,
    const int* __restrict__ esrc, const float* __restrict__ dinv,
    const float* __restrict__ gb, const float* __restrict__ gam,
    const float* __restrict__ bet, const float* __restrict__ mean,
    const float* __restrict__ var, ushort_t* __restrict__ A) {
    int n = (blockIdx.x * blockDim.x + threadIdx.x) >> 6;
    int l = threadIdx.x & 63;
    int beg = rowstart[n], end = rowstart[n + 1];
    float di = dinv[n];
    const unsigned* Hu = (const unsigned*)Hs;
    unsigned h = Hu[(size_t)n * 64 + l];
    float acc0 = lo16(h), acc1 = hi16(h);
    int j = beg;
    // 8-wide: 8 independent gathers in flight
    for (; j + 8 <= end; j += 8) {
        int s0 = esrc[j + 0], s1 = esrc[j + 1], s2 = esrc[j + 2], s3 = esrc[j + 3];
        int s4 = esrc[j + 4], s5 = esrc[j + 5], s6 = esrc[j + 6], s7 = esrc[j + 7];
        unsigned u0 = Hu[(size_t)s0 * 64 + l];
        unsigned u1 = Hu[(size_t)s1 * 64 + l];
        unsigned u2 = Hu[(size_t)s2 * 64 + l];
        unsigned u3 = Hu[(size_t)s3 * 64 + l];
        unsigned u4 = Hu[(size_t)s4 * 64 + l];
        unsigned u5 = Hu[(size_t)s5 * 64 + l];
        unsigned u6 = Hu[(size_t)s6 * 64 + l];
        unsigned u7 = Hu[(size_t)s7 * 64 + l];
        acc0 += ((lo16(u0) + lo16(u1)) + (lo16(u2) + lo16(u3))) +
                ((lo16(u4) + lo16(u5)) + (lo16(u6) + lo16(u7)));
        acc1 += ((hi16(u0) + hi16(u1)) + (hi16(u2) + hi16(u3))) +
                ((hi16(u4) + hi16(u5)) + (hi16(u6) + hi16(u7)));
    }
    if (j + 4 <= end) {
        int s0 = esrc[j + 0], s1 = esrc[j + 1], s2 = esrc[j + 2], s3 = esrc[j + 3];
        unsigned u0 = Hu[(size_t)s0 * 64 + l];
        unsigned u1 = Hu[(size_t)s1 * 64 + l];
        unsigned u2 = Hu[(size_t)s2 * 64 + l];
        unsigned u3 = Hu[(size_t)s3 * 64 + l];
        acc0 += (lo16(u0) + lo16(u1)) + (lo16(u2) + lo16(u3));
        acc1 += (hi16(u0) + hi16(u1)) + (hi16(u2) + hi16(u3));
        j += 4;
    }
    for (; j < end; j++) {
        unsigned u = Hu[(size_t)esrc[j] * 64 + l];
        acc0 += lo16(u);
        acc1 += hi16(u);
    }
    acc0 *= di; acc1 *= di;
    int c0 = 2 * l, c1 = 2 * l + 1;
    float o0 = (acc0 + gb[c0] - mean[c0]) * (gam[c0] * rsqrtf(var[c0] + 1e-5f)) + bet[c0];
    float o1 = (acc1 + gb[c1] - mean[c1]) * (gam[c1] * rsqrtf(var[c1] + 1e-5f)) + bet[c1];
    ((unsigned*)(A + (size_t)n * DD))[l] = pack2(fmaxf(o0, 0.f), fmaxf(o1, 0.f));
}

// ---------- per-graph softmax weights: W[n] = exp(s-m)/Z ----------
__global__ __launch_bounds__(512) void k_smax(const float* __restrict__ S,
                                              float* __restrict__ W) {
    int b = blockIdx.x;       // 0..2*BB
    int t = threadIdx.x;
    __shared__ float red[512];
    float s = S[b * NPG + t];
    red[t] = s;
    __syncthreads();
    for (int o = 256; o > 0; o >>= 1) { if (t < o) red[t] = fmaxf(red[t], red[t + o]); __syncthreads(); }
    float m = red[0];
    __syncthreads();
    float e = expf(s - m);
    red[t] = e;
    __syncthreads();
    for (int o = 256; o > 0; o >>= 1) { if (t < o) red[t] += red[t + o]; __syncthreads(); }
    W[b * NPG + t] = e / red[0];
}

// ---------- weighted sum: G[b][:] += sum_n W[n]*Emb[n][:]  (8 chunk-blocks per graph) ----------
__global__ __launch_bounds__(256) void k_pool(const float* __restrict__ W,
                                              const ushort_t* __restrict__ Emb,
                                              float* __restrict__ G) {
    int blk = blockIdx.x;            // 2*BB*8
    int b = blk >> 3, ch = blk & 7;  // 64-node chunk
    int t = threadIdx.x;
    int l = t & 63, grp = t >> 6;    // 4 groups of 16 nodes
    int nbase = b * NPG + ch * 64 + grp * 16;
    float a0 = 0.f, a1 = 0.f;
    for (int i = 0; i < 16; i++) {
        float wv = W[nbase + i];
        unsigned u = ((const unsigned*)(Emb + (size_t)(nbase + i) * DD))[l];
        a0 += wv * lo16(u);
        a1 += wv * hi16(u);
    }
    __shared__ float red0[256], red1[256];
    red0[t] = a0; red1[t] = a1;
    __syncthreads();
    if (t < 64) {
        float s0 = red0[t] + red0[t + 64] + red0[t + 128] + red0[t + 192];
        float s1 = red1[t] + red1[t + 64] + red1[t + 128] + red1[t + 192];
        atomicAdd(&G[b * DD + 2 * t], s0);
        atomicAdd(&G[b * DD + 2 * t + 1], s1);
    }
}

// ---------- row-normalize to bf16 ----------
__global__ __launch_bounds__(256) void k_norm(const ushort_t* __restrict__ A,
                                              ushort_t* __restrict__ Nrm) {
    int n = (blockIdx.x * blockDim.x + threadIdx.x) >> 6;
    int l = threadIdx.x & 63;
    unsigned u = ((const unsigned*)(A + (size_t)n * DD))[l];
    float a0 = lo16(u), a1 = hi16(u);
    float ss = a0 * a0 + a1 * a1;
    #pragma unroll
    for (int o = 32; o > 0; o >>= 1) ss += __shfl_xor(ss, o);
    float inv = 1.0f / fmaxf(sqrtf(ss), 1e-8f);
    ((unsigned*)(Nrm + (size_t)n * DD))[l] = pack2(a0 * inv, a1 * inv);
}

// ---------- MFMA cosine-sim histogram: block = 128x128 tile of one graph ----------
__global__ __launch_bounds__(256) void k_hist(const ushort_t* __restrict__ N1,
                                              const ushort_t* __restrict__ N2,
                                              float* __restrict__ Hist) {
    __shared__ int hl[256 * 17];
    __shared__ float hred[NBINS];
    int t = threadIdx.x, w = t >> 6, l = t & 63;
    int lr = l & 15, lg = l >> 4;
    int g = blockIdx.x >> 4, ti = (blockIdx.x >> 2) & 3, tj = blockIdx.x & 3;
    #pragma unroll
    for (int i = t; i < 256 * 17; i += 256) hl[i] = 0;
    if (t < NBINS) hred[t] = 0.f;
    __syncthreads();

    const ushort_t* arow = N1 + ((size_t)g * NPG + ti * 128 + w * 32 + lr) * DD + lg * 8;
    const ushort_t* brow = N2 + ((size_t)g * NPG + tj * 128 + lr) * DD + lg * 8;
    f32x4 acc[2][8];
    #pragma unroll
    for (int r = 0; r < 2; r++)
        #pragma unroll
        for (int c = 0; c < 8; c++) acc[r][c] = (f32x4){0.f, 0.f, 0.f, 0.f};
    for (int kt = 0; kt < 4; kt++) {
        short8 a0 = *(const short8*)(arow + kt * 32);
        short8 a1 = *(const short8*)(arow + (size_t)16 * DD + kt * 32);
        #pragma unroll
        for (int c = 0; c < 8; c++) {
            short8 b = *(const short8*)(brow + (size_t)c * 16 * DD + kt * 32);
            acc[0][c] = __builtin_amdgcn_mfma_f32_16x16x32_bf16(a0, b, acc[0][c], 0, 0, 0);
            acc[1][c] = __builtin_amdgcn_mfma_f32_16x16x32_bf16(a1, b, acc[1][c], 0, 0, 0);
        }
    }
    int base = t * 17;
    #pragma unroll
    for (int r = 0; r < 2; r++)
        #pragma unroll
        for (int c = 0; c < 8; c++)
            #pragma unroll
            for (int q = 0; q < 4; q++) {
                float sim = acc[r][c][q];
                float v = floorf((sim + 1.0f) * 8.0f);
                v = fminf(fmaxf(v, 0.f), 15.f);
                atomicAdd(&hl[base + (int)v], 1);   // private per-thread bins
            }
    __syncthreads();
    int bin = t & 15, r0 = (t >> 4) * 16;
    int s = 0;
    #pragma unroll
    for (int r = 0; r < 16; r++) s += hl[(r0 + r) * 17 + bin];
    atomicAdd(&hred[bin], (float)s);
    __syncthreads();
    if (t < NBINS) atomicAdd(&Hist[g * NBINS + t], hred[t]);
}

// ---------- NTN bilinear ----------
__global__ __launch_bounds__(128) void k_ntn(const float* __restrict__ G1,
                                             const float* __restrict__ G2,
                                             const float* __restrict__ T,
                                             const float* __restrict__ tb,
                                             float* __restrict__ TP) {
    int b = blockIdx.x, k = blockIdx.y;
    int e = threadIdx.x;
    const float* Tk = T + (size_t)k * DD * DD;
    float g2e = G2[b * DD + e];
    float acc = 0.f;
    for (int d = 0; d < DD; d++) acc += G1[b * DD + d] * Tk[(size_t)d * DD + e];
    float val = acc * g2e;
    #pragma unroll
    for (int o = 32; o > 0; o >>= 1) val += __shfl_down(val, o);
    __shared__ float ps[2];
    if ((e & 63) == 0) ps[e >> 6] = val;
    __syncthreads();
    if (e == 0) TP[b * KNTN + k] = ps[0] + ps[1] + tb[k];
}

__global__ void k_final(const float* __restrict__ TP, const float* __restrict__ Hist,
                        const float* nw1, const float* nb1, const float* nw2, const float* nb2,
                        const float* nw3, const float* nb3,
                        const float* hw1, const float* hb1, const float* hw2, const float* hb2,
                        const float* fw1, const float* fb1, const float* fw2, const float* fb2,
                        float* __restrict__ out) {
    int b = threadIdx.x;
    float h1[32];
    #pragma unroll
    for (int i = 0; i < 32; i++) {
        float a = nb1[i];
        for (int k = 0; k < 16; k++) a += TP[b * 16 + k] * nw1[i * 16 + k];
        h1[i] = fmaxf(a, 0.f);
    }
    float h2[16];
    #pragma unroll
    for (int j = 0; j < 16; j++) {
        float a = nb2[j];
        for (int i = 0; i < 32; i++) a += h1[i] * nw2[j * 32 + i];
        h2[j] = fmaxf(a, 0.f);
    }
    float nt = nb3[0];
    for (int j = 0; j < 16; j++) nt += h2[j] * nw3[j];
    nt = 1.f / (1.f + expf(-nt));
    float hh[16]; float sum = 0.f;
    for (int k = 0; k < 16; k++) { hh[k] = Hist[b * 16 + k]; sum += hh[k]; }
    float inv = 1.f / (sum + 1e-8f);
    for (int k = 0; k < 16; k++) hh[k] *= inv;
    float g1v[32];
    #pragma unroll
    for (int i = 0; i < 32; i++) {
        float a = hb1[i];
        for (int k = 0; k < 16; k++) a += hh[k] * hw1[i * 16 + k];
        g1v[i] = fmaxf(a, 0.f);
    }
    float hemb[16];
    #pragma unroll
    for (int j = 0; j < 16; j++) {
        float a = hb2[j];
        for (int i = 0; i < 32; i++) a += g1v[i] * hw2[j * 32 + i];
        hemb[j] = a;
    }
    float comb[17];
    comb[0] = nt;
    for (int j = 0; j < 16; j++) comb[1 + j] = hemb[j];
    float f1[8];
    #pragma unroll
    for (int i = 0; i < 8; i++) {
        float a = fb1[i];
        for (int j = 0; j < 17; j++) a += comb[j] * fw1[i * 17 + j];
        f1[i] = fmaxf(a, 0.f);
    }
    float o = fb2[0];
    for (int i = 0; i < 8; i++) o += f1[i] * fw2[i];
    out[b] = 1.f / (1.f + expf(-o));
}

extern "C" void kernel_launch(void* const* d_in, const int* in_sizes, int n_in,
                              void* d_out, int out_size, void* d_ws, size_t ws_size,
                              hipStream_t stream) {
    const float* x1    = (const float*)d_in[0];
    const float* x2    = (const float*)d_in[1];
    const int*   ei1   = (const int*)d_in[2];
    const int*   ei2   = (const int*)d_in[3];
    const float* gcn_w = (const float*)d_in[6];
    const float* gcn_b = (const float*)d_in[7];
    const float* bn_g  = (const float*)d_in[8];
    const float* bn_b  = (const float*)d_in[9];
    const float* bn_m  = (const float*)d_in[10];
    const float* bn_v  = (const float*)d_in[11];
    const float* ctx_b = (const float*)d_in[13];
    const float* att_w = (const float*)d_in[14];
    const float* att_b = (const float*)d_in[15];
    const float* ntn_T = (const float*)d_in[16];
    const float* ntn_b = (const float*)d_in[17];
    const float* nw1 = (const float*)d_in[18];
    const float* nb1 = (const float*)d_in[19];
    const float* nw2 = (const float*)d_in[20];
    const float* nb2 = (const float*)d_in[21];
    const float* nw3 = (const float*)d_in[22];
    const float* nb3 = (const float*)d_in[23];
    const float* hw1 = (const float*)d_in[24];
    const float* hb1 = (const float*)d_in[25];
    const float* hw2 = (const float*)d_in[26];
    const float* hb2 = (const float*)d_in[27];
    const float* fw1 = (const float*)d_in[28];
    const float* fb1 = (const float*)d_in[29];
    const float* fw2 = (const float*)d_in[30];
    const float* fb2 = (const float*)d_in[31];
    float* out = (float*)d_out;

    ushort_t* Xbf = (ushort_t*)d_ws;        // 2*NND (also reused as Nrm)
    ushort_t* Abf = Xbf + 2 * (size_t)NND;  // 2*NND
    ushort_t* Hbf = Abf + 2 * (size_t)NND;  // 2*NND
    ushort_t* wbf = Hbf + 2 * (size_t)NND;  // 4*DD*DD
    float* dinv = (float*)(wbf + 4 * DD * DD);  // 2*NN
    float* S    = dinv + 2 * NN;                // 2*NN
    float* Wsm  = S + 2 * NN;                   // 2*NN
    float* G    = Wsm + 2 * NN;                 // 2*BB*DD
    float* hist = G + 2 * BB * DD;              // BB*NBINS
    float* tp   = hist + BB * NBINS;            // BB*KNTN
    int* degi  = (int*)(tp + BB * KNTN);        // 2*NN
    int* rowst = degi + 2 * NN;                 // 2*NN+1
    int* curs  = rowst + 2 * NN + 1;            // 2*NN
    int* esrc  = curs + 2 * NN;                 // 2*EE

    k_wconv<<<4 * DD * DD / 4 / 256, 256, 0, stream>>>(gcn_w, (const float*)d_in[12], wbf);
    hipMemsetAsync(degi, 0, 2 * NN * sizeof(int), stream);
    hipMemsetAsync(G, 0, (2 * BB * DD + BB * NBINS) * sizeof(float), stream);
    k_counti2<<<2 * EE / 256, 256, 0, stream>>>(ei1 + EE, ei2 + EE, degi);
    k_scan2<<<1, 1024, 0, stream>>>(degi, rowst, curs, dinv);
    k_fill2<<<2 * EE / 256, 256, 0, stream>>>(ei1, ei2, curs, esrc);
    k_xconv<<<2 * NND / 4 / 256, 256, 0, stream>>>(x1, x2, Xbf);

    for (int l = 0; l < LL; l++) {
        k_mgemm<0><<<2 * NN / 64, 256, 0, stream>>>(l == 0 ? Xbf : Abf,
                                                    wbf + (size_t)l * DD * DD,
                                                    nullptr, Hbf, nullptr, nullptr, nullptr, dinv);
        k_agg<<<2 * NN / 4, 256, 0, stream>>>(Hbf, rowst, esrc, dinv,
                                              gcn_b + l * DD, bn_g + l * DD, bn_b + l * DD,
                                              bn_m + l * DD, bn_v + l * DD, Abf);
    }
    k_mgemm<2><<<2 * NN / 64, 256, 0, stream>>>(Abf, wbf + 3 * DD * DD, ctx_b,
                                                nullptr, att_w, att_b, S, nullptr);
    k_smax<<<2 * BB, 512, 0, stream>>>(S, Wsm);
    k_pool<<<2 * BB * 8, 256, 0, stream>>>(Wsm, Abf, G);
    k_norm<<<2 * NN / 4, 256, 0, stream>>>(Abf, Xbf);
    k_hist<<<BB * 16, 256, 0, stream>>>(Xbf, Xbf + NND, hist);
    k_ntn<<<dim3(BB, KNTN), 128, 0, stream>>>(G, G + BB * DD, ntn_T, ntn_b, tp);
    k_final<<<1, 64, 0, stream>>>(tp, hist, nw1, nb1, nw2, nb2, nw3, nb3,
                                  hw1, hb1, hw2, hb2, fw1, fb1, fw2, fb2, out);
}

// Round 6
// 380.255 us; speedup vs baseline: 15.6720x; 1.2684x over previous
//
#include <hip/hip_runtime.h>
#include <math.h>

#define NN 32768      // nodes per side
#define BB 64         // graphs per side
#define NPG 512
#define DD 128
#define LL 3
#define EE 524288     // edges per side
#define NBINS 16
#define KNTN 16
#define NND (NN*DD)
#define NBKT 128      // CSR buckets (512 nodes each)
#define BCAP 10240    // bucket capacity (mean 8192, std ~90)

typedef unsigned short ushort_t;
typedef __attribute__((ext_vector_type(8))) short short8;
typedef __attribute__((ext_vector_type(4))) float f32x4;

__device__ __forceinline__ ushort_t f2bf(float f) {
    unsigned u = __builtin_bit_cast(unsigned, f);
    u += 0x7FFFu + ((u >> 16) & 1u);
    return (ushort_t)(u >> 16);
}
__device__ __forceinline__ float bf2f(ushort_t h) {
    unsigned u = ((unsigned)h) << 16;
    return __builtin_bit_cast(float, u);
}
__device__ __forceinline__ unsigned pack2(float a, float b) {
    return (unsigned)f2bf(a) | ((unsigned)f2bf(b) << 16);
}
__device__ __forceinline__ float lo16(unsigned u) { return __builtin_bit_cast(float, u << 16); }
__device__ __forceinline__ float hi16(unsigned u) { return __builtin_bit_cast(float, u & 0xffff0000u); }

// ---------- CSR build pass A: bucket edges by dst>>9, coalesced region writes ----------
__global__ __launch_bounds__(256) void k_bucket(const int* __restrict__ ei1,
                                                const int* __restrict__ ei2,
                                                int* __restrict__ bcur,
                                                unsigned* __restrict__ ibuf) {
    __shared__ int cnt[NBKT], off[NBKT], gb[NBKT];
    __shared__ unsigned stage[2048];
    int t = threadIdx.x;
    int blk = blockIdx.x;                 // 0..511; 0..255 side1, 256..511 side2
    const int* ei = (blk < 256) ? ei1 : ei2;
    int ebase = (blk & 255) * 2048;
    int addn = (blk < 256) ? 0 : NN;
    for (int i = t; i < NBKT; i += 256) cnt[i] = 0;
    __syncthreads();
    unsigned pk[8]; int rk[8];
    #pragma unroll
    for (int k = 0; k < 8; k++) {
        int e = ebase + t + k * 256;
        int s = ei[e] + addn;
        int d = ei[EE + e] + addn;
        pk[k] = (unsigned)s | ((unsigned)d << 16);
        rk[k] = atomicAdd(&cnt[d >> 9 >> ((addn ? 0 : 0))], 0); // placeholder avoided below
    }
    // redo ranks properly (single atomic per edge)
    #pragma unroll
    for (int k = 0; k < 8; k++) {
        int bk = pk[k] >> 25;
        rk[k] = atomicAdd(&cnt[bk], 1);
    }
    __syncthreads();
    // note: first loop's atomicAdd(...,0) contributed nothing
    // exclusive scan cnt -> off (inclusive then subtract)
    if (t < NBKT) off[t] = cnt[t];
    __syncthreads();
    for (int o = 1; o < NBKT; o <<= 1) {
        int v = 0;
        if (t < NBKT && t >= o) v = off[t - o];
        __syncthreads();
        if (t < NBKT) off[t] += v;
        __syncthreads();
    }
    #pragma unroll
    for (int k = 0; k < 8; k++) {
        int bk = pk[k] >> 25;
        stage[off[bk] - cnt[bk] + rk[k]] = pk[k];
    }
    if (t < NBKT) {
        int c = cnt[t];
        gb[t] = c > 0 ? atomicAdd(&bcur[t], c) : 0;
    }
    __syncthreads();
    #pragma unroll
    for (int k = 0; k < 8; k++) {
        int idx = t + k * 256;
        unsigned p = stage[idx];
        int bk = p >> 25;
        int pos = idx - (off[bk] - cnt[bk]);
        ibuf[(size_t)bk * BCAP + gb[bk] + pos] = p;
    }
}

// ---------- pass B1: per-bucket degree count + dinv ----------
__global__ __launch_bounds__(256) void k_bcnt(const unsigned* __restrict__ ibuf,
                                              const int* __restrict__ bcur,
                                              int* __restrict__ deg,
                                              float* __restrict__ dinv) {
    __shared__ int cnt[512];
    int bk = blockIdx.x, t = threadIdx.x;
    for (int i = t; i < 512; i += 256) cnt[i] = 0;
    __syncthreads();
    int n = bcur[bk];
    const unsigned* buf = ibuf + (size_t)bk * BCAP;
    for (int i = t; i < n; i += 256) {
        int dl = (buf[i] >> 16) & 511;
        atomicAdd(&cnt[dl], 1);
    }
    __syncthreads();
    for (int i = t; i < 512; i += 256) {
        int c = cnt[i];
        deg[bk * 512 + i] = c;
        dinv[bk * 512 + i] = rsqrtf((float)c + 1.0f);
    }
}

// ---------- rowstart scan (single block) ----------
__global__ __launch_bounds__(1024) void k_scan2(const int* __restrict__ deg,
                                                int* __restrict__ rowstart) {
    __shared__ int part[1024];
    int t = threadIdx.x;
    int base = t * 64;
    int s = 0;
    for (int i = 0; i < 64; i++) s += deg[base + i];
    part[t] = s;
    __syncthreads();
    for (int o = 1; o < 1024; o <<= 1) {
        int v = (t >= o) ? part[t - o] : 0;
        __syncthreads();
        part[t] += v;
        __syncthreads();
    }
    int run = (t == 0) ? 0 : part[t - 1];
    for (int i = 0; i < 64; i++) {
        rowstart[base + i] = run;
        run += deg[base + i];
    }
    if (t == 1023) rowstart[2 * NN] = run;
}

// ---------- pass B2: per-bucket placement into esrc (localized writes) ----------
__global__ __launch_bounds__(256) void k_bplace(const unsigned* __restrict__ ibuf,
                                                const int* __restrict__ bcur,
                                                const int* __restrict__ rowstart,
                                                int* __restrict__ esrc) {
    __shared__ int lcur[512];
    int bk = blockIdx.x, t = threadIdx.x;
    for (int i = t; i < 512; i += 256) lcur[i] = rowstart[bk * 512 + i];
    __syncthreads();
    int n = bcur[bk];
    const unsigned* buf = ibuf + (size_t)bk * BCAP;
    for (int i = t; i < n; i += 256) {
        unsigned p = buf[i];
        int dl = (p >> 16) & 511;
        int slot = atomicAdd(&lcur[dl], 1);
        esrc[slot] = (int)(p & 0xffffu);
    }
}

// ---------- fp32 -> bf16 converts ----------
__global__ void k_xconv(const float* __restrict__ x1, const float* __restrict__ x2,
                        ushort_t* __restrict__ out) {
    int i = blockIdx.x * blockDim.x + threadIdx.x;
    const float4 v = (i < NND / 4) ? ((const float4*)x1)[i] : ((const float4*)x2)[i - NND / 4];
    uint2 o;
    o.x = pack2(v.x, v.y);
    o.y = pack2(v.z, v.w);
    ((uint2*)out)[i] = o;
}

__global__ void k_wconv(const float* __restrict__ gw, const float* __restrict__ cw,
                        ushort_t* __restrict__ out) {
    int i = blockIdx.x * blockDim.x + threadIdx.x;
    const float4 v = (i < 3 * DD * DD / 4) ? ((const float4*)gw)[i]
                                           : ((const float4*)cw)[i - 3 * DD * DD / 4];
    uint2 o;
    o.x = pack2(v.x, v.y);
    o.y = pack2(v.z, v.w);
    ((uint2*)out)[i] = o;
}

// ---------- MFMA GEMM: Out[n][j] = sum_d X[n][d]*W[j][d] ----------
template<int EPI>
__global__ __launch_bounds__(256) void k_mgemm(const ushort_t* __restrict__ X,
                                               const ushort_t* __restrict__ Wb,
                                               const float* __restrict__ bias,
                                               ushort_t* __restrict__ Out,
                                               const float* __restrict__ aw,
                                               const float* __restrict__ ab,
                                               float* __restrict__ Sout,
                                               const float* __restrict__ dscale) {
    int w = threadIdx.x >> 6, l = threadIdx.x & 63;
    int rw = blockIdx.x * 64 + w * 16;
    int lr = l & 15, lg = l >> 4;
    f32x4 acc[8];
    #pragma unroll
    for (int c = 0; c < 8; c++) acc[c] = (f32x4){0.f, 0.f, 0.f, 0.f};
    const ushort_t* xrow = X + (size_t)(rw + lr) * DD + lg * 8;
    const ushort_t* wrow = Wb + (size_t)lr * DD + lg * 8;
    for (int kt = 0; kt < 4; kt++) {
        short8 a = *(const short8*)(xrow + kt * 32);
        #pragma unroll
        for (int c = 0; c < 8; c++) {
            short8 b = *(const short8*)(wrow + (size_t)c * 16 * DD + kt * 32);
            acc[c] = __builtin_amdgcn_mfma_f32_16x16x32_bf16(a, b, acc[c], 0, 0, 0);
        }
    }
    if (EPI == 0) {
        float ds[4];
        #pragma unroll
        for (int q = 0; q < 4; q++) ds[q] = dscale[rw + lg * 4 + q];
        #pragma unroll
        for (int c = 0; c < 8; c++) {
            int col = c * 16 + lr;
            #pragma unroll
            for (int q = 0; q < 4; q++)
                Out[(size_t)(rw + lg * 4 + q) * DD + col] = f2bf(acc[c][q] * ds[q]);
        }
    } else {
        float rs0 = 0.f, rs1 = 0.f, rs2 = 0.f, rs3 = 0.f;
        #pragma unroll
        for (int c = 0; c < 8; c++) {
            int col = c * 16 + lr;
            float bv = bias[col], wv = aw[col];
            rs0 += tanhf(acc[c][0] + bv) * wv;
            rs1 += tanhf(acc[c][1] + bv) * wv;
            rs2 += tanhf(acc[c][2] + bv) * wv;
            rs3 += tanhf(acc[c][3] + bv) * wv;
        }
        #pragma unroll
        for (int m = 1; m < 16; m <<= 1) {
            rs0 += __shfl_xor(rs0, m);
            rs1 += __shfl_xor(rs1, m);
            rs2 += __shfl_xor(rs2, m);
            rs3 += __shfl_xor(rs3, m);
        }
        if (lr == 0) {
            float a0 = ab[0];
            Sout[rw + lg * 4 + 0] = rs0 + a0;
            Sout[rw + lg * 4 + 1] = rs1 + a0;
            Sout[rw + lg * 4 + 2] = rs2 + a0;
            Sout[rw + lg * 4 + 3] = rs3 + a0;
        }
    }
}

// ---------- aggregate; LAST=1 also emits L2-normalized rows ----------
template<int LAST>
__global__ __launch_bounds__(256) void k_agg(
    const ushort_t* __restrict__ Hs, const int* __restrict__ rowstart,
    const int* __restrict__ esrc, const float* __restrict__ dinv,
    const float* __restrict__ gb, const float* __restrict__ gam,
    const float* __restrict__ bet, const float* __restrict__ mean,
    const float* __restrict__ var, ushort_t* __restrict__ A,
    ushort_t* __restrict__ Nrm) {
    int n = (blockIdx.x * blockDim.x + threadIdx.x) >> 6;
    int l = threadIdx.x & 63;
    int beg = rowstart[n], end = rowstart[n + 1];
    float di = dinv[n];
    const unsigned* Hu = (const unsigned*)Hs;
    unsigned h = Hu[(size_t)n * 64 + l];
    float acc0 = lo16(h), acc1 = hi16(h);
    int j = beg;
    for (; j + 8 <= end; j += 8) {
        int s0 = esrc[j + 0], s1 = esrc[j + 1], s2 = esrc[j + 2], s3 = esrc[j + 3];
        int s4 = esrc[j + 4], s5 = esrc[j + 5], s6 = esrc[j + 6], s7 = esrc[j + 7];
        unsigned u0 = Hu[(size_t)s0 * 64 + l];
        unsigned u1 = Hu[(size_t)s1 * 64 + l];
        unsigned u2 = Hu[(size_t)s2 * 64 + l];
        unsigned u3 = Hu[(size_t)s3 * 64 + l];
        unsigned u4 = Hu[(size_t)s4 * 64 + l];
        unsigned u5 = Hu[(size_t)s5 * 64 + l];
        unsigned u6 = Hu[(size_t)s6 * 64 + l];
        unsigned u7 = Hu[(size_t)s7 * 64 + l];
        acc0 += ((lo16(u0) + lo16(u1)) + (lo16(u2) + lo16(u3))) +
                ((lo16(u4) + lo16(u5)) + (lo16(u6) + lo16(u7)));
        acc1 += ((hi16(u0) + hi16(u1)) + (hi16(u2) + hi16(u3))) +
                ((hi16(u4) + hi16(u5)) + (hi16(u6) + hi16(u7)));
    }
    if (j + 4 <= end) {
        int s0 = esrc[j + 0], s1 = esrc[j + 1], s2 = esrc[j + 2], s3 = esrc[j + 3];
        unsigned u0 = Hu[(size_t)s0 * 64 + l];
        unsigned u1 = Hu[(size_t)s1 * 64 + l];
        unsigned u2 = Hu[(size_t)s2 * 64 + l];
        unsigned u3 = Hu[(size_t)s3 * 64 + l];
        acc0 += (lo16(u0) + lo16(u1)) + (lo16(u2) + lo16(u3));
        acc1 += (hi16(u0) + hi16(u1)) + (hi16(u2) + hi16(u3));
        j += 4;
    }
    for (; j < end; j++) {
        unsigned u = Hu[(size_t)esrc[j] * 64 + l];
        acc0 += lo16(u);
        acc1 += hi16(u);
    }
    acc0 *= di; acc1 *= di;
    int c0 = 2 * l, c1 = 2 * l + 1;
    float o0 = (acc0 + gb[c0] - mean[c0]) * (gam[c0] * rsqrtf(var[c0] + 1e-5f)) + bet[c0];
    float o1 = (acc1 + gb[c1] - mean[c1]) * (gam[c1] * rsqrtf(var[c1] + 1e-5f)) + bet[c1];
    float r0 = fmaxf(o0, 0.f), r1 = fmaxf(o1, 0.f);
    ((unsigned*)(A + (size_t)n * DD))[l] = pack2(r0, r1);
    if (LAST) {
        // normalize the bf16-rounded values (match separate-pass numerics)
        r0 = bf2f(f2bf(r0)); r1 = bf2f(f2bf(r1));
        float ss = r0 * r0 + r1 * r1;
        #pragma unroll
        for (int o = 32; o > 0; o >>= 1) ss += __shfl_xor(ss, o);
        float inv = 1.0f / fmaxf(sqrtf(ss), 1e-8f);
        ((unsigned*)(Nrm + (size_t)n * DD))[l] = pack2(r0 * inv, r1 * inv);
    }
}

// ---------- per-graph softmax weights ----------
__global__ __launch_bounds__(512) void k_smax(const float* __restrict__ S,
                                              float* __restrict__ W) {
    int b = blockIdx.x;
    int t = threadIdx.x;
    __shared__ float red[512];
    float s = S[b * NPG + t];
    red[t] = s;
    __syncthreads();
    for (int o = 256; o > 0; o >>= 1) { if (t < o) red[t] = fmaxf(red[t], red[t + o]); __syncthreads(); }
    float m = red[0];
    __syncthreads();
    float e = expf(s - m);
    red[t] = e;
    __syncthreads();
    for (int o = 256; o > 0; o >>= 1) { if (t < o) red[t] += red[t + o]; __syncthreads(); }
    W[b * NPG + t] = e / red[0];
}

// ---------- weighted sum ----------
__global__ __launch_bounds__(256) void k_pool(const float* __restrict__ W,
                                              const ushort_t* __restrict__ Emb,
                                              float* __restrict__ G) {
    int blk = blockIdx.x;
    int b = blk >> 3, ch = blk & 7;
    int t = threadIdx.x;
    int l = t & 63, grp = t >> 6;
    int nbase = b * NPG + ch * 64 + grp * 16;
    float a0 = 0.f, a1 = 0.f;
    for (int i = 0; i < 16; i++) {
        float wv = W[nbase + i];
        unsigned u = ((const unsigned*)(Emb + (size_t)(nbase + i) * DD))[l];
        a0 += wv * lo16(u);
        a1 += wv * hi16(u);
    }
    __shared__ float red0[256], red1[256];
    red0[t] = a0; red1[t] = a1;
    __syncthreads();
    if (t < 64) {
        float s0 = red0[t] + red0[t + 64] + red0[t + 128] + red0[t + 192];
        float s1 = red1[t] + red1[t + 64] + red1[t + 128] + red1[t + 192];
        atomicAdd(&G[b * DD + 2 * t], s0);
        atomicAdd(&G[b * DD + 2 * t + 1], s1);
    }
}

// ---------- MFMA cosine-sim histogram ----------
__global__ __launch_bounds__(256) void k_hist(const ushort_t* __restrict__ N1,
                                              const ushort_t* __restrict__ N2,
                                              float* __restrict__ Hist) {
    __shared__ int hl[256 * 17];
    __shared__ float hred[NBINS];
    int t = threadIdx.x, w = t >> 6, l = t & 63;
    int lr = l & 15, lg = l >> 4;
    int g = blockIdx.x >> 4, ti = (blockIdx.x >> 2) & 3, tj = blockIdx.x & 3;
    #pragma unroll
    for (int i = t; i < 256 * 17; i += 256) hl[i] = 0;
    if (t < NBINS) hred[t] = 0.f;
    __syncthreads();

    const ushort_t* arow = N1 + ((size_t)g * NPG + ti * 128 + w * 32 + lr) * DD + lg * 8;
    const ushort_t* brow = N2 + ((size_t)g * NPG + tj * 128 + lr) * DD + lg * 8;
    f32x4 acc[2][8];
    #pragma unroll
    for (int r = 0; r < 2; r++)
        #pragma unroll
        for (int c = 0; c < 8; c++) acc[r][c] = (f32x4){0.f, 0.f, 0.f, 0.f};
    for (int kt = 0; kt < 4; kt++) {
        short8 a0 = *(const short8*)(arow + kt * 32);
        short8 a1 = *(const short8*)(arow + (size_t)16 * DD + kt * 32);
        #pragma unroll
        for (int c = 0; c < 8; c++) {
            short8 b = *(const short8*)(brow + (size_t)c * 16 * DD + kt * 32);
            acc[0][c] = __builtin_amdgcn_mfma_f32_16x16x32_bf16(a0, b, acc[0][c], 0, 0, 0);
            acc[1][c] = __builtin_amdgcn_mfma_f32_16x16x32_bf16(a1, b, acc[1][c], 0, 0, 0);
        }
    }
    int base = t * 17;
    #pragma unroll
    for (int r = 0; r < 2; r++)
        #pragma unroll
        for (int c = 0; c < 8; c++)
            #pragma unroll
            for (int q = 0; q < 4; q++) {
                float sim = acc[r][c][q];
                float v = floorf((sim + 1.0f) * 8.0f);
                v = fminf(fmaxf(v, 0.f), 15.f);
                atomicAdd(&hl[base + (int)v], 1);
            }
    __syncthreads();
    int bin = t & 15, r0 = (t >> 4) * 16;
    int s = 0;
    #pragma unroll
    for (int r = 0; r < 16; r++) s += hl[(r0 + r) * 17 + bin];
    atomicAdd(&hred[bin], (float)s);
    __syncthreads();
    if (t < NBINS) atomicAdd(&Hist[g * NBINS + t], hred[t]);
}

// ---------- NTN bilinear ----------
__global__ __launch_bounds__(128) void k_ntn(const float* __restrict__ G1,
                                             const float* __restrict__ G2,
                                             const float* __restrict__ T,
                                             const float* __restrict__ tb,
                                             float* __restrict__ TP) {
    int b = blockIdx.x, k = blockIdx.y;
    int e = threadIdx.x;
    const float* Tk = T + (size_t)k * DD * DD;
    float g2e = G2[b * DD + e];
    float acc = 0.f;
    for (int d = 0; d < DD; d++) acc += G1[b * DD + d] * Tk[(size_t)d * DD + e];
    float val = acc * g2e;
    #pragma unroll
    for (int o = 32; o > 0; o >>= 1) val += __shfl_down(val, o);
    __shared__ float ps[2];
    if ((e & 63) == 0) ps[e >> 6] = val;
    __syncthreads();
    if (e == 0) TP[b * KNTN + k] = ps[0] + ps[1] + tb[k];
}

__global__ void k_final(const float* __restrict__ TP, const float* __restrict__ Hist,
                        const float* nw1, const float* nb1, const float* nw2, const float* nb2,
                        const float* nw3, const float* nb3,
                        const float* hw1, const float* hb1, const float* hw2, const float* hb2,
                        const float* fw1, const float* fb1, const float* fw2, const float* fb2,
                        float* __restrict__ out) {
    int b = threadIdx.x;
    float h1[32];
    #pragma unroll
    for (int i = 0; i < 32; i++) {
        float a = nb1[i];
        for (int k = 0; k < 16; k++) a += TP[b * 16 + k] * nw1[i * 16 + k];
        h1[i] = fmaxf(a, 0.f);
    }
    float h2[16];
    #pragma unroll
    for (int j = 0; j < 16; j++) {
        float a = nb2[j];
        for (int i = 0; i < 32; i++) a += h1[i] * nw2[j * 32 + i];
        h2[j] = fmaxf(a, 0.f);
    }
    float nt = nb3[0];
    for (int j = 0; j < 16; j++) nt += h2[j] * nw3[j];
    nt = 1.f / (1.f + expf(-nt));
    float hh[16]; float sum = 0.f;
    for (int k = 0; k < 16; k++) { hh[k] = Hist[b * 16 + k]; sum += hh[k]; }
    float inv = 1.f / (sum + 1e-8f);
    for (int k = 0; k < 16; k++) hh[k] *= inv;
    float g1v[32];
    #pragma unroll
    for (int i = 0; i < 32; i++) {
        float a = hb1[i];
        for (int k = 0; k < 16; k++) a += hh[k] * hw1[i * 16 + k];
        g1v[i] = fmaxf(a, 0.f);
    }
    float hemb[16];
    #pragma unroll
    for (int j = 0; j < 16; j++) {
        float a = hb2[j];
        for (int i = 0; i < 32; i++) a += g1v[i] * hw2[j * 32 + i];
        hemb[j] = a;
    }
    float comb[17];
    comb[0] = nt;
    for (int j = 0; j < 16; j++) comb[1 + j] = hemb[j];
    float f1[8];
    #pragma unroll
    for (int i = 0; i < 8; i++) {
        float a = fb1[i];
        for (int j = 0; j < 17; j++) a += comb[j] * fw1[i * 17 + j];
        f1[i] = fmaxf(a, 0.f);
    }
    float o = fb2[0];
    for (int i = 0; i < 8; i++) o += f1[i] * fw2[i];
    out[b] = 1.f / (1.f + expf(-o));
}

extern "C" void kernel_launch(void* const* d_in, const int* in_sizes, int n_in,
                              void* d_out, int out_size, void* d_ws, size_t ws_size,
                              hipStream_t stream) {
    const float* x1    = (const float*)d_in[0];
    const float* x2    = (const float*)d_in[1];
    const int*   ei1   = (const int*)d_in[2];
    const int*   ei2   = (const int*)d_in[3];
    const float* gcn_w = (const float*)d_in[6];
    const float* gcn_b = (const float*)d_in[7];
    const float* bn_g  = (const float*)d_in[8];
    const float* bn_b  = (const float*)d_in[9];
    const float* bn_m  = (const float*)d_in[10];
    const float* bn_v  = (const float*)d_in[11];
    const float* ctx_b = (const float*)d_in[13];
    const float* att_w = (const float*)d_in[14];
    const float* att_b = (const float*)d_in[15];
    const float* ntn_T = (const float*)d_in[16];
    const float* ntn_b = (const float*)d_in[17];
    const float* nw1 = (const float*)d_in[18];
    const float* nb1 = (const float*)d_in[19];
    const float* nw2 = (const float*)d_in[20];
    const float* nb2 = (const float*)d_in[21];
    const float* nw3 = (const float*)d_in[22];
    const float* nb3 = (const float*)d_in[23];
    const float* hw1 = (const float*)d_in[24];
    const float* hb1 = (const float*)d_in[25];
    const float* hw2 = (const float*)d_in[26];
    const float* hb2 = (const float*)d_in[27];
    const float* fw1 = (const float*)d_in[28];
    const float* fb1 = (const float*)d_in[29];
    const float* fw2 = (const float*)d_in[30];
    const float* fb2 = (const float*)d_in[31];
    float* out = (float*)d_out;

    ushort_t* Xbf = (ushort_t*)d_ws;        // 2*NND (reused as Nrm)
    ushort_t* Abf = Xbf + 2 * (size_t)NND;  // 2*NND
    ushort_t* Hbf = Abf + 2 * (size_t)NND;  // 2*NND
    ushort_t* wbf = Hbf + 2 * (size_t)NND;  // 4*DD*DD
    float* dinv = (float*)(wbf + 4 * DD * DD);  // 2*NN
    float* S    = dinv + 2 * NN;                // 2*NN
    float* Wsm  = S + 2 * NN;                   // 2*NN
    float* G    = Wsm + 2 * NN;                 // 2*BB*DD
    float* hist = G + 2 * BB * DD;              // BB*NBINS
    float* tp   = hist + BB * NBINS;            // BB*KNTN
    int* degi  = (int*)(tp + BB * KNTN);        // 2*NN
    int* rowst = degi + 2 * NN;                 // 2*NN+1
    int* esrc  = rowst + 2 * NN + 1;            // 2*EE
    int* bcur  = esrc + 2 * EE;                 // NBKT
    unsigned* ibuf = (unsigned*)(bcur + NBKT);  // NBKT*BCAP

    k_wconv<<<4 * DD * DD / 4 / 256, 256, 0, stream>>>(gcn_w, (const float*)d_in[12], wbf);
    hipMemsetAsync(bcur, 0, NBKT * sizeof(int), stream);
    hipMemsetAsync(G, 0, (2 * BB * DD + BB * NBINS) * sizeof(float), stream);
    k_bucket<<<2 * EE / 2048, 256, 0, stream>>>(ei1, ei2, bcur, ibuf);
    k_bcnt<<<NBKT, 256, 0, stream>>>(ibuf, bcur, degi, dinv);
    k_scan2<<<1, 1024, 0, stream>>>(degi, rowst);
    k_bplace<<<NBKT, 256, 0, stream>>>(ibuf, bcur, rowst, esrc);
    k_xconv<<<2 * NND / 4 / 256, 256, 0, stream>>>(x1, x2, Xbf);

    for (int l = 0; l < LL; l++) {
        k_mgemm<0><<<2 * NN / 64, 256, 0, stream>>>(l == 0 ? Xbf : Abf,
                                                    wbf + (size_t)l * DD * DD,
                                                    nullptr, Hbf, nullptr, nullptr, nullptr, dinv);
        if (l < LL - 1)
            k_agg<0><<<2 * NN / 4, 256, 0, stream>>>(Hbf, rowst, esrc, dinv,
                                                     gcn_b + l * DD, bn_g + l * DD, bn_b + l * DD,
                                                     bn_m + l * DD, bn_v + l * DD, Abf, nullptr);
        else
            k_agg<1><<<2 * NN / 4, 256, 0, stream>>>(Hbf, rowst, esrc, dinv,
                                                     gcn_b + l * DD, bn_g + l * DD, bn_b + l * DD,
                                                     bn_m + l * DD, bn_v + l * DD, Abf, Xbf);
    }
    k_mgemm<2><<<2 * NN / 64, 256, 0, stream>>>(Abf, wbf + 3 * DD * DD, ctx_b,
                                                nullptr, att_w, att_b, S, nullptr);
    k_smax<<<2 * BB, 512, 0, stream>>>(S, Wsm);
    k_pool<<<2 * BB * 8, 256, 0, stream>>>(Wsm, Abf, G);
    k_hist<<<BB * 16, 256, 0, stream>>>(Xbf, Xbf + NND, hist);
    k_ntn<<<dim3(BB, KNTN), 128, 0, stream>>>(G, G + BB * DD, ntn_T, ntn_b, tp);
    k_final<<<1, 64, 0, stream>>>(tp, hist, nw1, nb1, nw2, nb2, nw3, nb3,
                                  hw1, hb1, hw2, hb2, fw1, fb1, fw2, fb2, out);
}

// Round 7
// 354.692 us; speedup vs baseline: 16.8015x; 1.0721x over previous
//
#include <hip/hip_runtime.h>
#include <math.h>

#define NN 32768      // nodes per side
#define BB 64         // graphs per side
#define NPG 512
#define DD 128
#define LL 3
#define EE 524288     // edges per side
#define NBINS 16
#define KNTN 16
#define NND (NN*DD)
#define NBKT 128      // CSR buckets (512 nodes each)
#define BCAP 10240    // bucket capacity (mean 8192, std ~90)

typedef unsigned short ushort_t;
typedef __attribute__((ext_vector_type(8))) short short8;
typedef __attribute__((ext_vector_type(4))) float f32x4;

__device__ __forceinline__ ushort_t f2bf(float f) {
    unsigned u = __builtin_bit_cast(unsigned, f);
    u += 0x7FFFu + ((u >> 16) & 1u);
    return (ushort_t)(u >> 16);
}
__device__ __forceinline__ float bf2f(ushort_t h) {
    unsigned u = ((unsigned)h) << 16;
    return __builtin_bit_cast(float, u);
}
__device__ __forceinline__ unsigned pack2(float a, float b) {
    return (unsigned)f2bf(a) | ((unsigned)f2bf(b) << 16);
}
__device__ __forceinline__ float lo16(unsigned u) { return __builtin_bit_cast(float, u << 16); }
__device__ __forceinline__ float hi16(unsigned u) { return __builtin_bit_cast(float, u & 0xffff0000u); }

// ---------- CSR build pass A: bucket edges by dst>>9, coalesced region writes ----------
__global__ __launch_bounds__(256) void k_bucket(const int* __restrict__ ei1,
                                                const int* __restrict__ ei2,
                                                int* __restrict__ bcur,
                                                unsigned* __restrict__ ibuf) {
    __shared__ int cnt[NBKT], off[NBKT], gb[NBKT];
    __shared__ unsigned stage[2048];
    int t = threadIdx.x;
    int blk = blockIdx.x;                 // 0..511; 0..255 side1, 256..511 side2
    const int* ei = (blk < 256) ? ei1 : ei2;
    int ebase = (blk & 255) * 2048;
    int addn = (blk < 256) ? 0 : NN;
    for (int i = t; i < NBKT; i += 256) cnt[i] = 0;
    __syncthreads();
    unsigned pk[8]; int rk[8];
    #pragma unroll
    for (int k = 0; k < 8; k++) {
        int e = ebase + t + k * 256;
        int s = ei[e] + addn;
        int d = ei[EE + e] + addn;
        pk[k] = (unsigned)s | ((unsigned)d << 16);
    }
    #pragma unroll
    for (int k = 0; k < 8; k++) {
        int bk = pk[k] >> 25;
        rk[k] = atomicAdd(&cnt[bk], 1);
    }
    __syncthreads();
    if (t < NBKT) off[t] = cnt[t];
    __syncthreads();
    for (int o = 1; o < NBKT; o <<= 1) {
        int v = 0;
        if (t < NBKT && t >= o) v = off[t - o];
        __syncthreads();
        if (t < NBKT) off[t] += v;
        __syncthreads();
    }
    #pragma unroll
    for (int k = 0; k < 8; k++) {
        int bk = pk[k] >> 25;
        stage[off[bk] - cnt[bk] + rk[k]] = pk[k];
    }
    if (t < NBKT) {
        int c = cnt[t];
        gb[t] = c > 0 ? atomicAdd(&bcur[t], c) : 0;
    }
    __syncthreads();
    #pragma unroll
    for (int k = 0; k < 8; k++) {
        int idx = t + k * 256;
        unsigned p = stage[idx];
        int bk = p >> 25;
        int pos = idx - (off[bk] - cnt[bk]);
        ibuf[(size_t)bk * BCAP + gb[bk] + pos] = p;
    }
}

// ---------- pass B1: per-bucket degree count + dinv ----------
__global__ __launch_bounds__(256) void k_bcnt(const unsigned* __restrict__ ibuf,
                                              const int* __restrict__ bcur,
                                              int* __restrict__ deg,
                                              float* __restrict__ dinv) {
    __shared__ int cnt[512];
    int bk = blockIdx.x, t = threadIdx.x;
    for (int i = t; i < 512; i += 256) cnt[i] = 0;
    __syncthreads();
    int n = bcur[bk];
    const unsigned* buf = ibuf + (size_t)bk * BCAP;
    for (int i = t; i < n; i += 256) {
        int dl = (buf[i] >> 16) & 511;
        atomicAdd(&cnt[dl], 1);
    }
    __syncthreads();
    for (int i = t; i < 512; i += 256) {
        int c = cnt[i];
        deg[bk * 512 + i] = c;
        dinv[bk * 512 + i] = rsqrtf((float)c + 1.0f);
    }
}

// ---------- rowstart scan (single block) ----------
__global__ __launch_bounds__(1024) void k_scan2(const int* __restrict__ deg,
                                                int* __restrict__ rowstart) {
    __shared__ int part[1024];
    int t = threadIdx.x;
    int base = t * 64;
    int s = 0;
    for (int i = 0; i < 64; i++) s += deg[base + i];
    part[t] = s;
    __syncthreads();
    for (int o = 1; o < 1024; o <<= 1) {
        int v = (t >= o) ? part[t - o] : 0;
        __syncthreads();
        part[t] += v;
        __syncthreads();
    }
    int run = (t == 0) ? 0 : part[t - 1];
    for (int i = 0; i < 64; i++) {
        rowstart[base + i] = run;
        run += deg[base + i];
    }
    if (t == 1023) rowstart[2 * NN] = run;
}

// ---------- pass B2: per-bucket placement into esrc (u16, localized writes) ----------
__global__ __launch_bounds__(256) void k_bplace(const unsigned* __restrict__ ibuf,
                                                const int* __restrict__ bcur,
                                                const int* __restrict__ rowstart,
                                                ushort_t* __restrict__ esrc) {
    __shared__ int lcur[512];
    int bk = blockIdx.x, t = threadIdx.x;
    for (int i = t; i < 512; i += 256) lcur[i] = rowstart[bk * 512 + i];
    __syncthreads();
    int n = bcur[bk];
    const unsigned* buf = ibuf + (size_t)bk * BCAP;
    for (int i = t; i < n; i += 256) {
        unsigned p = buf[i];
        int dl = (p >> 16) & 511;
        int slot = atomicAdd(&lcur[dl], 1);
        esrc[slot] = (ushort_t)(p & 0xffffu);
    }
}

// ---------- fp32 -> bf16 converts ----------
__global__ void k_xconv(const float* __restrict__ x1, const float* __restrict__ x2,
                        ushort_t* __restrict__ out) {
    int i = blockIdx.x * blockDim.x + threadIdx.x;
    const float4 v = (i < NND / 4) ? ((const float4*)x1)[i] : ((const float4*)x2)[i - NND / 4];
    uint2 o;
    o.x = pack2(v.x, v.y);
    o.y = pack2(v.z, v.w);
    ((uint2*)out)[i] = o;
}

// also zeroes bcur (runs before k_bucket)
__global__ void k_wconv(const float* __restrict__ gw, const float* __restrict__ cw,
                        ushort_t* __restrict__ out, int* __restrict__ bcur) {
    int i = blockIdx.x * blockDim.x + threadIdx.x;
    if (blockIdx.x == 0 && threadIdx.x < NBKT) bcur[threadIdx.x] = 0;
    const float4 v = (i < 3 * DD * DD / 4) ? ((const float4*)gw)[i]
                                           : ((const float4*)cw)[i - 3 * DD * DD / 4];
    uint2 o;
    o.x = pack2(v.x, v.y);
    o.y = pack2(v.z, v.w);
    ((uint2*)out)[i] = o;
}

// ---------- MFMA GEMM: Out[n][j] = sum_d X[n][d]*W[j][d] ----------
template<int EPI>
__global__ __launch_bounds__(256) void k_mgemm(const ushort_t* __restrict__ X,
                                               const ushort_t* __restrict__ Wb,
                                               const float* __restrict__ bias,
                                               ushort_t* __restrict__ Out,
                                               const float* __restrict__ aw,
                                               const float* __restrict__ ab,
                                               float* __restrict__ Sout,
                                               const float* __restrict__ dscale) {
    int w = threadIdx.x >> 6, l = threadIdx.x & 63;
    int rw = blockIdx.x * 64 + w * 16;
    int lr = l & 15, lg = l >> 4;
    f32x4 acc[8];
    #pragma unroll
    for (int c = 0; c < 8; c++) acc[c] = (f32x4){0.f, 0.f, 0.f, 0.f};
    const ushort_t* xrow = X + (size_t)(rw + lr) * DD + lg * 8;
    const ushort_t* wrow = Wb + (size_t)lr * DD + lg * 8;
    for (int kt = 0; kt < 4; kt++) {
        short8 a = *(const short8*)(xrow + kt * 32);
        #pragma unroll
        for (int c = 0; c < 8; c++) {
            short8 b = *(const short8*)(wrow + (size_t)c * 16 * DD + kt * 32);
            acc[c] = __builtin_amdgcn_mfma_f32_16x16x32_bf16(a, b, acc[c], 0, 0, 0);
        }
    }
    if (EPI == 0) {
        float ds[4];
        #pragma unroll
        for (int q = 0; q < 4; q++) ds[q] = dscale[rw + lg * 4 + q];
        #pragma unroll
        for (int c = 0; c < 8; c++) {
            int col = c * 16 + lr;
            #pragma unroll
            for (int q = 0; q < 4; q++)
                Out[(size_t)(rw + lg * 4 + q) * DD + col] = f2bf(acc[c][q] * ds[q]);
        }
    } else {
        float rs0 = 0.f, rs1 = 0.f, rs2 = 0.f, rs3 = 0.f;
        #pragma unroll
        for (int c = 0; c < 8; c++) {
            int col = c * 16 + lr;
            float bv = bias[col], wv = aw[col];
            rs0 += tanhf(acc[c][0] + bv) * wv;
            rs1 += tanhf(acc[c][1] + bv) * wv;
            rs2 += tanhf(acc[c][2] + bv) * wv;
            rs3 += tanhf(acc[c][3] + bv) * wv;
        }
        #pragma unroll
        for (int m = 1; m < 16; m <<= 1) {
            rs0 += __shfl_xor(rs0, m);
            rs1 += __shfl_xor(rs1, m);
            rs2 += __shfl_xor(rs2, m);
            rs3 += __shfl_xor(rs3, m);
        }
        if (lr == 0) {
            float a0 = ab[0];
            Sout[rw + lg * 4 + 0] = rs0 + a0;
            Sout[rw + lg * 4 + 1] = rs1 + a0;
            Sout[rw + lg * 4 + 2] = rs2 + a0;
            Sout[rw + lg * 4 + 3] = rs3 + a0;
        }
    }
}

// ---------- aggregate v3: one wave = 4 nodes; 16-lane quad owns a row (uint4/lane) ----------
// A[n] = relu(BN( dinv[n]*(sum_in Hs[s] + Hs[n]) + gb ));  LAST=1 also emits normalized rows
template<int LAST>
__global__ __launch_bounds__(256) void k_agg(
    const ushort_t* __restrict__ Hs, const int* __restrict__ rowstart,
    const ushort_t* __restrict__ esrc, const float* __restrict__ dinv,
    const float* __restrict__ gb, const float* __restrict__ gam,
    const float* __restrict__ bet, const float* __restrict__ mean,
    const float* __restrict__ var, ushort_t* __restrict__ A,
    ushort_t* __restrict__ Nrm) {
    int wid = (blockIdx.x * blockDim.x + threadIdx.x) >> 6;
    int l = threadIdx.x & 63;
    int q = l >> 4, cl = l & 15;
    int n = wid * 4 + q;
    const uint4* Hu4 = (const uint4*)Hs;
    int beg = rowstart[n], end = rowstart[n + 1];
    float di = dinv[n];
    uint4 h = Hu4[(size_t)n * 16 + cl];
    float a0 = lo16(h.x), a1 = hi16(h.x), a2 = lo16(h.y), a3 = hi16(h.y);
    float a4 = lo16(h.z), a5 = hi16(h.z), a6 = lo16(h.w), a7 = hi16(h.w);
    int j = beg;
    for (; j + 2 <= end; j += 2) {
        unsigned s0 = esrc[j], s1 = esrc[j + 1];
        uint4 u0 = Hu4[(size_t)s0 * 16 + cl];
        uint4 u1 = Hu4[(size_t)s1 * 16 + cl];
        a0 += lo16(u0.x) + lo16(u1.x); a1 += hi16(u0.x) + hi16(u1.x);
        a2 += lo16(u0.y) + lo16(u1.y); a3 += hi16(u0.y) + hi16(u1.y);
        a4 += lo16(u0.z) + lo16(u1.z); a5 += hi16(u0.z) + hi16(u1.z);
        a6 += lo16(u0.w) + lo16(u1.w); a7 += hi16(u0.w) + hi16(u1.w);
    }
    if (j < end) {
        unsigned s0 = esrc[j];
        uint4 u0 = Hu4[(size_t)s0 * 16 + cl];
        a0 += lo16(u0.x); a1 += hi16(u0.x);
        a2 += lo16(u0.y); a3 += hi16(u0.y);
        a4 += lo16(u0.z); a5 += hi16(u0.z);
        a6 += lo16(u0.w); a7 += hi16(u0.w);
    }
    int c = cl * 8;
    float4 gbA = *(const float4*)&gb[c],   gbB = *(const float4*)&gb[c + 4];
    float4 gmA = *(const float4*)&gam[c],  gmB = *(const float4*)&gam[c + 4];
    float4 btA = *(const float4*)&bet[c],  btB = *(const float4*)&bet[c + 4];
    float4 mnA = *(const float4*)&mean[c], mnB = *(const float4*)&mean[c + 4];
    float4 vrA = *(const float4*)&var[c],  vrB = *(const float4*)&var[c + 4];
    float o0 = (a0 * di + gbA.x - mnA.x) * (gmA.x * rsqrtf(vrA.x + 1e-5f)) + btA.x;
    float o1 = (a1 * di + gbA.y - mnA.y) * (gmA.y * rsqrtf(vrA.y + 1e-5f)) + btA.y;
    float o2 = (a2 * di + gbA.z - mnA.z) * (gmA.z * rsqrtf(vrA.z + 1e-5f)) + btA.z;
    float o3 = (a3 * di + gbA.w - mnA.w) * (gmA.w * rsqrtf(vrA.w + 1e-5f)) + btA.w;
    float o4 = (a4 * di + gbB.x - mnB.x) * (gmB.x * rsqrtf(vrB.x + 1e-5f)) + btB.x;
    float o5 = (a5 * di + gbB.y - mnB.y) * (gmB.y * rsqrtf(vrB.y + 1e-5f)) + btB.y;
    float o6 = (a6 * di + gbB.z - mnB.z) * (gmB.z * rsqrtf(vrB.z + 1e-5f)) + btB.z;
    float o7 = (a7 * di + gbB.w - mnB.w) * (gmB.w * rsqrtf(vrB.w + 1e-5f)) + btB.w;
    uint4 av;
    av.x = pack2(fmaxf(o0, 0.f), fmaxf(o1, 0.f));
    av.y = pack2(fmaxf(o2, 0.f), fmaxf(o3, 0.f));
    av.z = pack2(fmaxf(o4, 0.f), fmaxf(o5, 0.f));
    av.w = pack2(fmaxf(o6, 0.f), fmaxf(o7, 0.f));
    ((uint4*)A)[(size_t)n * 16 + cl] = av;
    if (LAST) {
        float r0 = lo16(av.x), r1 = hi16(av.x), r2 = lo16(av.y), r3 = hi16(av.y);
        float r4 = lo16(av.z), r5 = hi16(av.z), r6 = lo16(av.w), r7 = hi16(av.w);
        float ss = ((r0 * r0 + r1 * r1) + (r2 * r2 + r3 * r3)) +
                   ((r4 * r4 + r5 * r5) + (r6 * r6 + r7 * r7));
        #pragma unroll
        for (int o = 8; o > 0; o >>= 1) ss += __shfl_xor(ss, o);
        float inv = 1.0f / fmaxf(sqrtf(ss), 1e-8f);
        uint4 nv;
        nv.x = pack2(r0 * inv, r1 * inv);
        nv.y = pack2(r2 * inv, r3 * inv);
        nv.z = pack2(r4 * inv, r5 * inv);
        nv.w = pack2(r6 * inv, r7 * inv);
        ((uint4*)Nrm)[(size_t)n * 16 + cl] = nv;
    }
}

// ---------- per-graph softmax weights (also zeroes G and hist) ----------
__global__ __launch_bounds__(512) void k_smax(const float* __restrict__ S,
                                              float* __restrict__ W,
                                              float* __restrict__ G,
                                              float* __restrict__ hist) {
    int b = blockIdx.x;
    int t = threadIdx.x;
    if (t < DD) G[b * DD + t] = 0.f;
    if (b < BB && t >= DD && t < DD + NBINS) hist[b * NBINS + (t - DD)] = 0.f;
    __shared__ float red[512];
    float s = S[b * NPG + t];
    red[t] = s;
    __syncthreads();
    for (int o = 256; o > 0; o >>= 1) { if (t < o) red[t] = fmaxf(red[t], red[t + o]); __syncthreads(); }
    float m = red[0];
    __syncthreads();
    float e = expf(s - m);
    red[t] = e;
    __syncthreads();
    for (int o = 256; o > 0; o >>= 1) { if (t < o) red[t] += red[t + o]; __syncthreads(); }
    W[b * NPG + t] = e / red[0];
}

// ---------- weighted sum ----------
__global__ __launch_bounds__(256) void k_pool(const float* __restrict__ W,
                                              const ushort_t* __restrict__ Emb,
                                              float* __restrict__ G) {
    int blk = blockIdx.x;
    int b = blk >> 3, ch = blk & 7;
    int t = threadIdx.x;
    int l = t & 63, grp = t >> 6;
    int nbase = b * NPG + ch * 64 + grp * 16;
    float a0 = 0.f, a1 = 0.f;
    for (int i = 0; i < 16; i++) {
        float wv = W[nbase + i];
        unsigned u = ((const unsigned*)(Emb + (size_t)(nbase + i) * DD))[l];
        a0 += wv * lo16(u);
        a1 += wv * hi16(u);
    }
    __shared__ float red0[256], red1[256];
    red0[t] = a0; red1[t] = a1;
    __syncthreads();
    if (t < 64) {
        float s0 = red0[t] + red0[t + 64] + red0[t + 128] + red0[t + 192];
        float s1 = red1[t] + red1[t + 64] + red1[t + 128] + red1[t + 192];
        atomicAdd(&G[b * DD + 2 * t], s0);
        atomicAdd(&G[b * DD + 2 * t + 1], s1);
    }
}

// ---------- MFMA cosine-sim histogram ----------
__global__ __launch_bounds__(256) void k_hist(const ushort_t* __restrict__ N1,
                                              const ushort_t* __restrict__ N2,
                                              float* __restrict__ Hist) {
    __shared__ int hl[256 * 17];
    __shared__ float hred[NBINS];
    int t = threadIdx.x, w = t >> 6, l = t & 63;
    int lr = l & 15, lg = l >> 4;
    int g = blockIdx.x >> 4, ti = (blockIdx.x >> 2) & 3, tj = blockIdx.x & 3;
    #pragma unroll
    for (int i = t; i < 256 * 17; i += 256) hl[i] = 0;
    if (t < NBINS) hred[t] = 0.f;
    __syncthreads();

    const ushort_t* arow = N1 + ((size_t)g * NPG + ti * 128 + w * 32 + lr) * DD + lg * 8;
    const ushort_t* brow = N2 + ((size_t)g * NPG + tj * 128 + lr) * DD + lg * 8;
    f32x4 acc[2][8];
    #pragma unroll
    for (int r = 0; r < 2; r++)
        #pragma unroll
        for (int c = 0; c < 8; c++) acc[r][c] = (f32x4){0.f, 0.f, 0.f, 0.f};
    for (int kt = 0; kt < 4; kt++) {
        short8 a0 = *(const short8*)(arow + kt * 32);
        short8 a1 = *(const short8*)(arow + (size_t)16 * DD + kt * 32);
        #pragma unroll
        for (int c = 0; c < 8; c++) {
            short8 b = *(const short8*)(brow + (size_t)c * 16 * DD + kt * 32);
            acc[0][c] = __builtin_amdgcn_mfma_f32_16x16x32_bf16(a0, b, acc[0][c], 0, 0, 0);
            acc[1][c] = __builtin_amdgcn_mfma_f32_16x16x32_bf16(a1, b, acc[1][c], 0, 0, 0);
        }
    }
    int base = t * 17;
    #pragma unroll
    for (int r = 0; r < 2; r++)
        #pragma unroll
        for (int c = 0; c < 8; c++)
            #pragma unroll
            for (int q = 0; q < 4; q++) {
                float sim = acc[r][c][q];
                float v = floorf((sim + 1.0f) * 8.0f);
                v = fminf(fmaxf(v, 0.f), 15.f);
                atomicAdd(&hl[base + (int)v], 1);
            }
    __syncthreads();
    int bin = t & 15, r0 = (t >> 4) * 16;
    int s = 0;
    #pragma unroll
    for (int r = 0; r < 16; r++) s += hl[(r0 + r) * 17 + bin];
    atomicAdd(&hred[bin], (float)s);
    __syncthreads();
    if (t < NBINS) atomicAdd(&Hist[g * NBINS + t], hred[t]);
}

// ---------- NTN bilinear ----------
__global__ __launch_bounds__(128) void k_ntn(const float* __restrict__ G1,
                                             const float* __restrict__ G2,
                                             const float* __restrict__ T,
                                             const float* __restrict__ tb,
                                             float* __restrict__ TP) {
    int b = blockIdx.x, k = blockIdx.y;
    int e = threadIdx.x;
    const float* Tk = T + (size_t)k * DD * DD;
    float g2e = G2[b * DD + e];
    float acc = 0.f;
    for (int d = 0; d < DD; d++) acc += G1[b * DD + d] * Tk[(size_t)d * DD + e];
    float val = acc * g2e;
    #pragma unroll
    for (int o = 32; o > 0; o >>= 1) val += __shfl_down(val, o);
    __shared__ float ps[2];
    if ((e & 63) == 0) ps[e >> 6] = val;
    __syncthreads();
    if (e == 0) TP[b * KNTN + k] = ps[0] + ps[1] + tb[k];
}

__global__ void k_final(const float* __restrict__ TP, const float* __restrict__ Hist,
                        const float* nw1, const float* nb1, const float* nw2, const float* nb2,
                        const float* nw3, const float* nb3,
                        const float* hw1, const float* hb1, const float* hw2, const float* hb2,
                        const float* fw1, const float* fb1, const float* fw2, const float* fb2,
                        float* __restrict__ out) {
    int b = threadIdx.x;
    float h1[32];
    #pragma unroll
    for (int i = 0; i < 32; i++) {
        float a = nb1[i];
        for (int k = 0; k < 16; k++) a += TP[b * 16 + k] * nw1[i * 16 + k];
        h1[i] = fmaxf(a, 0.f);
    }
    float h2[16];
    #pragma unroll
    for (int j = 0; j < 16; j++) {
        float a = nb2[j];
        for (int i = 0; i < 32; i++) a += h1[i] * nw2[j * 32 + i];
        h2[j] = fmaxf(a, 0.f);
    }
    float nt = nb3[0];
    for (int j = 0; j < 16; j++) nt += h2[j] * nw3[j];
    nt = 1.f / (1.f + expf(-nt));
    float hh[16]; float sum = 0.f;
    for (int k = 0; k < 16; k++) { hh[k] = Hist[b * 16 + k]; sum += hh[k]; }
    float inv = 1.f / (sum + 1e-8f);
    for (int k = 0; k < 16; k++) hh[k] *= inv;
    float g1v[32];
    #pragma unroll
    for (int i = 0; i < 32; i++) {
        float a = hb1[i];
        for (int k = 0; k < 16; k++) a += hh[k] * hw1[i * 16 + k];
        g1v[i] = fmaxf(a, 0.f);
    }
    float hemb[16];
    #pragma unroll
    for (int j = 0; j < 16; j++) {
        float a = hb2[j];
        for (int i = 0; i < 32; i++) a += g1v[i] * hw2[j * 32 + i];
        hemb[j] = a;
    }
    float comb[17];
    comb[0] = nt;
    for (int j = 0; j < 16; j++) comb[1 + j] = hemb[j];
    float f1[8];
    #pragma unroll
    for (int i = 0; i < 8; i++) {
        float a = fb1[i];
        for (int j = 0; j < 17; j++) a += comb[j] * fw1[i * 17 + j];
        f1[i] = fmaxf(a, 0.f);
    }
    float o = fb2[0];
    for (int i = 0; i < 8; i++) o += f1[i] * fw2[i];
    out[b] = 1.f / (1.f + expf(-o));
}

extern "C" void kernel_launch(void* const* d_in, const int* in_sizes, int n_in,
                              void* d_out, int out_size, void* d_ws, size_t ws_size,
                              hipStream_t stream) {
    const float* x1    = (const float*)d_in[0];
    const float* x2    = (const float*)d_in[1];
    const int*   ei1   = (const int*)d_in[2];
    const int*   ei2   = (const int*)d_in[3];
    const float* gcn_w = (const float*)d_in[6];
    const float* gcn_b = (const float*)d_in[7];
    const float* bn_g  = (const float*)d_in[8];
    const float* bn_b  = (const float*)d_in[9];
    const float* bn_m  = (const float*)d_in[10];
    const float* bn_v  = (const float*)d_in[11];
    const float* ctx_b = (const float*)d_in[13];
    const float* att_w = (const float*)d_in[14];
    const float* att_b = (const float*)d_in[15];
    const float* ntn_T = (const float*)d_in[16];
    const float* ntn_b = (const float*)d_in[17];
    const float* nw1 = (const float*)d_in[18];
    const float* nb1 = (const float*)d_in[19];
    const float* nw2 = (const float*)d_in[20];
    const float* nb2 = (const float*)d_in[21];
    const float* nw3 = (const float*)d_in[22];
    const float* nb3 = (const float*)d_in[23];
    const float* hw1 = (const float*)d_in[24];
    const float* hb1 = (const float*)d_in[25];
    const float* hw2 = (const float*)d_in[26];
    const float* hb2 = (const float*)d_in[27];
    const float* fw1 = (const float*)d_in[28];
    const float* fb1 = (const float*)d_in[29];
    const float* fw2 = (const float*)d_in[30];
    const float* fb2 = (const float*)d_in[31];
    float* out = (float*)d_out;

    ushort_t* Xbf = (ushort_t*)d_ws;        // 2*NND (reused as Nrm)
    ushort_t* Abf = Xbf + 2 * (size_t)NND;  // 2*NND
    ushort_t* Hbf = Abf + 2 * (size_t)NND;  // 2*NND
    ushort_t* wbf = Hbf + 2 * (size_t)NND;  // 4*DD*DD
    float* dinv = (float*)(wbf + 4 * DD * DD);  // 2*NN
    float* S    = dinv + 2 * NN;                // 2*NN
    float* Wsm  = S + 2 * NN;                   // 2*NN
    float* G    = Wsm + 2 * NN;                 // 2*BB*DD
    float* hist = G + 2 * BB * DD;              // BB*NBINS
    float* tp   = hist + BB * NBINS;            // BB*KNTN
    int* degi  = (int*)(tp + BB * KNTN);        // 2*NN
    int* rowst = degi + 2 * NN;                 // 2*NN+1
    int* bcur  = rowst + 2 * NN + 1;            // NBKT
    ushort_t* esrc = (ushort_t*)(bcur + NBKT);  // 2*EE u16
    unsigned* ibuf = (unsigned*)(esrc + 2 * EE);// NBKT*BCAP

    k_wconv<<<4 * DD * DD / 4 / 256, 256, 0, stream>>>(gcn_w, (const float*)d_in[12], wbf, bcur);
    k_bucket<<<2 * EE / 2048, 256, 0, stream>>>(ei1, ei2, bcur, ibuf);
    k_bcnt<<<NBKT, 256, 0, stream>>>(ibuf, bcur, degi, dinv);
    k_scan2<<<1, 1024, 0, stream>>>(degi, rowst);
    k_bplace<<<NBKT, 256, 0, stream>>>(ibuf, bcur, rowst, esrc);
    k_xconv<<<2 * NND / 4 / 256, 256, 0, stream>>>(x1, x2, Xbf);

    for (int l = 0; l < LL; l++) {
        k_mgemm<0><<<2 * NN / 64, 256, 0, stream>>>(l == 0 ? Xbf : Abf,
                                                    wbf + (size_t)l * DD * DD,
                                                    nullptr, Hbf, nullptr, nullptr, nullptr, dinv);
        if (l < LL - 1)
            k_agg<0><<<2 * NN / 16, 256, 0, stream>>>(Hbf, rowst, esrc, dinv,
                                                      gcn_b + l * DD, bn_g + l * DD, bn_b + l * DD,
                                                      bn_m + l * DD, bn_v + l * DD, Abf, nullptr);
        else
            k_agg<1><<<2 * NN / 16, 256, 0, stream>>>(Hbf, rowst, esrc, dinv,
                                                      gcn_b + l * DD, bn_g + l * DD, bn_b + l * DD,
                                                      bn_m + l * DD, bn_v + l * DD, Abf, Xbf);
    }
    k_mgemm<2><<<2 * NN / 64, 256, 0, stream>>>(Abf, wbf + 3 * DD * DD, ctx_b,
                                                nullptr, att_w, att_b, S, nullptr);
    k_smax<<<2 * BB, 512, 0, stream>>>(S, Wsm, G, hist);
    k_pool<<<2 * BB * 8, 256, 0, stream>>>(Wsm, Abf, G);
    k_hist<<<BB * 16, 256, 0, stream>>>(Xbf, Xbf + NND, hist);
    k_ntn<<<dim3(BB, KNTN), 128, 0, stream>>>(G, G + BB * DD, ntn_T, ntn_b, tp);
    k_final<<<1, 64, 0, stream>>>(tp, hist, nw1, nb1, nw2, nb2, nw3, nb3,
                                  hw1, hb1, hw2, hb2, fw1, fb1, fw2, fb2, out);
}

// Round 8
// 304.041 us; speedup vs baseline: 19.6004x; 1.1666x over previous
//
#include <hip/hip_runtime.h>
#include <math.h>

#define NN 32768      // nodes per side
#define BB 64         // graphs per side
#define NPG 512
#define DD 128
#define LL 3
#define EE 524288     // edges per side
#define NBINS 16
#define KNTN 16
#define NND (NN*DD)
#define NBKT 128      // CSR buckets (512 nodes each)
#define BCAP 10240    // bucket edge capacity (mean 8192, std ~90)

typedef unsigned short ushort_t;
typedef __attribute__((ext_vector_type(8))) short short8;
typedef __attribute__((ext_vector_type(4))) float f32x4;

__device__ __forceinline__ ushort_t f2bf(float f) {
    unsigned u = __builtin_bit_cast(unsigned, f);
    u += 0x7FFFu + ((u >> 16) & 1u);
    return (ushort_t)(u >> 16);
}
__device__ __forceinline__ float bf2f(ushort_t h) {
    unsigned u = ((unsigned)h) << 16;
    return __builtin_bit_cast(float, u);
}
__device__ __forceinline__ unsigned pack2(float a, float b) {
    return (unsigned)f2bf(a) | ((unsigned)f2bf(b) << 16);
}
__device__ __forceinline__ float lo16(unsigned u) { return __builtin_bit_cast(float, u << 16); }
__device__ __forceinline__ float hi16(unsigned u) { return __builtin_bit_cast(float, u & 0xffff0000u); }

// ---------- prep: x->bf16, weights->bf16, BN fold, bcur zero ----------
__global__ __launch_bounds__(256) void k_prep(const float* __restrict__ x1,
                                              const float* __restrict__ x2,
                                              const float* __restrict__ gw,
                                              const float* __restrict__ cw,
                                              const float* __restrict__ gcn_b,
                                              const float* __restrict__ bn_g,
                                              const float* __restrict__ bn_b,
                                              const float* __restrict__ bn_m,
                                              const float* __restrict__ bn_v,
                                              ushort_t* __restrict__ Xbf,
                                              ushort_t* __restrict__ wbf,
                                              float* __restrict__ bnsc,
                                              float* __restrict__ bnsh,
                                              int* __restrict__ bcur) {
    int b = blockIdx.x, t = threadIdx.x;
    if (b < 8192) {
        int i = b * 256 + t;
        const float4 v = (i < NND / 4) ? ((const float4*)x1)[i] : ((const float4*)x2)[i - NND / 4];
        uint2 o;
        o.x = pack2(v.x, v.y);
        o.y = pack2(v.z, v.w);
        ((uint2*)Xbf)[i] = o;
    } else if (b < 8256) {
        int i = (b - 8192) * 256 + t;
        const float4 v = (i < 3 * DD * DD / 4) ? ((const float4*)gw)[i]
                                               : ((const float4*)cw)[i - 3 * DD * DD / 4];
        uint2 o;
        o.x = pack2(v.x, v.y);
        o.y = pack2(v.z, v.w);
        ((uint2*)wbf)[i] = o;
    } else {
        if (t < NBKT) bcur[t] = 0;
        if (t < DD) {
            #pragma unroll
            for (int l = 0; l < LL; l++) {
                int c = l * DD + t;
                float sc = bn_g[c] * rsqrtf(bn_v[c] + 1e-5f);
                bnsc[c] = sc;
                bnsh[c] = (gcn_b[c] - bn_m[c]) * sc + bn_b[c];
            }
        }
    }
}

// ---------- CSR build pass A: bucket edges by dst>>9, coalesced region writes ----------
__global__ __launch_bounds__(256) void k_bucket(const int* __restrict__ ei1,
                                                const int* __restrict__ ei2,
                                                int* __restrict__ bcur,
                                                unsigned* __restrict__ ibuf) {
    __shared__ int cnt[NBKT], off[NBKT], gb[NBKT];
    __shared__ unsigned stage[2048];
    int t = threadIdx.x;
    int blk = blockIdx.x;                 // 0..511; 0..255 side1, 256..511 side2
    const int* ei = (blk < 256) ? ei1 : ei2;
    int ebase = (blk & 255) * 2048;
    int addn = (blk < 256) ? 0 : NN;
    for (int i = t; i < NBKT; i += 256) cnt[i] = 0;
    __syncthreads();
    unsigned pk[8]; int rk[8];
    #pragma unroll
    for (int k = 0; k < 8; k++) {
        int e = ebase + t + k * 256;
        int s = ei[e] + addn;
        int d = ei[EE + e] + addn;
        pk[k] = (unsigned)s | ((unsigned)d << 16);
    }
    #pragma unroll
    for (int k = 0; k < 8; k++) {
        int bk = pk[k] >> 25;
        rk[k] = atomicAdd(&cnt[bk], 1);
    }
    __syncthreads();
    if (t < NBKT) off[t] = cnt[t];
    __syncthreads();
    for (int o = 1; o < NBKT; o <<= 1) {
        int v = 0;
        if (t < NBKT && t >= o) v = off[t - o];
        __syncthreads();
        if (t < NBKT) off[t] += v;
        __syncthreads();
    }
    #pragma unroll
    for (int k = 0; k < 8; k++) {
        int bk = pk[k] >> 25;
        stage[off[bk] - cnt[bk] + rk[k]] = pk[k];
    }
    if (t < NBKT) {
        int c = cnt[t];
        gb[t] = c > 0 ? atomicAdd(&bcur[t], c) : 0;
    }
    __syncthreads();
    #pragma unroll
    for (int k = 0; k < 8; k++) {
        int idx = t + k * 256;
        unsigned p = stage[idx];
        int bk = p >> 25;
        int pos = idx - (off[bk] - cnt[bk]);
        ibuf[(size_t)bk * BCAP + gb[bk] + pos] = p;
    }
}

// ---------- pass B1: per-bucket degree count + dinv + bucket-local rowstart ----------
__global__ __launch_bounds__(256) void k_bcnt(const unsigned* __restrict__ ibuf,
                                              const int* __restrict__ bcur,
                                              int* __restrict__ deg,
                                              float* __restrict__ dinv,
                                              int* __restrict__ rowstart) {
    __shared__ int cnt[512];
    __shared__ int ps[256];
    int bk = blockIdx.x, t = threadIdx.x;
    for (int i = t; i < 512; i += 256) cnt[i] = 0;
    __syncthreads();
    int n = bcur[bk];
    const unsigned* buf = ibuf + (size_t)bk * BCAP;
    for (int i = t; i < n; i += 256) {
        int dl = (buf[i] >> 16) & 511;
        atomicAdd(&cnt[dl], 1);
    }
    __syncthreads();
    int c0 = cnt[2 * t], c1 = cnt[2 * t + 1];
    ps[t] = c0 + c1;
    __syncthreads();
    for (int o = 1; o < 256; o <<= 1) {
        int v = (t >= o) ? ps[t - o] : 0;
        __syncthreads();
        ps[t] += v;
        __syncthreads();
    }
    int excl = (t == 0) ? 0 : ps[t - 1];
    int base = bk * BCAP;
    int g0 = bk * 512 + 2 * t, g1 = g0 + 1;
    deg[g0] = c0; deg[g1] = c1;
    dinv[g0] = rsqrtf((float)c0 + 1.0f);
    dinv[g1] = rsqrtf((float)c1 + 1.0f);
    rowstart[g0] = base + excl;
    rowstart[g1] = base + excl + c0;
}

// ---------- pass B2: per-bucket placement into esrc (u16, localized writes) ----------
__global__ __launch_bounds__(256) void k_bplace(const unsigned* __restrict__ ibuf,
                                                const int* __restrict__ bcur,
                                                const int* __restrict__ rowstart,
                                                ushort_t* __restrict__ esrc) {
    __shared__ int lcur[512];
    int bk = blockIdx.x, t = threadIdx.x;
    for (int i = t; i < 512; i += 256) lcur[i] = rowstart[bk * 512 + i];
    __syncthreads();
    int n = bcur[bk];
    const unsigned* buf = ibuf + (size_t)bk * BCAP;
    for (int i = t; i < n; i += 256) {
        unsigned p = buf[i];
        int dl = (p >> 16) & 511;
        int slot = atomicAdd(&lcur[dl], 1);
        esrc[slot] = (ushort_t)(p & 0xffffu);
    }
}

// ---------- MFMA GEMM: Out[n][j] = sum_d X[n][d]*W[j][d] ----------
template<int EPI>
__global__ __launch_bounds__(256) void k_mgemm(const ushort_t* __restrict__ X,
                                               const ushort_t* __restrict__ Wb,
                                               const float* __restrict__ bias,
                                               ushort_t* __restrict__ Out,
                                               const float* __restrict__ aw,
                                               const float* __restrict__ ab,
                                               float* __restrict__ Sout,
                                               const float* __restrict__ dscale) {
    int w = threadIdx.x >> 6, l = threadIdx.x & 63;
    int rw = blockIdx.x * 64 + w * 16;
    int lr = l & 15, lg = l >> 4;
    f32x4 acc[8];
    #pragma unroll
    for (int c = 0; c < 8; c++) acc[c] = (f32x4){0.f, 0.f, 0.f, 0.f};
    const ushort_t* xrow = X + (size_t)(rw + lr) * DD + lg * 8;
    const ushort_t* wrow = Wb + (size_t)lr * DD + lg * 8;
    for (int kt = 0; kt < 4; kt++) {
        short8 a = *(const short8*)(xrow + kt * 32);
        #pragma unroll
        for (int c = 0; c < 8; c++) {
            short8 b = *(const short8*)(wrow + (size_t)c * 16 * DD + kt * 32);
            acc[c] = __builtin_amdgcn_mfma_f32_16x16x32_bf16(a, b, acc[c], 0, 0, 0);
        }
    }
    if (EPI == 0) {
        float ds[4];
        #pragma unroll
        for (int q = 0; q < 4; q++) ds[q] = dscale[rw + lg * 4 + q];
        #pragma unroll
        for (int c = 0; c < 8; c++) {
            int col = c * 16 + lr;
            #pragma unroll
            for (int q = 0; q < 4; q++)
                Out[(size_t)(rw + lg * 4 + q) * DD + col] = f2bf(acc[c][q] * ds[q]);
        }
    } else {
        float rs0 = 0.f, rs1 = 0.f, rs2 = 0.f, rs3 = 0.f;
        #pragma unroll
        for (int c = 0; c < 8; c++) {
            int col = c * 16 + lr;
            float bv = bias[col], wv = aw[col];
            rs0 += tanhf(acc[c][0] + bv) * wv;
            rs1 += tanhf(acc[c][1] + bv) * wv;
            rs2 += tanhf(acc[c][2] + bv) * wv;
            rs3 += tanhf(acc[c][3] + bv) * wv;
        }
        #pragma unroll
        for (int m = 1; m < 16; m <<= 1) {
            rs0 += __shfl_xor(rs0, m);
            rs1 += __shfl_xor(rs1, m);
            rs2 += __shfl_xor(rs2, m);
            rs3 += __shfl_xor(rs3, m);
        }
        if (lr == 0) {
            float a0 = ab[0];
            Sout[rw + lg * 4 + 0] = rs0 + a0;
            Sout[rw + lg * 4 + 1] = rs1 + a0;
            Sout[rw + lg * 4 + 2] = rs2 + a0;
            Sout[rw + lg * 4 + 3] = rs3 + a0;
        }
    }
}

#define GATHER(u, s) uint4 u = Hu4[(size_t)(s) * 16 + cl]
#define ACCUM(u) \
    a0 += lo16(u.x); a1 += hi16(u.x); a2 += lo16(u.y); a3 += hi16(u.y); \
    a4 += lo16(u.z); a5 += hi16(u.z); a6 += lo16(u.w); a7 += hi16(u.w)

// ---------- aggregate v4: one wave = 4 nodes; 16-lane quad owns a row; unroll-8 MLP ----------
// A[n] = relu( (sum*di)*bnsc + bnsh );  LAST=1 also emits L2-normalized rows
template<int LAST>
__global__ __launch_bounds__(256) void k_agg(
    const ushort_t* __restrict__ Hs, const int* __restrict__ rowstart,
    const int* __restrict__ deg, const ushort_t* __restrict__ esrc,
    const float* __restrict__ dinv, const float* __restrict__ bnsc,
    const float* __restrict__ bnsh, ushort_t* __restrict__ A,
    ushort_t* __restrict__ Nrm) {
    int wid = (blockIdx.x * blockDim.x + threadIdx.x) >> 6;
    int l = threadIdx.x & 63;
    int q = l >> 4, cl = l & 15;
    int n = wid * 4 + q;
    const uint4* Hu4 = (const uint4*)Hs;
    int beg = rowstart[n];
    int end = beg + deg[n];
    float di = dinv[n];
    uint4 h = Hu4[(size_t)n * 16 + cl];
    float a0 = lo16(h.x), a1 = hi16(h.x), a2 = lo16(h.y), a3 = hi16(h.y);
    float a4 = lo16(h.z), a5 = hi16(h.z), a6 = lo16(h.w), a7 = hi16(h.w);
    int j = beg;
    for (; j + 8 <= end; j += 8) {
        unsigned s0 = esrc[j + 0], s1 = esrc[j + 1], s2 = esrc[j + 2], s3 = esrc[j + 3];
        unsigned s4 = esrc[j + 4], s5 = esrc[j + 5], s6 = esrc[j + 6], s7 = esrc[j + 7];
        GATHER(u0, s0); GATHER(u1, s1); GATHER(u2, s2); GATHER(u3, s3);
        GATHER(u4, s4); GATHER(u5, s5); GATHER(u6, s6); GATHER(u7, s7);
        ACCUM(u0); ACCUM(u1); ACCUM(u2); ACCUM(u3);
        ACCUM(u4); ACCUM(u5); ACCUM(u6); ACCUM(u7);
    }
    for (; j + 2 <= end; j += 2) {
        unsigned s0 = esrc[j], s1 = esrc[j + 1];
        GATHER(u0, s0); GATHER(u1, s1);
        ACCUM(u0); ACCUM(u1);
    }
    if (j < end) {
        unsigned s0 = esrc[j];
        GATHER(u0, s0);
        ACCUM(u0);
    }
    int c = cl * 8;
    float4 scA = *(const float4*)&bnsc[c], scB = *(const float4*)&bnsc[c + 4];
    float4 shA = *(const float4*)&bnsh[c], shB = *(const float4*)&bnsh[c + 4];
    float o0 = fmaf(a0 * di, scA.x, shA.x);
    float o1 = fmaf(a1 * di, scA.y, shA.y);
    float o2 = fmaf(a2 * di, scA.z, shA.z);
    float o3 = fmaf(a3 * di, scA.w, shA.w);
    float o4 = fmaf(a4 * di, scB.x, shB.x);
    float o5 = fmaf(a5 * di, scB.y, shB.y);
    float o6 = fmaf(a6 * di, scB.z, shB.z);
    float o7 = fmaf(a7 * di, scB.w, shB.w);
    uint4 av;
    av.x = pack2(fmaxf(o0, 0.f), fmaxf(o1, 0.f));
    av.y = pack2(fmaxf(o2, 0.f), fmaxf(o3, 0.f));
    av.z = pack2(fmaxf(o4, 0.f), fmaxf(o5, 0.f));
    av.w = pack2(fmaxf(o6, 0.f), fmaxf(o7, 0.f));
    ((uint4*)A)[(size_t)n * 16 + cl] = av;
    if (LAST) {
        float r0 = lo16(av.x), r1 = hi16(av.x), r2 = lo16(av.y), r3 = hi16(av.y);
        float r4 = lo16(av.z), r5 = hi16(av.z), r6 = lo16(av.w), r7 = hi16(av.w);
        float ss = ((r0 * r0 + r1 * r1) + (r2 * r2 + r3 * r3)) +
                   ((r4 * r4 + r5 * r5) + (r6 * r6 + r7 * r7));
        #pragma unroll
        for (int o = 8; o > 0; o >>= 1) ss += __shfl_xor(ss, o);
        float inv = 1.0f / fmaxf(sqrtf(ss), 1e-8f);
        uint4 nv;
        nv.x = pack2(r0 * inv, r1 * inv);
        nv.y = pack2(r2 * inv, r3 * inv);
        nv.z = pack2(r4 * inv, r5 * inv);
        nv.w = pack2(r6 * inv, r7 * inv);
        ((uint4*)Nrm)[(size_t)n * 16 + cl] = nv;
    }
}

// ---------- per-graph softmax weights (also zeroes G and hist) ----------
__global__ __launch_bounds__(512) void k_smax(const float* __restrict__ S,
                                              float* __restrict__ W,
                                              float* __restrict__ G,
                                              float* __restrict__ hist) {
    int b = blockIdx.x;
    int t = threadIdx.x;
    if (t < DD) G[b * DD + t] = 0.f;
    if (b < BB && t >= DD && t < DD + NBINS) hist[b * NBINS + (t - DD)] = 0.f;
    __shared__ float red[512];
    float s = S[b * NPG + t];
    red[t] = s;
    __syncthreads();
    for (int o = 256; o > 0; o >>= 1) { if (t < o) red[t] = fmaxf(red[t], red[t + o]); __syncthreads(); }
    float m = red[0];
    __syncthreads();
    float e = expf(s - m);
    red[t] = e;
    __syncthreads();
    for (int o = 256; o > 0; o >>= 1) { if (t < o) red[t] += red[t + o]; __syncthreads(); }
    W[b * NPG + t] = e / red[0];
}

// ---------- weighted sum ----------
__global__ __launch_bounds__(256) void k_pool(const float* __restrict__ W,
                                              const ushort_t* __restrict__ Emb,
                                              float* __restrict__ G) {
    int blk = blockIdx.x;
    int b = blk >> 3, ch = blk & 7;
    int t = threadIdx.x;
    int l = t & 63, grp = t >> 6;
    int nbase = b * NPG + ch * 64 + grp * 16;
    float a0 = 0.f, a1 = 0.f;
    for (int i = 0; i < 16; i++) {
        float wv = W[nbase + i];
        unsigned u = ((const unsigned*)(Emb + (size_t)(nbase + i) * DD))[l];
        a0 += wv * lo16(u);
        a1 += wv * hi16(u);
    }
    __shared__ float red0[256], red1[256];
    red0[t] = a0; red1[t] = a1;
    __syncthreads();
    if (t < 64) {
        float s0 = red0[t] + red0[t + 64] + red0[t + 128] + red0[t + 192];
        float s1 = red1[t] + red1[t + 64] + red1[t + 128] + red1[t + 192];
        atomicAdd(&G[b * DD + 2 * t], s0);
        atomicAdd(&G[b * DD + 2 * t + 1], s1);
    }
}

// ---------- MFMA cosine-sim histogram ----------
__global__ __launch_bounds__(256) void k_hist(const ushort_t* __restrict__ N1,
                                              const ushort_t* __restrict__ N2,
                                              float* __restrict__ Hist) {
    __shared__ int hl[256 * 17];
    __shared__ float hred[NBINS];
    int t = threadIdx.x, w = t >> 6, l = t & 63;
    int lr = l & 15, lg = l >> 4;
    int g = blockIdx.x >> 4, ti = (blockIdx.x >> 2) & 3, tj = blockIdx.x & 3;
    #pragma unroll
    for (int i = t; i < 256 * 17; i += 256) hl[i] = 0;
    if (t < NBINS) hred[t] = 0.f;
    __syncthreads();

    const ushort_t* arow = N1 + ((size_t)g * NPG + ti * 128 + w * 32 + lr) * DD + lg * 8;
    const ushort_t* brow = N2 + ((size_t)g * NPG + tj * 128 + lr) * DD + lg * 8;
    f32x4 acc[2][8];
    #pragma unroll
    for (int r = 0; r < 2; r++)
        #pragma unroll
        for (int c = 0; c < 8; c++) acc[r][c] = (f32x4){0.f, 0.f, 0.f, 0.f};
    for (int kt = 0; kt < 4; kt++) {
        short8 a0 = *(const short8*)(arow + kt * 32);
        short8 a1 = *(const short8*)(arow + (size_t)16 * DD + kt * 32);
        #pragma unroll
        for (int c = 0; c < 8; c++) {
            short8 b = *(const short8*)(brow + (size_t)c * 16 * DD + kt * 32);
            acc[0][c] = __builtin_amdgcn_mfma_f32_16x16x32_bf16(a0, b, acc[0][c], 0, 0, 0);
            acc[1][c] = __builtin_amdgcn_mfma_f32_16x16x32_bf16(a1, b, acc[1][c], 0, 0, 0);
        }
    }
    int base = t * 17;
    #pragma unroll
    for (int r = 0; r < 2; r++)
        #pragma unroll
        for (int c = 0; c < 8; c++)
            #pragma unroll
            for (int q = 0; q < 4; q++) {
                float sim = acc[r][c][q];
                float v = floorf((sim + 1.0f) * 8.0f);
                v = fminf(fmaxf(v, 0.f), 15.f);
                atomicAdd(&hl[base + (int)v], 1);
            }
    __syncthreads();
    int bin = t & 15, r0 = (t >> 4) * 16;
    int s = 0;
    #pragma unroll
    for (int r = 0; r < 16; r++) s += hl[(r0 + r) * 17 + bin];
    atomicAdd(&hred[bin], (float)s);
    __syncthreads();
    if (t < NBINS) atomicAdd(&Hist[g * NBINS + t], hred[t]);
}

// ---------- NTN bilinear ----------
__global__ __launch_bounds__(128) void k_ntn(const float* __restrict__ G1,
                                             const float* __restrict__ G2,
                                             const float* __restrict__ T,
                                             const float* __restrict__ tb,
                                             float* __restrict__ TP) {
    int b = blockIdx.x, k = blockIdx.y;
    int e = threadIdx.x;
    const float* Tk = T + (size_t)k * DD * DD;
    float g2e = G2[b * DD + e];
    float acc = 0.f;
    for (int d = 0; d < DD; d++) acc += G1[b * DD + d] * Tk[(size_t)d * DD + e];
    float val = acc * g2e;
    #pragma unroll
    for (int o = 32; o > 0; o >>= 1) val += __shfl_down(val, o);
    __shared__ float ps[2];
    if ((e & 63) == 0) ps[e >> 6] = val;
    __syncthreads();
    if (e == 0) TP[b * KNTN + k] = ps[0] + ps[1] + tb[k];
}

__global__ void k_final(const float* __restrict__ TP, const float* __restrict__ Hist,
                        const float* nw1, const float* nb1, const float* nw2, const float* nb2,
                        const float* nw3, const float* nb3,
                        const float* hw1, const float* hb1, const float* hw2, const float* hb2,
                        const float* fw1, const float* fb1, const float* fw2, const float* fb2,
                        float* __restrict__ out) {
    int b = threadIdx.x;
    float h1[32];
    #pragma unroll
    for (int i = 0; i < 32; i++) {
        float a = nb1[i];
        for (int k = 0; k < 16; k++) a += TP[b * 16 + k] * nw1[i * 16 + k];
        h1[i] = fmaxf(a, 0.f);
    }
    float h2[16];
    #pragma unroll
    for (int j = 0; j < 16; j++) {
        float a = nb2[j];
        for (int i = 0; i < 32; i++) a += h1[i] * nw2[j * 32 + i];
        h2[j] = fmaxf(a, 0.f);
    }
    float nt = nb3[0];
    for (int j = 0; j < 16; j++) nt += h2[j] * nw3[j];
    nt = 1.f / (1.f + expf(-nt));
    float hh[16]; float sum = 0.f;
    for (int k = 0; k < 16; k++) { hh[k] = Hist[b * 16 + k]; sum += hh[k]; }
    float inv = 1.f / (sum + 1e-8f);
    for (int k = 0; k < 16; k++) hh[k] *= inv;
    float g1v[32];
    #pragma unroll
    for (int i = 0; i < 32; i++) {
        float a = hb1[i];
        for (int k = 0; k < 16; k++) a += hh[k] * hw1[i * 16 + k];
        g1v[i] = fmaxf(a, 0.f);
    }
    float hemb[16];
    #pragma unroll
    for (int j = 0; j < 16; j++) {
        float a = hb2[j];
        for (int i = 0; i < 32; i++) a += g1v[i] * hw2[j * 32 + i];
        hemb[j] = a;
    }
    float comb[17];
    comb[0] = nt;
    for (int j = 0; j < 16; j++) comb[1 + j] = hemb[j];
    float f1[8];
    #pragma unroll
    for (int i = 0; i < 8; i++) {
        float a = fb1[i];
        for (int j = 0; j < 17; j++) a += comb[j] * fw1[i * 17 + j];
        f1[i] = fmaxf(a, 0.f);
    }
    float o = fb2[0];
    for (int i = 0; i < 8; i++) o += f1[i] * fw2[i];
    out[b] = 1.f / (1.f + expf(-o));
}

extern "C" void kernel_launch(void* const* d_in, const int* in_sizes, int n_in,
                              void* d_out, int out_size, void* d_ws, size_t ws_size,
                              hipStream_t stream) {
    const float* x1    = (const float*)d_in[0];
    const float* x2    = (const float*)d_in[1];
    const int*   ei1   = (const int*)d_in[2];
    const int*   ei2   = (const int*)d_in[3];
    const float* gcn_w = (const float*)d_in[6];
    const float* gcn_b = (const float*)d_in[7];
    const float* bn_g  = (const float*)d_in[8];
    const float* bn_b  = (const float*)d_in[9];
    const float* bn_m  = (const float*)d_in[10];
    const float* bn_v  = (const float*)d_in[11];
    const float* ctx_w = (const float*)d_in[12];
    const float* ctx_b = (const float*)d_in[13];
    const float* att_w = (const float*)d_in[14];
    const float* att_b = (const float*)d_in[15];
    const float* ntn_T = (const float*)d_in[16];
    const float* ntn_b = (const float*)d_in[17];
    const float* nw1 = (const float*)d_in[18];
    const float* nb1 = (const float*)d_in[19];
    const float* nw2 = (const float*)d_in[20];
    const float* nb2 = (const float*)d_in[21];
    const float* nw3 = (const float*)d_in[22];
    const float* nb3 = (const float*)d_in[23];
    const float* hw1 = (const float*)d_in[24];
    const float* hb1 = (const float*)d_in[25];
    const float* hw2 = (const float*)d_in[26];
    const float* hb2 = (const float*)d_in[27];
    const float* fw1 = (const float*)d_in[28];
    const float* fb1 = (const float*)d_in[29];
    const float* fw2 = (const float*)d_in[30];
    const float* fb2 = (const float*)d_in[31];
    float* out = (float*)d_out;

    ushort_t* Xbf = (ushort_t*)d_ws;        // 2*NND (reused as Nrm)
    ushort_t* Abf = Xbf + 2 * (size_t)NND;  // 2*NND
    ushort_t* Hbf = Abf + 2 * (size_t)NND;  // 2*NND
    ushort_t* wbf = Hbf + 2 * (size_t)NND;  // 4*DD*DD
    float* dinv = (float*)(wbf + 4 * DD * DD);  // 2*NN
    float* S    = dinv + 2 * NN;                // 2*NN
    float* Wsm  = S + 2 * NN;                   // 2*NN
    float* G    = Wsm + 2 * NN;                 // 2*BB*DD
    float* hist = G + 2 * BB * DD;              // BB*NBINS
    float* tp   = hist + BB * NBINS;            // BB*KNTN
    float* bnsc = tp + BB * KNTN;               // LL*DD
    float* bnsh = bnsc + LL * DD;               // LL*DD
    int* degi  = (int*)(bnsh + LL * DD);        // 2*NN
    int* rowst = degi + 2 * NN;                 // 2*NN
    int* bcur  = rowst + 2 * NN;                // NBKT
    ushort_t* esrc = (ushort_t*)(bcur + NBKT);  // NBKT*BCAP u16
    unsigned* ibuf = (unsigned*)(esrc + (size_t)NBKT * BCAP);  // NBKT*BCAP u32

    k_prep<<<8257, 256, 0, stream>>>(x1, x2, gcn_w, ctx_w, gcn_b, bn_g, bn_b, bn_m, bn_v,
                                     Xbf, wbf, bnsc, bnsh, bcur);
    k_bucket<<<2 * EE / 2048, 256, 0, stream>>>(ei1, ei2, bcur, ibuf);
    k_bcnt<<<NBKT, 256, 0, stream>>>(ibuf, bcur, degi, dinv, rowst);
    k_bplace<<<NBKT, 256, 0, stream>>>(ibuf, bcur, rowst, esrc);

    for (int l = 0; l < LL; l++) {
        k_mgemm<0><<<2 * NN / 64, 256, 0, stream>>>(l == 0 ? Xbf : Abf,
                                                    wbf + (size_t)l * DD * DD,
                                                    nullptr, Hbf, nullptr, nullptr, nullptr, dinv);
        if (l < LL - 1)
            k_agg<0><<<2 * NN / 16, 256, 0, stream>>>(Hbf, rowst, degi, esrc, dinv,
                                                      bnsc + l * DD, bnsh + l * DD, Abf, nullptr);
        else
            k_agg<1><<<2 * NN / 16, 256, 0, stream>>>(Hbf, rowst, degi, esrc, dinv,
                                                      bnsc + l * DD, bnsh + l * DD, Abf, Xbf);
    }
    k_mgemm<2><<<2 * NN / 64, 256, 0, stream>>>(Abf, wbf + 3 * DD * DD, ctx_b,
                                                nullptr, att_w, att_b, S, nullptr);
    k_smax<<<2 * BB, 512, 0, stream>>>(S, Wsm, G, hist);
    k_pool<<<2 * BB * 8, 256, 0, stream>>>(Wsm, Abf, G);
    k_hist<<<BB * 16, 256, 0, stream>>>(Xbf, Xbf + NND, hist);
    k_ntn<<<dim3(BB, KNTN), 128, 0, stream>>>(G, G + BB * DD, ntn_T, ntn_b, tp);
    k_final<<<1, 64, 0, stream>>>(tp, hist, nw1, nb1, nw2, nb2, nw3, nb3,
                                  hw1, hb1, hw2, hb2, fw1, fb1, fw2, fb2, out);
}

// Round 9
// 293.863 us; speedup vs baseline: 20.2793x; 1.0346x over previous
//
#include <hip/hip_runtime.h>
#include <math.h>

#define NN 32768      // nodes per side
#define BB 64         // graphs per side
#define NPG 512
#define DD 128
#define LL 3
#define EE 524288     // edges per side
#define NBINS 16
#define KNTN 16
#define NND (NN*DD)
#define NBKT 128      // CSR buckets (512 nodes each)
#define BCAP 10240    // bucket edge capacity (mean 8192, std ~90)

typedef unsigned short ushort_t;
typedef __attribute__((ext_vector_type(8))) short short8;
typedef __attribute__((ext_vector_type(4))) float f32x4;

__device__ __forceinline__ ushort_t f2bf(float f) {
    unsigned u = __builtin_bit_cast(unsigned, f);
    u += 0x7FFFu + ((u >> 16) & 1u);
    return (ushort_t)(u >> 16);
}
__device__ __forceinline__ float bf2f(ushort_t h) {
    unsigned u = ((unsigned)h) << 16;
    return __builtin_bit_cast(float, u);
}
__device__ __forceinline__ unsigned pack2(float a, float b) {
    return (unsigned)f2bf(a) | ((unsigned)f2bf(b) << 16);
}
__device__ __forceinline__ float lo16(unsigned u) { return __builtin_bit_cast(float, u << 16); }
__device__ __forceinline__ float hi16(unsigned u) { return __builtin_bit_cast(float, u & 0xffff0000u); }

// ---------- prep: x->bf16, weights->bf16, BN fold, bcur zero, hist zero ----------
__global__ __launch_bounds__(256) void k_prep(const float* __restrict__ x1,
                                              const float* __restrict__ x2,
                                              const float* __restrict__ gw,
                                              const float* __restrict__ cw,
                                              const float* __restrict__ gcn_b,
                                              const float* __restrict__ bn_g,
                                              const float* __restrict__ bn_b,
                                              const float* __restrict__ bn_m,
                                              const float* __restrict__ bn_v,
                                              ushort_t* __restrict__ Xbf,
                                              ushort_t* __restrict__ wbf,
                                              float* __restrict__ bnsc,
                                              float* __restrict__ bnsh,
                                              int* __restrict__ bcur,
                                              float* __restrict__ hist) {
    int b = blockIdx.x, t = threadIdx.x;
    if (b < 8192) {
        int i = b * 256 + t;
        const float4 v = (i < NND / 4) ? ((const float4*)x1)[i] : ((const float4*)x2)[i - NND / 4];
        uint2 o;
        o.x = pack2(v.x, v.y);
        o.y = pack2(v.z, v.w);
        ((uint2*)Xbf)[i] = o;
    } else if (b < 8256) {
        int i = (b - 8192) * 256 + t;
        const float4 v = (i < 3 * DD * DD / 4) ? ((const float4*)gw)[i]
                                               : ((const float4*)cw)[i - 3 * DD * DD / 4];
        uint2 o;
        o.x = pack2(v.x, v.y);
        o.y = pack2(v.z, v.w);
        ((uint2*)wbf)[i] = o;
    } else {
        if (t < NBKT) bcur[t] = 0;
        for (int i = t; i < BB * NBINS; i += 256) hist[i] = 0.f;
        if (t < DD) {
            #pragma unroll
            for (int l = 0; l < LL; l++) {
                int c = l * DD + t;
                float sc = bn_g[c] * rsqrtf(bn_v[c] + 1e-5f);
                bnsc[c] = sc;
                bnsh[c] = (gcn_b[c] - bn_m[c]) * sc + bn_b[c];
            }
        }
    }
}

// ---------- CSR build pass A: bucket edges by dst>>9, coalesced region writes ----------
__global__ __launch_bounds__(256) void k_bucket(const int* __restrict__ ei1,
                                                const int* __restrict__ ei2,
                                                int* __restrict__ bcur,
                                                unsigned* __restrict__ ibuf) {
    __shared__ int cnt[NBKT], off[NBKT], gb[NBKT];
    __shared__ unsigned stage[2048];
    int t = threadIdx.x;
    int blk = blockIdx.x;                 // 0..511; 0..255 side1, 256..511 side2
    const int* ei = (blk < 256) ? ei1 : ei2;
    int ebase = (blk & 255) * 2048;
    int addn = (blk < 256) ? 0 : NN;
    for (int i = t; i < NBKT; i += 256) cnt[i] = 0;
    __syncthreads();
    unsigned pk[8]; int rk[8];
    #pragma unroll
    for (int k = 0; k < 8; k++) {
        int e = ebase + t + k * 256;
        int s = ei[e] + addn;
        int d = ei[EE + e] + addn;
        pk[k] = (unsigned)s | ((unsigned)d << 16);
    }
    #pragma unroll
    for (int k = 0; k < 8; k++) {
        int bk = pk[k] >> 25;
        rk[k] = atomicAdd(&cnt[bk], 1);
    }
    __syncthreads();
    if (t < NBKT) off[t] = cnt[t];
    __syncthreads();
    for (int o = 1; o < NBKT; o <<= 1) {
        int v = 0;
        if (t < NBKT && t >= o) v = off[t - o];
        __syncthreads();
        if (t < NBKT) off[t] += v;
        __syncthreads();
    }
    #pragma unroll
    for (int k = 0; k < 8; k++) {
        int bk = pk[k] >> 25;
        stage[off[bk] - cnt[bk] + rk[k]] = pk[k];
    }
    if (t < NBKT) {
        int c = cnt[t];
        gb[t] = c > 0 ? atomicAdd(&bcur[t], c) : 0;
    }
    __syncthreads();
    #pragma unroll
    for (int k = 0; k < 8; k++) {
        int idx = t + k * 256;
        unsigned p = stage[idx];
        int bk = p >> 25;
        int pos = idx - (off[bk] - cnt[bk]);
        ibuf[(size_t)bk * BCAP + gb[bk] + pos] = p;
    }
}

// ---------- pass B1: per-bucket degree count + dinv + bucket-local rowstart ----------
__global__ __launch_bounds__(256) void k_bcnt(const unsigned* __restrict__ ibuf,
                                              const int* __restrict__ bcur,
                                              int* __restrict__ deg,
                                              float* __restrict__ dinv,
                                              int* __restrict__ rowstart) {
    __shared__ int cnt[512];
    __shared__ int ps[256];
    int bk = blockIdx.x, t = threadIdx.x;
    for (int i = t; i < 512; i += 256) cnt[i] = 0;
    __syncthreads();
    int n = bcur[bk];
    const unsigned* buf = ibuf + (size_t)bk * BCAP;
    for (int i = t; i < n; i += 256) {
        int dl = (buf[i] >> 16) & 511;
        atomicAdd(&cnt[dl], 1);
    }
    __syncthreads();
    int c0 = cnt[2 * t], c1 = cnt[2 * t + 1];
    ps[t] = c0 + c1;
    __syncthreads();
    for (int o = 1; o < 256; o <<= 1) {
        int v = (t >= o) ? ps[t - o] : 0;
        __syncthreads();
        ps[t] += v;
        __syncthreads();
    }
    int excl = (t == 0) ? 0 : ps[t - 1];
    int base = bk * BCAP;
    int g0 = bk * 512 + 2 * t, g1 = g0 + 1;
    deg[g0] = c0; deg[g1] = c1;
    dinv[g0] = rsqrtf((float)c0 + 1.0f);
    dinv[g1] = rsqrtf((float)c1 + 1.0f);
    rowstart[g0] = base + excl;
    rowstart[g1] = base + excl + c0;
}

// ---------- pass B2: per-bucket placement into esrc (u16, localized writes) ----------
__global__ __launch_bounds__(256) void k_bplace(const unsigned* __restrict__ ibuf,
                                                const int* __restrict__ bcur,
                                                const int* __restrict__ rowstart,
                                                ushort_t* __restrict__ esrc) {
    __shared__ int lcur[512];
    int bk = blockIdx.x, t = threadIdx.x;
    for (int i = t; i < 512; i += 256) lcur[i] = rowstart[bk * 512 + i];
    __syncthreads();
    int n = bcur[bk];
    const unsigned* buf = ibuf + (size_t)bk * BCAP;
    for (int i = t; i < n; i += 256) {
        unsigned p = buf[i];
        int dl = (p >> 16) & 511;
        int slot = atomicAdd(&lcur[dl], 1);
        esrc[slot] = (ushort_t)(p & 0xffffu);
    }
}

// ---------- MFMA GEMM: Out[n][j] = sum_d X[n][d]*W[j][d] ----------
template<int EPI>
__global__ __launch_bounds__(256) void k_mgemm(const ushort_t* __restrict__ X,
                                               const ushort_t* __restrict__ Wb,
                                               const float* __restrict__ bias,
                                               ushort_t* __restrict__ Out,
                                               const float* __restrict__ aw,
                                               const float* __restrict__ ab,
                                               float* __restrict__ Sout,
                                               const float* __restrict__ dscale) {
    int w = threadIdx.x >> 6, l = threadIdx.x & 63;
    int rw = blockIdx.x * 64 + w * 16;
    int lr = l & 15, lg = l >> 4;
    f32x4 acc[8];
    #pragma unroll
    for (int c = 0; c < 8; c++) acc[c] = (f32x4){0.f, 0.f, 0.f, 0.f};
    const ushort_t* xrow = X + (size_t)(rw + lr) * DD + lg * 8;
    const ushort_t* wrow = Wb + (size_t)lr * DD + lg * 8;
    for (int kt = 0; kt < 4; kt++) {
        short8 a = *(const short8*)(xrow + kt * 32);
        #pragma unroll
        for (int c = 0; c < 8; c++) {
            short8 b = *(const short8*)(wrow + (size_t)c * 16 * DD + kt * 32);
            acc[c] = __builtin_amdgcn_mfma_f32_16x16x32_bf16(a, b, acc[c], 0, 0, 0);
        }
    }
    if (EPI == 0) {
        float ds[4];
        #pragma unroll
        for (int q = 0; q < 4; q++) ds[q] = dscale[rw + lg * 4 + q];
        #pragma unroll
        for (int c = 0; c < 8; c++) {
            int col = c * 16 + lr;
            #pragma unroll
            for (int q = 0; q < 4; q++)
                Out[(size_t)(rw + lg * 4 + q) * DD + col] = f2bf(acc[c][q] * ds[q]);
        }
    } else {
        float rs0 = 0.f, rs1 = 0.f, rs2 = 0.f, rs3 = 0.f;
        #pragma unroll
        for (int c = 0; c < 8; c++) {
            int col = c * 16 + lr;
            float bv = bias[col], wv = aw[col];
            rs0 += tanhf(acc[c][0] + bv) * wv;
            rs1 += tanhf(acc[c][1] + bv) * wv;
            rs2 += tanhf(acc[c][2] + bv) * wv;
            rs3 += tanhf(acc[c][3] + bv) * wv;
        }
        #pragma unroll
        for (int m = 1; m < 16; m <<= 1) {
            rs0 += __shfl_xor(rs0, m);
            rs1 += __shfl_xor(rs1, m);
            rs2 += __shfl_xor(rs2, m);
            rs3 += __shfl_xor(rs3, m);
        }
        if (lr == 0) {
            float a0 = ab[0];
            Sout[rw + lg * 4 + 0] = rs0 + a0;
            Sout[rw + lg * 4 + 1] = rs1 + a0;
            Sout[rw + lg * 4 + 2] = rs2 + a0;
            Sout[rw + lg * 4 + 3] = rs3 + a0;
        }
    }
}

#define GATHER(u, s) uint4 u = Hu4[(size_t)(s) * 16 + cl]
#define ACCUM(u) \
    a0 += lo16(u.x); a1 += hi16(u.x); a2 += lo16(u.y); a3 += hi16(u.y); \
    a4 += lo16(u.z); a5 += hi16(u.z); a6 += lo16(u.w); a7 += hi16(u.w)

// ---------- aggregate v4: one wave = 4 nodes; 16-lane quad owns a row; unroll-8 MLP ----------
template<int LAST>
__global__ __launch_bounds__(256) void k_agg(
    const ushort_t* __restrict__ Hs, const int* __restrict__ rowstart,
    const int* __restrict__ deg, const ushort_t* __restrict__ esrc,
    const float* __restrict__ dinv, const float* __restrict__ bnsc,
    const float* __restrict__ bnsh, ushort_t* __restrict__ A,
    ushort_t* __restrict__ Nrm) {
    int wid = (blockIdx.x * blockDim.x + threadIdx.x) >> 6;
    int l = threadIdx.x & 63;
    int q = l >> 4, cl = l & 15;
    int n = wid * 4 + q;
    const uint4* Hu4 = (const uint4*)Hs;
    int beg = rowstart[n];
    int end = beg + deg[n];
    float di = dinv[n];
    uint4 h = Hu4[(size_t)n * 16 + cl];
    float a0 = lo16(h.x), a1 = hi16(h.x), a2 = lo16(h.y), a3 = hi16(h.y);
    float a4 = lo16(h.z), a5 = hi16(h.z), a6 = lo16(h.w), a7 = hi16(h.w);
    int j = beg;
    for (; j + 8 <= end; j += 8) {
        unsigned s0 = esrc[j + 0], s1 = esrc[j + 1], s2 = esrc[j + 2], s3 = esrc[j + 3];
        unsigned s4 = esrc[j + 4], s5 = esrc[j + 5], s6 = esrc[j + 6], s7 = esrc[j + 7];
        GATHER(u0, s0); GATHER(u1, s1); GATHER(u2, s2); GATHER(u3, s3);
        GATHER(u4, s4); GATHER(u5, s5); GATHER(u6, s6); GATHER(u7, s7);
        ACCUM(u0); ACCUM(u1); ACCUM(u2); ACCUM(u3);
        ACCUM(u4); ACCUM(u5); ACCUM(u6); ACCUM(u7);
    }
    for (; j + 2 <= end; j += 2) {
        unsigned s0 = esrc[j], s1 = esrc[j + 1];
        GATHER(u0, s0); GATHER(u1, s1);
        ACCUM(u0); ACCUM(u1);
    }
    if (j < end) {
        unsigned s0 = esrc[j];
        GATHER(u0, s0);
        ACCUM(u0);
    }
    int c = cl * 8;
    float4 scA = *(const float4*)&bnsc[c], scB = *(const float4*)&bnsc[c + 4];
    float4 shA = *(const float4*)&bnsh[c], shB = *(const float4*)&bnsh[c + 4];
    float o0 = fmaf(a0 * di, scA.x, shA.x);
    float o1 = fmaf(a1 * di, scA.y, shA.y);
    float o2 = fmaf(a2 * di, scA.z, shA.z);
    float o3 = fmaf(a3 * di, scA.w, shA.w);
    float o4 = fmaf(a4 * di, scB.x, shB.x);
    float o5 = fmaf(a5 * di, scB.y, shB.y);
    float o6 = fmaf(a6 * di, scB.z, shB.z);
    float o7 = fmaf(a7 * di, scB.w, shB.w);
    uint4 av;
    av.x = pack2(fmaxf(o0, 0.f), fmaxf(o1, 0.f));
    av.y = pack2(fmaxf(o2, 0.f), fmaxf(o3, 0.f));
    av.z = pack2(fmaxf(o4, 0.f), fmaxf(o5, 0.f));
    av.w = pack2(fmaxf(o6, 0.f), fmaxf(o7, 0.f));
    ((uint4*)A)[(size_t)n * 16 + cl] = av;
    if (LAST) {
        float r0 = lo16(av.x), r1 = hi16(av.x), r2 = lo16(av.y), r3 = hi16(av.y);
        float r4 = lo16(av.z), r5 = hi16(av.z), r6 = lo16(av.w), r7 = hi16(av.w);
        float ss = ((r0 * r0 + r1 * r1) + (r2 * r2 + r3 * r3)) +
                   ((r4 * r4 + r5 * r5) + (r6 * r6 + r7 * r7));
        #pragma unroll
        for (int o = 8; o > 0; o >>= 1) ss += __shfl_xor(ss, o);
        float inv = 1.0f / fmaxf(sqrtf(ss), 1e-8f);
        uint4 nv;
        nv.x = pack2(r0 * inv, r1 * inv);
        nv.y = pack2(r2 * inv, r3 * inv);
        nv.z = pack2(r4 * inv, r5 * inv);
        nv.w = pack2(r6 * inv, r7 * inv);
        ((uint4*)Nrm)[(size_t)n * 16 + cl] = nv;
    }
}

// ---------- fused per-graph softmax + weighted sum (no atomics) ----------
__global__ __launch_bounds__(512) void k_pool2(const float* __restrict__ S,
                                               const ushort_t* __restrict__ Emb,
                                               float* __restrict__ G) {
    int b = blockIdx.x, t = threadIdx.x;
    __shared__ float red[512];
    __shared__ float w[512];
    __shared__ float red0[512], red1[512];
    float s = S[b * NPG + t];
    red[t] = s;
    __syncthreads();
    for (int o = 256; o > 0; o >>= 1) { if (t < o) red[t] = fmaxf(red[t], red[t + o]); __syncthreads(); }
    float m = red[0];
    __syncthreads();
    float e = expf(s - m);
    w[t] = e;
    red[t] = e;
    __syncthreads();
    for (int o = 256; o > 0; o >>= 1) { if (t < o) red[t] += red[t + o]; __syncthreads(); }
    float inv = 1.0f / red[0];
    // weighted sum: l = uint column (2 bf16), ch = 64-node chunk
    int l = t & 63, ch = t >> 6;
    int nbase = b * NPG + ch * 64;
    float a0 = 0.f, a1 = 0.f;
    #pragma unroll 4
    for (int i = 0; i < 64; i++) {
        float wv = w[ch * 64 + i];
        unsigned u = ((const unsigned*)(Emb + (size_t)(nbase + i) * DD))[l];
        a0 += wv * lo16(u);
        a1 += wv * hi16(u);
    }
    red0[t] = a0; red1[t] = a1;
    __syncthreads();
    if (t < 64) {
        float s0 = 0.f, s1 = 0.f;
        #pragma unroll
        for (int c = 0; c < 8; c++) { s0 += red0[t + c * 64]; s1 += red1[t + c * 64]; }
        G[b * DD + 2 * t] = s0 * inv;
        G[b * DD + 2 * t + 1] = s1 * inv;
    }
}

// ---------- MFMA cosine-sim histogram ----------
__global__ __launch_bounds__(256) void k_hist(const ushort_t* __restrict__ N1,
                                              const ushort_t* __restrict__ N2,
                                              float* __restrict__ Hist) {
    __shared__ int hl[256 * 17];
    __shared__ float hred[NBINS];
    int t = threadIdx.x, w = t >> 6, l = t & 63;
    int lr = l & 15, lg = l >> 4;
    int g = blockIdx.x >> 4, ti = (blockIdx.x >> 2) & 3, tj = blockIdx.x & 3;
    #pragma unroll
    for (int i = t; i < 256 * 17; i += 256) hl[i] = 0;
    if (t < NBINS) hred[t] = 0.f;
    __syncthreads();

    const ushort_t* arow = N1 + ((size_t)g * NPG + ti * 128 + w * 32 + lr) * DD + lg * 8;
    const ushort_t* brow = N2 + ((size_t)g * NPG + tj * 128 + lr) * DD + lg * 8;
    f32x4 acc[2][8];
    #pragma unroll
    for (int r = 0; r < 2; r++)
        #pragma unroll
        for (int c = 0; c < 8; c++) acc[r][c] = (f32x4){0.f, 0.f, 0.f, 0.f};
    for (int kt = 0; kt < 4; kt++) {
        short8 a0 = *(const short8*)(arow + kt * 32);
        short8 a1 = *(const short8*)(arow + (size_t)16 * DD + kt * 32);
        #pragma unroll
        for (int c = 0; c < 8; c++) {
            short8 b = *(const short8*)(brow + (size_t)c * 16 * DD + kt * 32);
            acc[0][c] = __builtin_amdgcn_mfma_f32_16x16x32_bf16(a0, b, acc[0][c], 0, 0, 0);
            acc[1][c] = __builtin_amdgcn_mfma_f32_16x16x32_bf16(a1, b, acc[1][c], 0, 0, 0);
        }
    }
    int base = t * 17;
    #pragma unroll
    for (int r = 0; r < 2; r++)
        #pragma unroll
        for (int c = 0; c < 8; c++)
            #pragma unroll
            for (int q = 0; q < 4; q++) {
                float sim = acc[r][c][q];
                float v = floorf((sim + 1.0f) * 8.0f);
                v = fminf(fmaxf(v, 0.f), 15.f);
                atomicAdd(&hl[base + (int)v], 1);
            }
    __syncthreads();
    int bin = t & 15, r0 = (t >> 4) * 16;
    int s = 0;
    #pragma unroll
    for (int r = 0; r < 16; r++) s += hl[(r0 + r) * 17 + bin];
    atomicAdd(&hred[bin], (float)s);
    __syncthreads();
    if (t < NBINS) atomicAdd(&Hist[g * NBINS + t], hred[t]);
}

// ---------- NTN bilinear ----------
__global__ __launch_bounds__(128) void k_ntn(const float* __restrict__ G1,
                                             const float* __restrict__ G2,
                                             const float* __restrict__ T,
                                             const float* __restrict__ tb,
                                             float* __restrict__ TP) {
    int b = blockIdx.x, k = blockIdx.y;
    int e = threadIdx.x;
    const float* Tk = T + (size_t)k * DD * DD;
    float g2e = G2[b * DD + e];
    float acc = 0.f;
    for (int d = 0; d < DD; d++) acc += G1[b * DD + d] * Tk[(size_t)d * DD + e];
    float val = acc * g2e;
    #pragma unroll
    for (int o = 32; o > 0; o >>= 1) val += __shfl_down(val, o);
    __shared__ float ps[2];
    if ((e & 63) == 0) ps[e >> 6] = val;
    __syncthreads();
    if (e == 0) TP[b * KNTN + k] = ps[0] + ps[1] + tb[k];
}

// ---------- final MLPs: staged-LDS weights, 64 graphs in parallel ----------
__global__ __launch_bounds__(256) void k_final(const float* __restrict__ TP, const float* __restrict__ Hist,
                        const float* nw1, const float* nb1, const float* nw2, const float* nb2,
                        const float* nw3, const float* nb3,
                        const float* hw1, const float* hb1, const float* hw2, const float* hb2,
                        const float* fw1, const float* fb1, const float* fw2, const float* fb2,
                        float* __restrict__ out) {
    __shared__ float sTP[BB * 16], sHist[BB * 16];
    __shared__ float snw1[512], snw2[512], shw1[512], shw2[512];
    __shared__ float snw3[16], snb1[32], snb2[16], shb1[32], shb2[16];
    __shared__ float sfw1[136], sfb1[8], sfw2[8], sscal[2];
    int t = threadIdx.x;
    for (int i = t; i < BB * 16; i += 256) { sTP[i] = TP[i]; sHist[i] = Hist[i]; }
    for (int i = t; i < 512; i += 256) {
        snw1[i] = nw1[i]; snw2[i] = nw2[i]; shw1[i] = hw1[i]; shw2[i] = hw2[i];
    }
    if (t < 136) sfw1[t] = fw1[t];
    if (t < 32) { snb1[t] = nb1[t]; shb1[t] = hb1[t]; }
    if (t < 16) { snb2[t] = nb2[t]; shb2[t] = hb2[t]; snw3[t] = nw3[t]; }
    if (t < 8) { sfb1[t] = fb1[t]; sfw2[t] = fw2[t]; }
    if (t == 0) { sscal[0] = nb3[0]; sscal[1] = fb2[0]; }
    __syncthreads();
    if (t >= BB) return;
    int b = t;
    float h1[32];
    #pragma unroll
    for (int i = 0; i < 32; i++) {
        float a = snb1[i];
        for (int k = 0; k < 16; k++) a += sTP[b * 16 + k] * snw1[i * 16 + k];
        h1[i] = fmaxf(a, 0.f);
    }
    float h2[16];
    #pragma unroll
    for (int j = 0; j < 16; j++) {
        float a = snb2[j];
        for (int i = 0; i < 32; i++) a += h1[i] * snw2[j * 32 + i];
        h2[j] = fmaxf(a, 0.f);
    }
    float nt = sscal[0];
    for (int j = 0; j < 16; j++) nt += h2[j] * snw3[j];
    nt = 1.f / (1.f + expf(-nt));
    float hh[16]; float sum = 0.f;
    for (int k = 0; k < 16; k++) { hh[k] = sHist[b * 16 + k]; sum += hh[k]; }
    float inv = 1.f / (sum + 1e-8f);
    for (int k = 0; k < 16; k++) hh[k] *= inv;
    float g1v[32];
    #pragma unroll
    for (int i = 0; i < 32; i++) {
        float a = shb1[i];
        for (int k = 0; k < 16; k++) a += hh[k] * shw1[i * 16 + k];
        g1v[i] = fmaxf(a, 0.f);
    }
    float hemb[16];
    #pragma unroll
    for (int j = 0; j < 16; j++) {
        float a = shb2[j];
        for (int i = 0; i < 32; i++) a += g1v[i] * shw2[j * 32 + i];
        hemb[j] = a;
    }
    float comb[17];
    comb[0] = nt;
    for (int j = 0; j < 16; j++) comb[1 + j] = hemb[j];
    float f1[8];
    #pragma unroll
    for (int i = 0; i < 8; i++) {
        float a = sfb1[i];
        for (int j = 0; j < 17; j++) a += comb[j] * sfw1[i * 17 + j];
        f1[i] = fmaxf(a, 0.f);
    }
    float o = sscal[1];
    for (int i = 0; i < 8; i++) o += f1[i] * sfw2[i];
    out[b] = 1.f / (1.f + expf(-o));
}

extern "C" void kernel_launch(void* const* d_in, const int* in_sizes, int n_in,
                              void* d_out, int out_size, void* d_ws, size_t ws_size,
                              hipStream_t stream) {
    const float* x1    = (const float*)d_in[0];
    const float* x2    = (const float*)d_in[1];
    const int*   ei1   = (const int*)d_in[2];
    const int*   ei2   = (const int*)d_in[3];
    const float* gcn_w = (const float*)d_in[6];
    const float* gcn_b = (const float*)d_in[7];
    const float* bn_g  = (const float*)d_in[8];
    const float* bn_b  = (const float*)d_in[9];
    const float* bn_m  = (const float*)d_in[10];
    const float* bn_v  = (const float*)d_in[11];
    const float* ctx_w = (const float*)d_in[12];
    const float* ctx_b = (const float*)d_in[13];
    const float* att_w = (const float*)d_in[14];
    const float* att_b = (const float*)d_in[15];
    const float* ntn_T = (const float*)d_in[16];
    const float* ntn_b = (const float*)d_in[17];
    const float* nw1 = (const float*)d_in[18];
    const float* nb1 = (const float*)d_in[19];
    const float* nw2 = (const float*)d_in[20];
    const float* nb2 = (const float*)d_in[21];
    const float* nw3 = (const float*)d_in[22];
    const float* nb3 = (const float*)d_in[23];
    const float* hw1 = (const float*)d_in[24];
    const float* hb1 = (const float*)d_in[25];
    const float* hw2 = (const float*)d_in[26];
    const float* hb2 = (const float*)d_in[27];
    const float* fw1 = (const float*)d_in[28];
    const float* fb1 = (const float*)d_in[29];
    const float* fw2 = (const float*)d_in[30];
    const float* fb2 = (const float*)d_in[31];
    float* out = (float*)d_out;

    ushort_t* Xbf = (ushort_t*)d_ws;        // 2*NND (reused as Nrm)
    ushort_t* Abf = Xbf + 2 * (size_t)NND;  // 2*NND
    ushort_t* Hbf = Abf + 2 * (size_t)NND;  // 2*NND
    ushort_t* wbf = Hbf + 2 * (size_t)NND;  // 4*DD*DD
    float* dinv = (float*)(wbf + 4 * DD * DD);  // 2*NN
    float* S    = dinv + 2 * NN;                // 2*NN
    float* G    = S + 2 * NN;                   // 2*BB*DD
    float* hist = G + 2 * BB * DD;              // BB*NBINS
    float* tp   = hist + BB * NBINS;            // BB*KNTN
    float* bnsc = tp + BB * KNTN;               // LL*DD
    float* bnsh = bnsc + LL * DD;               // LL*DD
    int* degi  = (int*)(bnsh + LL * DD);        // 2*NN
    int* rowst = degi + 2 * NN;                 // 2*NN
    int* bcur  = rowst + 2 * NN;                // NBKT
    ushort_t* esrc = (ushort_t*)(bcur + NBKT);  // NBKT*BCAP u16
    unsigned* ibuf = (unsigned*)(esrc + (size_t)NBKT * BCAP);  // NBKT*BCAP u32

    k_prep<<<8257, 256, 0, stream>>>(x1, x2, gcn_w, ctx_w, gcn_b, bn_g, bn_b, bn_m, bn_v,
                                     Xbf, wbf, bnsc, bnsh, bcur, hist);
    k_bucket<<<2 * EE / 2048, 256, 0, stream>>>(ei1, ei2, bcur, ibuf);
    k_bcnt<<<NBKT, 256, 0, stream>>>(ibuf, bcur, degi, dinv, rowst);
    k_bplace<<<NBKT, 256, 0, stream>>>(ibuf, bcur, rowst, esrc);

    for (int l = 0; l < LL; l++) {
        k_mgemm<0><<<2 * NN / 64, 256, 0, stream>>>(l == 0 ? Xbf : Abf,
                                                    wbf + (size_t)l * DD * DD,
                                                    nullptr, Hbf, nullptr, nullptr, nullptr, dinv);
        if (l < LL - 1)
            k_agg<0><<<2 * NN / 16, 256, 0, stream>>>(Hbf, rowst, degi, esrc, dinv,
                                                      bnsc + l * DD, bnsh + l * DD, Abf, nullptr);
        else
            k_agg<1><<<2 * NN / 16, 256, 0, stream>>>(Hbf, rowst, degi, esrc, dinv,
                                                      bnsc + l * DD, bnsh + l * DD, Abf, Xbf);
    }
    k_mgemm<2><<<2 * NN / 64, 256, 0, stream>>>(Abf, wbf + 3 * DD * DD, ctx_b,
                                                nullptr, att_w, att_b, S, nullptr);
    k_pool2<<<2 * BB, 512, 0, stream>>>(S, Abf, G);
    k_hist<<<BB * 16, 256, 0, stream>>>(Xbf, Xbf + NND, hist);
    k_ntn<<<dim3(BB, KNTN), 128, 0, stream>>>(G, G + BB * DD, ntn_T, ntn_b, tp);
    k_final<<<1, 256, 0, stream>>>(tp, hist, nw1, nb1, nw2, nb2, nw3, nb3,
                                   hw1, hb1, hw2, hb2, fw1, fb1, fw2, fb2, out);
}

// Round 10
// 235.454 us; speedup vs baseline: 25.3100x; 1.2481x over previous
//
#include <hip/hip_runtime.h>
#include <math.h>

#define NN 32768      // nodes per side
#define BB 64         // graphs per side
#define NPG 512
#define DD 128
#define LL 3
#define EE 524288     // edges per side
#define NBINS 16
#define KNTN 16
#define NND (NN*DD)
#define NBKT 128      // CSR buckets (512 nodes each)
#define BCAP 10240    // bucket edge capacity (mean 8192, std ~90)

typedef unsigned short ushort_t;
typedef __attribute__((ext_vector_type(8))) short short8;
typedef __attribute__((ext_vector_type(4))) float f32x4;

__device__ __forceinline__ ushort_t f2bf(float f) {
    unsigned u = __builtin_bit_cast(unsigned, f);
    u += 0x7FFFu + ((u >> 16) & 1u);
    return (ushort_t)(u >> 16);
}
__device__ __forceinline__ float bf2f(ushort_t h) {
    unsigned u = ((unsigned)h) << 16;
    return __builtin_bit_cast(float, u);
}
__device__ __forceinline__ unsigned pack2(float a, float b) {
    return (unsigned)f2bf(a) | ((unsigned)f2bf(b) << 16);
}
__device__ __forceinline__ float lo16(unsigned u) { return __builtin_bit_cast(float, u << 16); }
__device__ __forceinline__ float hi16(unsigned u) { return __builtin_bit_cast(float, u & 0xffff0000u); }

// ---------- prep: x->bf16, weights->bf16, BN fold, bcur zero, hist zero ----------
__global__ __launch_bounds__(256) void k_prep(const float* __restrict__ x1,
                                              const float* __restrict__ x2,
                                              const float* __restrict__ gw,
                                              const float* __restrict__ cw,
                                              const float* __restrict__ gcn_b,
                                              const float* __restrict__ bn_g,
                                              const float* __restrict__ bn_b,
                                              const float* __restrict__ bn_m,
                                              const float* __restrict__ bn_v,
                                              ushort_t* __restrict__ Xbf,
                                              ushort_t* __restrict__ wbf,
                                              float* __restrict__ bnsc,
                                              float* __restrict__ bnsh,
                                              int* __restrict__ bcur,
                                              float* __restrict__ hist) {
    int b = blockIdx.x, t = threadIdx.x;
    if (b < 8192) {
        int i = b * 256 + t;
        const float4 v = (i < NND / 4) ? ((const float4*)x1)[i] : ((const float4*)x2)[i - NND / 4];
        uint2 o;
        o.x = pack2(v.x, v.y);
        o.y = pack2(v.z, v.w);
        ((uint2*)Xbf)[i] = o;
    } else if (b < 8256) {
        int i = (b - 8192) * 256 + t;
        const float4 v = (i < 3 * DD * DD / 4) ? ((const float4*)gw)[i]
                                               : ((const float4*)cw)[i - 3 * DD * DD / 4];
        uint2 o;
        o.x = pack2(v.x, v.y);
        o.y = pack2(v.z, v.w);
        ((uint2*)wbf)[i] = o;
    } else {
        if (t < NBKT) bcur[t] = 0;
        for (int i = t; i < BB * NBINS; i += 256) hist[i] = 0.f;
        if (t < DD) {
            #pragma unroll
            for (int l = 0; l < LL; l++) {
                int c = l * DD + t;
                float sc = bn_g[c] * rsqrtf(bn_v[c] + 1e-5f);
                bnsc[c] = sc;
                bnsh[c] = (gcn_b[c] - bn_m[c]) * sc + bn_b[c];
            }
        }
    }
}

// ---------- CSR build pass A: bucket edges by dst>>9, coalesced region writes ----------
__global__ __launch_bounds__(256) void k_bucket(const int* __restrict__ ei1,
                                                const int* __restrict__ ei2,
                                                int* __restrict__ bcur,
                                                unsigned* __restrict__ ibuf) {
    __shared__ int cnt[NBKT], off[NBKT], gb[NBKT];
    __shared__ unsigned stage[2048];
    int t = threadIdx.x;
    int blk = blockIdx.x;                 // 0..511; 0..255 side1, 256..511 side2
    const int* ei = (blk < 256) ? ei1 : ei2;
    int ebase = (blk & 255) * 2048;
    int addn = (blk < 256) ? 0 : NN;
    for (int i = t; i < NBKT; i += 256) cnt[i] = 0;
    __syncthreads();
    unsigned pk[8]; int rk[8];
    #pragma unroll
    for (int k = 0; k < 8; k++) {
        int e = ebase + t + k * 256;
        int s = ei[e] + addn;
        int d = ei[EE + e] + addn;
        pk[k] = (unsigned)s | ((unsigned)d << 16);
    }
    #pragma unroll
    for (int k = 0; k < 8; k++) {
        int bk = pk[k] >> 25;
        rk[k] = atomicAdd(&cnt[bk], 1);
    }
    __syncthreads();
    if (t < NBKT) off[t] = cnt[t];
    __syncthreads();
    for (int o = 1; o < NBKT; o <<= 1) {
        int v = 0;
        if (t < NBKT && t >= o) v = off[t - o];
        __syncthreads();
        if (t < NBKT) off[t] += v;
        __syncthreads();
    }
    #pragma unroll
    for (int k = 0; k < 8; k++) {
        int bk = pk[k] >> 25;
        stage[off[bk] - cnt[bk] + rk[k]] = pk[k];
    }
    if (t < NBKT) {
        int c = cnt[t];
        gb[t] = c > 0 ? atomicAdd(&bcur[t], c) : 0;
    }
    __syncthreads();
    #pragma unroll
    for (int k = 0; k < 8; k++) {
        int idx = t + k * 256;
        unsigned p = stage[idx];
        int bk = p >> 25;
        int pos = idx - (off[bk] - cnt[bk]);
        ibuf[(size_t)bk * BCAP + gb[bk] + pos] = p;
    }
}

// ---------- pass B (merged): per-bucket count -> scan -> deg/dinv/rowstart -> place ----------
__global__ __launch_bounds__(256) void k_bcsr(const unsigned* __restrict__ ibuf,
                                              const int* __restrict__ bcur,
                                              int* __restrict__ deg,
                                              float* __restrict__ dinv,
                                              int* __restrict__ rowstart,
                                              ushort_t* __restrict__ esrc) {
    __shared__ int cnt[512];
    __shared__ int ps[256];
    __shared__ int lcur[512];
    int bk = blockIdx.x, t = threadIdx.x;
    for (int i = t; i < 512; i += 256) cnt[i] = 0;
    __syncthreads();
    int n = bcur[bk];
    const unsigned* buf = ibuf + (size_t)bk * BCAP;
    for (int i = t; i < n; i += 256) {
        int dl = (buf[i] >> 16) & 511;
        atomicAdd(&cnt[dl], 1);
    }
    __syncthreads();
    int c0 = cnt[2 * t], c1 = cnt[2 * t + 1];
    ps[t] = c0 + c1;
    __syncthreads();
    for (int o = 1; o < 256; o <<= 1) {
        int v = (t >= o) ? ps[t - o] : 0;
        __syncthreads();
        ps[t] += v;
        __syncthreads();
    }
    int excl = (t == 0) ? 0 : ps[t - 1];
    int base = bk * BCAP;
    int g0 = bk * 512 + 2 * t, g1 = g0 + 1;
    deg[g0] = c0; deg[g1] = c1;
    dinv[g0] = rsqrtf((float)c0 + 1.0f);
    dinv[g1] = rsqrtf((float)c1 + 1.0f);
    int r0 = base + excl, r1 = base + excl + c0;
    rowstart[g0] = r0;
    rowstart[g1] = r1;
    lcur[2 * t] = r0;
    lcur[2 * t + 1] = r1;
    __syncthreads();
    for (int i = t; i < n; i += 256) {
        unsigned p = buf[i];
        int dl = (p >> 16) & 511;
        int slot = atomicAdd(&lcur[dl], 1);
        esrc[slot] = (ushort_t)(p & 0xffffu);
    }
}

// ---------- MFMA GEMM v2: W staged in LDS (swizzled), 128 rows/block ----------
// EPI 0: bf16 out scaled by dscale[row].  EPI 2: bias+tanh+attention-score -> Sout.
template<int EPI>
__global__ __launch_bounds__(256) void k_mgemm(const ushort_t* __restrict__ X,
                                               const ushort_t* __restrict__ Wb,
                                               const float* __restrict__ bias,
                                               ushort_t* __restrict__ Out,
                                               const float* __restrict__ aw,
                                               const float* __restrict__ ab,
                                               float* __restrict__ Sout,
                                               const float* __restrict__ dscale) {
    __shared__ __align__(16) ushort_t wlds[128 * 128];
    int t = threadIdx.x;
    {
        int r = t >> 1, h = t & 1;
        const uint4* src = (const uint4*)(Wb + (size_t)r * DD + h * 64);
        #pragma unroll
        for (int i = 0; i < 8; i++) {
            int co = h * 128 + i * 16;                 // byte col offset
            int sw = co ^ ((r & 7) << 4);              // XOR swizzle
            *(uint4*)&wlds[r * DD + (sw >> 1)] = src[i];
        }
    }
    __syncthreads();
    int w = t >> 6, l = t & 63;
    int rw = blockIdx.x * 128 + w * 32;
    int lr = l & 15, lg = l >> 4;
    f32x4 acc[2][8];
    #pragma unroll
    for (int g = 0; g < 2; g++)
        #pragma unroll
        for (int c = 0; c < 8; c++) acc[g][c] = (f32x4){0.f, 0.f, 0.f, 0.f};
    const ushort_t* xrow0 = X + (size_t)(rw + lr) * DD + lg * 8;
    const ushort_t* xrow1 = xrow0 + (size_t)16 * DD;
    int swl = (lr & 7) << 4;
    for (int kt = 0; kt < 4; kt++) {
        short8 a0 = *(const short8*)(xrow0 + kt * 32);
        short8 a1 = *(const short8*)(xrow1 + kt * 32);
        int colsw = (kt * 64 + lg * 16) ^ swl;         // byte offset in row
        #pragma unroll
        for (int c = 0; c < 8; c++) {
            int row = c * 16 + lr;
            short8 b = *(const short8*)&wlds[row * DD + (colsw >> 1)];
            acc[0][c] = __builtin_amdgcn_mfma_f32_16x16x32_bf16(a0, b, acc[0][c], 0, 0, 0);
            acc[1][c] = __builtin_amdgcn_mfma_f32_16x16x32_bf16(a1, b, acc[1][c], 0, 0, 0);
        }
    }
    if (EPI == 0) {
        float ds[2][4];
        #pragma unroll
        for (int g = 0; g < 2; g++)
            #pragma unroll
            for (int q = 0; q < 4; q++) ds[g][q] = dscale[rw + g * 16 + lg * 4 + q];
        #pragma unroll
        for (int g = 0; g < 2; g++)
            #pragma unroll
            for (int c = 0; c < 8; c++) {
                int col = c * 16 + lr;
                #pragma unroll
                for (int q = 0; q < 4; q++)
                    Out[(size_t)(rw + g * 16 + lg * 4 + q) * DD + col] = f2bf(acc[g][c][q] * ds[g][q]);
            }
    } else {
        float rs[2][4] = {};
        #pragma unroll
        for (int c = 0; c < 8; c++) {
            int col = c * 16 + lr;
            float bv = bias[col], wv = aw[col];
            #pragma unroll
            for (int g = 0; g < 2; g++)
                #pragma unroll
                for (int q = 0; q < 4; q++)
                    rs[g][q] += tanhf(acc[g][c][q] + bv) * wv;
        }
        #pragma unroll
        for (int m = 1; m < 16; m <<= 1)
            #pragma unroll
            for (int g = 0; g < 2; g++)
                #pragma unroll
                for (int q = 0; q < 4; q++) rs[g][q] += __shfl_xor(rs[g][q], m);
        if (lr == 0) {
            float a0 = ab[0];
            #pragma unroll
            for (int g = 0; g < 2; g++)
                #pragma unroll
                for (int q = 0; q < 4; q++)
                    Sout[rw + g * 16 + lg * 4 + q] = rs[g][q] + a0;
        }
    }
}

#define GATHER(u, s) uint4 u = Hu4[(size_t)(s) * 16 + cl]
#define ACCUM(u) \
    a0 += lo16(u.x); a1 += hi16(u.x); a2 += lo16(u.y); a3 += hi16(u.y); \
    a4 += lo16(u.z); a5 += hi16(u.z); a6 += lo16(u.w); a7 += hi16(u.w)

// ---------- aggregate v4: one wave = 4 nodes; 16-lane quad owns a row; unroll-8 MLP ----------
template<int LAST>
__global__ __launch_bounds__(256) void k_agg(
    const ushort_t* __restrict__ Hs, const int* __restrict__ rowstart,
    const int* __restrict__ deg, const ushort_t* __restrict__ esrc,
    const float* __restrict__ dinv, const float* __restrict__ bnsc,
    const float* __restrict__ bnsh, ushort_t* __restrict__ A,
    ushort_t* __restrict__ Nrm) {
    int wid = (blockIdx.x * blockDim.x + threadIdx.x) >> 6;
    int l = threadIdx.x & 63;
    int q = l >> 4, cl = l & 15;
    int n = wid * 4 + q;
    const uint4* Hu4 = (const uint4*)Hs;
    int beg = rowstart[n];
    int end = beg + deg[n];
    float di = dinv[n];
    uint4 h = Hu4[(size_t)n * 16 + cl];
    float a0 = lo16(h.x), a1 = hi16(h.x), a2 = lo16(h.y), a3 = hi16(h.y);
    float a4 = lo16(h.z), a5 = hi16(h.z), a6 = lo16(h.w), a7 = hi16(h.w);
    int j = beg;
    for (; j + 8 <= end; j += 8) {
        unsigned s0 = esrc[j + 0], s1 = esrc[j + 1], s2 = esrc[j + 2], s3 = esrc[j + 3];
        unsigned s4 = esrc[j + 4], s5 = esrc[j + 5], s6 = esrc[j + 6], s7 = esrc[j + 7];
        GATHER(u0, s0); GATHER(u1, s1); GATHER(u2, s2); GATHER(u3, s3);
        GATHER(u4, s4); GATHER(u5, s5); GATHER(u6, s6); GATHER(u7, s7);
        ACCUM(u0); ACCUM(u1); ACCUM(u2); ACCUM(u3);
        ACCUM(u4); ACCUM(u5); ACCUM(u6); ACCUM(u7);
    }
    for (; j + 2 <= end; j += 2) {
        unsigned s0 = esrc[j], s1 = esrc[j + 1];
        GATHER(u0, s0); GATHER(u1, s1);
        ACCUM(u0); ACCUM(u1);
    }
    if (j < end) {
        unsigned s0 = esrc[j];
        GATHER(u0, s0);
        ACCUM(u0);
    }
    int c = cl * 8;
    float4 scA = *(const float4*)&bnsc[c], scB = *(const float4*)&bnsc[c + 4];
    float4 shA = *(const float4*)&bnsh[c], shB = *(const float4*)&bnsh[c + 4];
    float o0 = fmaf(a0 * di, scA.x, shA.x);
    float o1 = fmaf(a1 * di, scA.y, shA.y);
    float o2 = fmaf(a2 * di, scA.z, shA.z);
    float o3 = fmaf(a3 * di, scA.w, shA.w);
    float o4 = fmaf(a4 * di, scB.x, shB.x);
    float o5 = fmaf(a5 * di, scB.y, shB.y);
    float o6 = fmaf(a6 * di, scB.z, shB.z);
    float o7 = fmaf(a7 * di, scB.w, shB.w);
    uint4 av;
    av.x = pack2(fmaxf(o0, 0.f), fmaxf(o1, 0.f));
    av.y = pack2(fmaxf(o2, 0.f), fmaxf(o3, 0.f));
    av.z = pack2(fmaxf(o4, 0.f), fmaxf(o5, 0.f));
    av.w = pack2(fmaxf(o6, 0.f), fmaxf(o7, 0.f));
    ((uint4*)A)[(size_t)n * 16 + cl] = av;
    if (LAST) {
        float r0 = lo16(av.x), r1 = hi16(av.x), r2 = lo16(av.y), r3 = hi16(av.y);
        float r4 = lo16(av.z), r5 = hi16(av.z), r6 = lo16(av.w), r7 = hi16(av.w);
        float ss = ((r0 * r0 + r1 * r1) + (r2 * r2 + r3 * r3)) +
                   ((r4 * r4 + r5 * r5) + (r6 * r6 + r7 * r7));
        #pragma unroll
        for (int o = 8; o > 0; o >>= 1) ss += __shfl_xor(ss, o);
        float inv = 1.0f / fmaxf(sqrtf(ss), 1e-8f);
        uint4 nv;
        nv.x = pack2(r0 * inv, r1 * inv);
        nv.y = pack2(r2 * inv, r3 * inv);
        nv.z = pack2(r4 * inv, r5 * inv);
        nv.w = pack2(r6 * inv, r7 * inv);
        ((uint4*)Nrm)[(size_t)n * 16 + cl] = nv;
    }
}

// ---------- fused per-graph softmax + weighted sum (no atomics) ----------
__global__ __launch_bounds__(512) void k_pool2(const float* __restrict__ S,
                                               const ushort_t* __restrict__ Emb,
                                               float* __restrict__ G) {
    int b = blockIdx.x, t = threadIdx.x;
    __shared__ float red[512];
    __shared__ float w[512];
    __shared__ float red0[512], red1[512];
    float s = S[b * NPG + t];
    red[t] = s;
    __syncthreads();
    for (int o = 256; o > 0; o >>= 1) { if (t < o) red[t] = fmaxf(red[t], red[t + o]); __syncthreads(); }
    float m = red[0];
    __syncthreads();
    float e = expf(s - m);
    w[t] = e;
    red[t] = e;
    __syncthreads();
    for (int o = 256; o > 0; o >>= 1) { if (t < o) red[t] += red[t + o]; __syncthreads(); }
    float inv = 1.0f / red[0];
    int l = t & 63, ch = t >> 6;
    int nbase = b * NPG + ch * 64;
    float a0 = 0.f, a1 = 0.f;
    #pragma unroll 4
    for (int i = 0; i < 64; i++) {
        float wv = w[ch * 64 + i];
        unsigned u = ((const unsigned*)(Emb + (size_t)(nbase + i) * DD))[l];
        a0 += wv * lo16(u);
        a1 += wv * hi16(u);
    }
    red0[t] = a0; red1[t] = a1;
    __syncthreads();
    if (t < 64) {
        float s0 = 0.f, s1 = 0.f;
        #pragma unroll
        for (int c = 0; c < 8; c++) { s0 += red0[t + c * 64]; s1 += red1[t + c * 64]; }
        G[b * DD + 2 * t] = s0 * inv;
        G[b * DD + 2 * t + 1] = s1 * inv;
    }
}

// ---------- MFMA cosine-sim histogram v2: B-tile staged in LDS (swizzled) ----------
__global__ __launch_bounds__(256) void k_hist(const ushort_t* __restrict__ N1,
                                              const ushort_t* __restrict__ N2,
                                              float* __restrict__ Hist) {
    __shared__ __align__(16) ushort_t blds[128 * 128];
    __shared__ int hl[256 * 17];
    __shared__ float hred[NBINS];
    int t = threadIdx.x, w = t >> 6, l = t & 63;
    int lr = l & 15, lg = l >> 4;
    int g = blockIdx.x >> 4, ti = (blockIdx.x >> 2) & 3, tj = blockIdx.x & 3;
    {
        int r = t >> 1, h = t & 1;
        const uint4* src = (const uint4*)(N2 + ((size_t)g * NPG + tj * 128 + r) * DD + h * 64);
        #pragma unroll
        for (int i = 0; i < 8; i++) {
            int co = h * 128 + i * 16;
            int sw = co ^ ((r & 7) << 4);
            *(uint4*)&blds[r * DD + (sw >> 1)] = src[i];
        }
    }
    #pragma unroll
    for (int i = t; i < 256 * 17; i += 256) hl[i] = 0;
    if (t < NBINS) hred[t] = 0.f;
    __syncthreads();

    const ushort_t* arow = N1 + ((size_t)g * NPG + ti * 128 + w * 32 + lr) * DD + lg * 8;
    f32x4 acc[2][8];
    #pragma unroll
    for (int r = 0; r < 2; r++)
        #pragma unroll
        for (int c = 0; c < 8; c++) acc[r][c] = (f32x4){0.f, 0.f, 0.f, 0.f};
    int swl = (lr & 7) << 4;
    for (int kt = 0; kt < 4; kt++) {
        short8 a0 = *(const short8*)(arow + kt * 32);
        short8 a1 = *(const short8*)(arow + (size_t)16 * DD + kt * 32);
        int colsw = (kt * 64 + lg * 16) ^ swl;
        #pragma unroll
        for (int c = 0; c < 8; c++) {
            int row = c * 16 + lr;
            short8 b = *(const short8*)&blds[row * DD + (colsw >> 1)];
            acc[0][c] = __builtin_amdgcn_mfma_f32_16x16x32_bf16(a0, b, acc[0][c], 0, 0, 0);
            acc[1][c] = __builtin_amdgcn_mfma_f32_16x16x32_bf16(a1, b, acc[1][c], 0, 0, 0);
        }
    }
    int base = t * 17;
    #pragma unroll
    for (int r = 0; r < 2; r++)
        #pragma unroll
        for (int c = 0; c < 8; c++)
            #pragma unroll
            for (int q = 0; q < 4; q++) {
                float sim = acc[r][c][q];
                float v = floorf((sim + 1.0f) * 8.0f);
                v = fminf(fmaxf(v, 0.f), 15.f);
                atomicAdd(&hl[base + (int)v], 1);
            }
    __syncthreads();
    int bin = t & 15, r0 = (t >> 4) * 16;
    int s = 0;
    #pragma unroll
    for (int r = 0; r < 16; r++) s += hl[(r0 + r) * 17 + bin];
    atomicAdd(&hred[bin], (float)s);
    __syncthreads();
    if (t < NBINS) atomicAdd(&Hist[g * NBINS + t], hred[t]);
}

// ---------- NTN bilinear ----------
__global__ __launch_bounds__(128) void k_ntn(const float* __restrict__ G1,
                                             const float* __restrict__ G2,
                                             const float* __restrict__ T,
                                             const float* __restrict__ tb,
                                             float* __restrict__ TP) {
    int b = blockIdx.x, k = blockIdx.y;
    int e = threadIdx.x;
    const float* Tk = T + (size_t)k * DD * DD;
    float g2e = G2[b * DD + e];
    float acc = 0.f;
    for (int d = 0; d < DD; d++) acc += G1[b * DD + d] * Tk[(size_t)d * DD + e];
    float val = acc * g2e;
    #pragma unroll
    for (int o = 32; o > 0; o >>= 1) val += __shfl_down(val, o);
    __shared__ float ps[2];
    if ((e & 63) == 0) ps[e >> 6] = val;
    __syncthreads();
    if (e == 0) TP[b * KNTN + k] = ps[0] + ps[1] + tb[k];
}

// ---------- final MLPs: staged-LDS weights, 64 graphs in parallel ----------
__global__ __launch_bounds__(256) void k_final(const float* __restrict__ TP, const float* __restrict__ Hist,
                        const float* nw1, const float* nb1, const float* nw2, const float* nb2,
                        const float* nw3, const float* nb3,
                        const float* hw1, const float* hb1, const float* hw2, const float* hb2,
                        const float* fw1, const float* fb1, const float* fw2, const float* fb2,
                        float* __restrict__ out) {
    __shared__ float sTP[BB * 16], sHist[BB * 16];
    __shared__ float snw1[512], snw2[512], shw1[512], shw2[512];
    __shared__ float snw3[16], snb1[32], snb2[16], shb1[32], shb2[16];
    __shared__ float sfw1[136], sfb1[8], sfw2[8], sscal[2];
    int t = threadIdx.x;
    for (int i = t; i < BB * 16; i += 256) { sTP[i] = TP[i]; sHist[i] = Hist[i]; }
    for (int i = t; i < 512; i += 256) {
        snw1[i] = nw1[i]; snw2[i] = nw2[i]; shw1[i] = hw1[i]; shw2[i] = hw2[i];
    }
    if (t < 136) sfw1[t] = fw1[t];
    if (t < 32) { snb1[t] = nb1[t]; shb1[t] = hb1[t]; }
    if (t < 16) { snb2[t] = nb2[t]; shb2[t] = hb2[t]; snw3[t] = nw3[t]; }
    if (t < 8) { sfb1[t] = fb1[t]; sfw2[t] = fw2[t]; }
    if (t == 0) { sscal[0] = nb3[0]; sscal[1] = fb2[0]; }
    __syncthreads();
    if (t >= BB) return;
    int b = t;
    float h1[32];
    #pragma unroll
    for (int i = 0; i < 32; i++) {
        float a = snb1[i];
        for (int k = 0; k < 16; k++) a += sTP[b * 16 + k] * snw1[i * 16 + k];
        h1[i] = fmaxf(a, 0.f);
    }
    float h2[16];
    #pragma unroll
    for (int j = 0; j < 16; j++) {
        float a = snb2[j];
        for (int i = 0; i < 32; i++) a += h1[i] * snw2[j * 32 + i];
        h2[j] = fmaxf(a, 0.f);
    }
    float nt = sscal[0];
    for (int j = 0; j < 16; j++) nt += h2[j] * snw3[j];
    nt = 1.f / (1.f + expf(-nt));
    float hh[16]; float sum = 0.f;
    for (int k = 0; k < 16; k++) { hh[k] = sHist[b * 16 + k]; sum += hh[k]; }
    float inv = 1.f / (sum + 1e-8f);
    for (int k = 0; k < 16; k++) hh[k] *= inv;
    float g1v[32];
    #pragma unroll
    for (int i = 0; i < 32; i++) {
        float a = shb1[i];
        for (int k = 0; k < 16; k++) a += hh[k] * shw1[i * 16 + k];
        g1v[i] = fmaxf(a, 0.f);
    }
    float hemb[16];
    #pragma unroll
    for (int j = 0; j < 16; j++) {
        float a = shb2[j];
        for (int i = 0; i < 32; i++) a += g1v[i] * shw2[j * 32 + i];
        hemb[j] = a;
    }
    float comb[17];
    comb[0] = nt;
    for (int j = 0; j < 16; j++) comb[1 + j] = hemb[j];
    float f1[8];
    #pragma unroll
    for (int i = 0; i < 8; i++) {
        float a = sfb1[i];
        for (int j = 0; j < 17; j++) a += comb[j] * sfw1[i * 17 + j];
        f1[i] = fmaxf(a, 0.f);
    }
    float o = sscal[1];
    for (int i = 0; i < 8; i++) o += f1[i] * sfw2[i];
    out[b] = 1.f / (1.f + expf(-o));
}

extern "C" void kernel_launch(void* const* d_in, const int* in_sizes, int n_in,
                              void* d_out, int out_size, void* d_ws, size_t ws_size,
                              hipStream_t stream) {
    const float* x1    = (const float*)d_in[0];
    const float* x2    = (const float*)d_in[1];
    const int*   ei1   = (const int*)d_in[2];
    const int*   ei2   = (const int*)d_in[3];
    const float* gcn_w = (const float*)d_in[6];
    const float* gcn_b = (const float*)d_in[7];
    const float* bn_g  = (const float*)d_in[8];
    const float* bn_b  = (const float*)d_in[9];
    const float* bn_m  = (const float*)d_in[10];
    const float* bn_v  = (const float*)d_in[11];
    const float* ctx_w = (const float*)d_in[12];
    const float* ctx_b = (const float*)d_in[13];
    const float* att_w = (const float*)d_in[14];
    const float* att_b = (const float*)d_in[15];
    const float* ntn_T = (const float*)d_in[16];
    const float* ntn_b = (const float*)d_in[17];
    const float* nw1 = (const float*)d_in[18];
    const float* nb1 = (const float*)d_in[19];
    const float* nw2 = (const float*)d_in[20];
    const float* nb2 = (const float*)d_in[21];
    const float* nw3 = (const float*)d_in[22];
    const float* nb3 = (const float*)d_in[23];
    const float* hw1 = (const float*)d_in[24];
    const float* hb1 = (const float*)d_in[25];
    const float* hw2 = (const float*)d_in[26];
    const float* hb2 = (const float*)d_in[27];
    const float* fw1 = (const float*)d_in[28];
    const float* fb1 = (const float*)d_in[29];
    const float* fw2 = (const float*)d_in[30];
    const float* fb2 = (const float*)d_in[31];
    float* out = (float*)d_out;

    ushort_t* Xbf = (ushort_t*)d_ws;        // 2*NND (reused as Nrm)
    ushort_t* Abf = Xbf + 2 * (size_t)NND;  // 2*NND
    ushort_t* Hbf = Abf + 2 * (size_t)NND;  // 2*NND
    ushort_t* wbf = Hbf + 2 * (size_t)NND;  // 4*DD*DD
    float* dinv = (float*)(wbf + 4 * DD * DD);  // 2*NN
    float* S    = dinv + 2 * NN;                // 2*NN
    float* G    = S + 2 * NN;                   // 2*BB*DD
    float* hist = G + 2 * BB * DD;              // BB*NBINS
    float* tp   = hist + BB * NBINS;            // BB*KNTN
    float* bnsc = tp + BB * KNTN;               // LL*DD
    float* bnsh = bnsc + LL * DD;               // LL*DD
    int* degi  = (int*)(bnsh + LL * DD);        // 2*NN
    int* rowst = degi + 2 * NN;                 // 2*NN
    int* bcur  = rowst + 2 * NN;                // NBKT
    ushort_t* esrc = (ushort_t*)(bcur + NBKT);  // NBKT*BCAP u16
    unsigned* ibuf = (unsigned*)(esrc + (size_t)NBKT * BCAP);  // NBKT*BCAP u32

    k_prep<<<8257, 256, 0, stream>>>(x1, x2, gcn_w, ctx_w, gcn_b, bn_g, bn_b, bn_m, bn_v,
                                     Xbf, wbf, bnsc, bnsh, bcur, hist);
    k_bucket<<<2 * EE / 2048, 256, 0, stream>>>(ei1, ei2, bcur, ibuf);
    k_bcsr<<<NBKT, 256, 0, stream>>>(ibuf, bcur, degi, dinv, rowst, esrc);

    for (int l = 0; l < LL; l++) {
        k_mgemm<0><<<2 * NN / 128, 256, 0, stream>>>(l == 0 ? Xbf : Abf,
                                                     wbf + (size_t)l * DD * DD,
                                                     nullptr, Hbf, nullptr, nullptr, nullptr, dinv);
        if (l < LL - 1)
            k_agg<0><<<2 * NN / 16, 256, 0, stream>>>(Hbf, rowst, degi, esrc, dinv,
                                                      bnsc + l * DD, bnsh + l * DD, Abf, nullptr);
        else
            k_agg<1><<<2 * NN / 16, 256, 0, stream>>>(Hbf, rowst, degi, esrc, dinv,
                                                      bnsc + l * DD, bnsh + l * DD, Abf, Xbf);
    }
    k_mgemm<2><<<2 * NN / 128, 256, 0, stream>>>(Abf, wbf + 3 * DD * DD, ctx_b,
                                                 nullptr, att_w, att_b, S, nullptr);
    k_pool2<<<2 * BB, 512, 0, stream>>>(S, Abf, G);
    k_hist<<<BB * 16, 256, 0, stream>>>(Xbf, Xbf + NND, hist);
    k_ntn<<<dim3(BB, KNTN), 128, 0, stream>>>(G, G + BB * DD, ntn_T, ntn_b, tp);
    k_final<<<1, 256, 0, stream>>>(tp, hist, nw1, nb1, nw2, nb2, nw3, nb3,
                                   hw1, hb1, hw2, hb2, fw1, fb1, fw2, fb2, out);
}